// Round 4
// baseline (1855.750 us; speedup 1.0000x reference)
//
#include <hip/hip_runtime.h>

#define DIM 200
#define NENT 100000
#define NEDGE 1000000
#define EHALF 500000
#define NB 1024
#define NFILT 200
#define FLATSZ 39200

#define NDF ((size_t)NENT * DIM)
#define REGF ((size_t)20100000)
#define WPLANE (208 * 224)

typedef float floatx4 __attribute__((ext_vector_type(4)));
typedef short bf16x8 __attribute__((ext_vector_type(8)));
typedef short bf16x4 __attribute__((ext_vector_type(4)));
typedef _Float16 halfx8 __attribute__((ext_vector_type(8)));
typedef _Float16 halfx4 __attribute__((ext_vector_type(4)));

__device__ __forceinline__ void gAtomicAdd(float* p, float v) { unsafeAtomicAdd(p, v); }
__device__ __forceinline__ void gAtomicAdd(double* p, double v) { unsafeAtomicAdd(p, v); }

__device__ __forceinline__ short f2bf(float f) {
    union { float f; unsigned u; } v; v.f = f;
    unsigned r = v.u + 0x7fffu + ((v.u >> 16) & 1u);
    return (short)(r >> 16);
}
__device__ __forceinline__ float bf2f(short s) {
    union { float f; unsigned u; } v; v.u = ((unsigned)(unsigned short)s) << 16;
    return v.f;
}
// truncation split: hi = trunc-to-bf16(v), lo = trunc-to-bf16(v - hi).
__device__ __forceinline__ short f2bf_t(float f) {
    union { float f; unsigned u; } v; v.f = f;
    return (short)(v.u >> 16);
}
__device__ __forceinline__ void split8t(const floatx4& lo4, const floatx4& hi4,
                                        bf16x8& h, bf16x8& l) {
#pragma unroll
    for (int e = 0; e < 4; ++e) {
        short hh = f2bf_t(lo4[e]); h[e] = hh; l[e] = f2bf_t(lo4[e] - bf2f(hh));
        short hh2 = f2bf_t(hi4[e]); h[e + 4] = hh2; l[e + 4] = f2bf_t(hi4[e] - bf2f(hh2));
    }
}
// rounding split for producer-side split (matches original numerics)
__device__ __forceinline__ void split4r(const float4& v, bf16x4& h, bf16x4& l) {
    float a0 = v.x, a1 = v.y, a2 = v.z, a3 = v.w;
    short h0 = f2bf(a0), h1 = f2bf(a1), h2 = f2bf(a2), h3 = f2bf(a3);
    h[0] = h0; h[1] = h1; h[2] = h2; h[3] = h3;
    l[0] = f2bf(a0 - bf2f(h0)); l[1] = f2bf(a1 - bf2f(h1));
    l[2] = f2bf(a2 - bf2f(h2)); l[3] = f2bf(a3 - bf2f(h3));
}

// ---------------------------------------------------------------- CSR build
__global__ __launch_bounds__(256) void edge_hist(
    const int* __restrict__ dst, int* __restrict__ hist)
{
    int stride = gridDim.x * blockDim.x;
    for (int e = blockIdx.x * 256 + threadIdx.x; e < NEDGE; e += stride)
        atomicAdd(&hist[dst[e]], 1);
}

__global__ __launch_bounds__(256) void scan1(
    const int* __restrict__ hist, int* __restrict__ incl, int* __restrict__ bsum)
{
    __shared__ int sm[256];
    int i = blockIdx.x * 256 + threadIdx.x;
    int t = threadIdx.x;
    sm[t] = (i < NENT) ? hist[i] : 0;
    __syncthreads();
    for (int off = 1; off < 256; off <<= 1) {
        int v = (t >= off) ? sm[t - off] : 0;
        __syncthreads();
        sm[t] += v;
        __syncthreads();
    }
    if (i < NENT) incl[i] = sm[t];
    if (t == 255) bsum[blockIdx.x] = sm[255];
}

__global__ __launch_bounds__(512) void scan2(int* bsum, int nb)
{
    __shared__ int sm[512];
    int t = threadIdx.x;
    int v = (t < nb) ? bsum[t] : 0;
    sm[t] = v;
    __syncthreads();
    for (int off = 1; off < 512; off <<= 1) {
        int u = (t >= off) ? sm[t - off] : 0;
        __syncthreads();
        sm[t] += u;
        __syncthreads();
    }
    if (t < nb) bsum[t] = sm[t] - v;
}

__global__ __launch_bounds__(256) void scan3(
    const int* __restrict__ hist, int* __restrict__ offs,
    const int* __restrict__ bsum, int* __restrict__ cursor)
{
    int i = blockIdx.x * 256 + threadIdx.x;
    if (i < NENT) {
        int excl = offs[i] - hist[i] + bsum[blockIdx.x];
        offs[i] = excl;
        cursor[i] = excl;
    }
    if (i == 0) offs[NENT] = NEDGE;
}

__global__ __launch_bounds__(256) void edge_fill(
    const int* __restrict__ src, const int* __restrict__ dst,
    const int* __restrict__ etype, const float* __restrict__ enorm,
    int* __restrict__ cursor, int4* __restrict__ recs)
{
    int stride = gridDim.x * blockDim.x;
    for (int e = blockIdx.x * 256 + threadIdx.x; e < NEDGE; e += stride) {
        int pos = atomicAdd(&cursor[dst[e]], 1);
        recs[pos] = make_int4(src[e], etype[e] | ((e >= EHALF) ? 0x10000 : 0),
                              __float_as_int(enorm[e]), 0);
    }
}

__global__ __launch_bounds__(256) void build_map(
    const int* __restrict__ subj, const int* __restrict__ obj, int* __restrict__ map)
{
    int i = blockIdx.x * 256 + threadIdx.x;
    if (i < NB) map[subj[i]] = i;
    else if (i < 2 * NB) map[obj[i - NB]] = i;
}

// fp32 -> fp16 elementwise (x rows for the gathers)
__global__ __launch_bounds__(256) void to_f16(
    const float* __restrict__ X, _Float16* __restrict__ Y, long n4)
{
    long stride = (long)gridDim.x * blockDim.x;
    for (long i = (long)blockIdx.x * blockDim.x + threadIdx.x; i < n4; i += stride) {
        float4 v = ((const float4*)X)[i];
        halfx4 h;
        h[0] = (_Float16)v.x; h[1] = (_Float16)v.y;
        h[2] = (_Float16)v.z; h[3] = (_Float16)v.w;
        ((halfx4*)Y)[i] = h;
    }
}

// ---------------------------------------------------------------- gather (2-deep pipelined, fp16 x rows)
// outputs pre-split bf16 hi/lo planes: row = 400 shorts (hi[0..200), lo[200..400))
__global__ __launch_bounds__(256) void gather_nodes(
    const _Float16* __restrict__ x16, const float* __restrict__ r,
    const int* __restrict__ offs, const int4* __restrict__ recs,
    short* __restrict__ aggI, short* __restrict__ aggO)
{
    int node = blockIdx.x * 4 + (threadIdx.x >> 6);
    int lane = threadIdx.x & 63;
    if (node >= NENT) return;
    int beg = offs[node], end = offs[node + 1];
    bool act = lane < 50;
    int lane_c = min(lane, 49);
    const float4* rb = (const float4*)r;
    float4 aI = make_float4(0.f, 0.f, 0.f, 0.f);
    float4 aO = make_float4(0.f, 0.f, 0.f, 0.f);

    auto ld_x = [&](int s) -> float4 {
        halfx4 v = *(const halfx4*)&x16[(size_t)s * 200 + lane_c * 4];
        return make_float4((float)v[0], (float)v[1], (float)v[2], (float)v[3]);
    };

    if (beg < end) {
        int i1 = min(beg + 1, end - 1);
        int4 rcA = recs[beg];
        int4 rcB = recs[i1];
        float4 xvA = ld_x(rcA.x);
        float4 rvA = rb[(size_t)(rcA.y & 0xffff) * 50 + lane_c];
        for (int i = beg; i < end; ++i) {
            int i2 = min(i + 2, end - 1);
            int4 rcC = recs[i2];
            float4 xvB = ld_x(rcB.x);
            float4 rvB = rb[(size_t)(rcB.y & 0xffff) * 50 + lane_c];
            float w = __int_as_float(rcA.z);
            float wI = (rcA.y & 0x10000) ? 0.f : w;
            float wO = w - wI;
            float px = xvA.x * rvA.x, py = xvA.y * rvA.y,
                  pz = xvA.z * rvA.z, pw = xvA.w * rvA.w;
            aI.x += px * wI; aI.y += py * wI; aI.z += pz * wI; aI.w += pw * wI;
            aO.x += px * wO; aO.y += py * wO; aO.z += pz * wO; aO.w += pw * wO;
            rcA = rcB; rcB = rcC; xvA = xvB; rvA = rvB;
        }
    }
    if (act) {
        bf16x4 hI, lI, hO, lO;
        split4r(aI, hI, lI);
        split4r(aO, hO, lO);
        size_t base = (size_t)node * 400 + lane * 4;
        *(bf16x4*)&aggI[base] = hI;
        *(bf16x4*)&aggI[base + 200] = lI;
        *(bf16x4*)&aggO[base] = hO;
        *(bf16x4*)&aggO[base + 200] = lO;
    }
}

// ---------------------------------------------------------------- weight packing
__global__ __launch_bounds__(256) void pack_w3(
    const float* __restrict__ w0, const float* __restrict__ w1,
    const float* __restrict__ w2, const float* __restrict__ lrel,
    short* __restrict__ Wp)
{
    int i = blockIdx.x * 256 + threadIdx.x;
    if (i >= 3 * WPLANE) return;
    int seg = i / WPLANE, rem = i % WPLANE;
    int n = rem / 224, k = rem % 224;
    const float* W = (seg == 0) ? w0 : (seg == 1) ? w1 : w2;
    float v = (n < 200 && k < 200) ? W[k * 200 + n] : 0.f;
    if (seg == 2 && n < 200 && k < 200) v *= lrel[k];
    short hi = f2bf(v);
    Wp[i] = hi;
    Wp[i + 3 * WPLANE] = f2bf(v - bf2f(hi));
}

__global__ __launch_bounds__(256) void pack_fcw(
    const float* __restrict__ W, _Float16* __restrict__ Wt)
{
    long i = (long)blockIdx.x * 256 + threadIdx.x;
    if (i >= (long)208 * FLATSZ) return;
    int n = (int)(i / FLATSZ);
    Wt[i] = (n < 200) ? (_Float16)W[i] : (_Float16)0.f;
}

// ---------------------------------------------------------------- split-bf16 MFMA GEMM
// Barrier-free K loop: B fragments are read DIRECTLY from global (L1/L2-resident
// Wp, ~26 KB per kc panel shared by all waves on the CU) with the exact lane
// pattern the old LDS read used -- no LDS staging, no per-kc __syncthreads, no
// bank conflicts. Each wave streams independently; 12 waves/CU hide L2 latency
// under the 78-MFMA cluster per kc. A is prefetched 1-deep in registers.
template<int A2MODE>
__global__ __launch_bounds__(256) void gemm_mfma(
    const short* __restrict__ A0s, const short* __restrict__ A1s,
    const float* __restrict__ A2f, const _Float16* __restrict__ A2h,
    const short* __restrict__ WpH, const short* __restrict__ WpL,
    float* C, const float* __restrict__ bias, const int* __restrict__ map,
    float alpha, int M, double* __restrict__ s1, double* __restrict__ s2)
{
    constexpr int NF = 13;
    __shared__ float fsum[208];
    __shared__ float fsq[208];

    int t = threadIdx.x;
    int lane = t & 63, wave = t >> 6;
    int col16 = lane & 15, quad = lane >> 4;
    int row_base = blockIdx.x * 128 + wave * 32;
    if (t < 208) { fsum[t] = 0.f; fsq[t] = 0.f; }
    __syncthreads();

    floatx4 acc[NF][2];
#pragma unroll
    for (int nf = 0; nf < NF; ++nf) { acc[nf][0] = (floatx4)0.f; acc[nf][1] = (floatx4)0.f; }
    int r0 = row_base + col16, r1 = row_base + 16 + col16;
    int r0c = min(r0, M - 1), r1c = min(r1, M - 1);
    size_t b0 = (size_t)r0c * 400, b1 = (size_t)r1c * 400;

    // per-lane B offset within a kc panel: row (nf*16+col16), k (k0+quad*8)
    const int bl_off = col16 * 224 + quad * 8;

    bf16x8 ch0, cl0, ch1, cl1;                 // current A frags
    bf16x8 nh0, nl0v, nh1, nl1v;               // next A frags

    auto loadA = [&](int kc, bf16x8& h0, bf16x8& l0, bf16x8& h1, bf16x8& l1) {
        int seg = kc / 7, c = kc - seg * 7;
        int koff = c * 32 + quad * 8;
        if (koff < 200) {
            if (seg < 2) {
                const short* A = seg ? A1s : A0s;
                h0 = *(const bf16x8*)&A[b0 + koff];
                l0 = *(const bf16x8*)&A[b0 + 200 + koff];
                h1 = *(const bf16x8*)&A[b1 + koff];
                l1 = *(const bf16x8*)&A[b1 + 200 + koff];
            } else {
                size_t o0 = (size_t)r0c * 200 + koff, o1 = (size_t)r1c * 200 + koff;
                floatx4 x0, x1v, y0, y1v;
                if (A2MODE == 0) {
                    x0 = *(const floatx4*)&A2f[o0];
                    x1v = *(const floatx4*)&A2f[o0 + 4];
                    y0 = *(const floatx4*)&A2f[o1];
                    y1v = *(const floatx4*)&A2f[o1 + 4];
                } else {
                    halfx8 v0 = *(const halfx8*)&A2h[o0];
                    halfx8 v1 = *(const halfx8*)&A2h[o1];
#pragma unroll
                    for (int e = 0; e < 4; ++e) {
                        x0[e] = (float)v0[e]; x1v[e] = (float)v0[e + 4];
                        y0[e] = (float)v1[e]; y1v[e] = (float)v1[e + 4];
                    }
                }
                split8t(x0, x1v, h0, l0);
                split8t(y0, y1v, h1, l1);
            }
        } else {
            h0 = (bf16x8)0; l0 = (bf16x8)0; h1 = (bf16x8)0; l1 = (bf16x8)0;
        }
    };

    loadA(0, ch0, cl0, ch1, cl1);

    for (int kc = 0; kc < 21; ++kc) {
        if (kc < 20)
            loadA(kc + 1, nh0, nl0v, nh1, nl1v);
        int seg = kc / 7, c = kc - seg * 7, k0 = c * 32;
        const short* WH = WpH + seg * WPLANE + k0 + bl_off;
        const short* WL = WpL + seg * WPLANE + k0 + bl_off;
        __builtin_amdgcn_s_setprio(1);
#pragma unroll
        for (int nf = 0; nf < NF; ++nf) {
            bf16x8 bh = *(const bf16x8*)&WH[nf * (16 * 224)];
            bf16x8 bl = *(const bf16x8*)&WL[nf * (16 * 224)];
            acc[nf][0] = __builtin_amdgcn_mfma_f32_16x16x32_bf16(ch0, bh, acc[nf][0], 0, 0, 0);
            acc[nf][0] = __builtin_amdgcn_mfma_f32_16x16x32_bf16(ch0, bl, acc[nf][0], 0, 0, 0);
            acc[nf][0] = __builtin_amdgcn_mfma_f32_16x16x32_bf16(cl0, bh, acc[nf][0], 0, 0, 0);
            acc[nf][1] = __builtin_amdgcn_mfma_f32_16x16x32_bf16(ch1, bh, acc[nf][1], 0, 0, 0);
            acc[nf][1] = __builtin_amdgcn_mfma_f32_16x16x32_bf16(ch1, bl, acc[nf][1], 0, 0, 0);
            acc[nf][1] = __builtin_amdgcn_mfma_f32_16x16x32_bf16(cl1, bh, acc[nf][1], 0, 0, 0);
        }
        __builtin_amdgcn_s_setprio(0);
        ch0 = nh0; cl0 = nl0v; ch1 = nh1; cl1 = nl1v;
    }

    int slot[2][4];
    if (map) {
#pragma unroll
        for (int h = 0; h < 2; ++h)
#pragma unroll
            for (int j = 0; j < 4; ++j) {
                int rr = row_base + h * 16 + quad * 4 + j;
                slot[h][j] = (rr < M) ? map[rr] : -1;
            }
    }
#pragma unroll
    for (int nf = 0; nf < NF; ++nf) {
        int lc = nf * 16 + col16;
        int colg = lc;
        if (colg >= 200) continue;
        float bv = bias[colg];
        float ls = 0.f, lq = 0.f;
#pragma unroll
        for (int h = 0; h < 2; ++h) {
            int rbase = row_base + h * 16 + quad * 4;
#pragma unroll
            for (int j = 0; j < 4; ++j) {
                int rr = rbase + j;
                if (rr < M) {
                    float v = acc[nf][h][j] * alpha + bv;
                    ls += v; lq += v * v;
                    if (!map) {
                        C[(size_t)rr * 200 + colg] = v;
                    } else {
                        int s = slot[h][j];
                        if (s >= 0) C[(size_t)s * 200 + colg] = v;
                    }
                }
            }
        }
        ls += __shfl_down(ls, 32); ls += __shfl_down(ls, 16);
        lq += __shfl_down(lq, 32); lq += __shfl_down(lq, 16);
        if (quad == 0) {
            atomicAdd(&fsum[lc], ls);
            atomicAdd(&fsq[lc], lq);
        }
    }
    __syncthreads();
    if (t < 200) {
        gAtomicAdd(&s1[t], (double)fsum[t]);
        gAtomicAdd(&s2[t], (double)fsq[t]);
    }
}

// ---------------------------------------------------------------- fc MFMA GEMM body (fp16)
template<int NF0, int NF>
__device__ __forceinline__ void fc_gemm_body(
    const _Float16* __restrict__ Ph, const _Float16* __restrict__ Wt,
    float* __restrict__ part, int ky, _Float16* Bs)
{
    int t = threadIdx.x;
    int lane = t & 63, wave = t >> 6;
    int col16 = lane & 15, quad = lane >> 4;
    int row_base = blockIdx.x * 128 + wave * 32;
    int c0 = ky * 25;
    floatx4 acc[NF][2];
#pragma unroll
    for (int nf = 0; nf < NF; ++nf) { acc[nf][0] = (floatx4)0.f; acc[nf][1] = (floatx4)0.f; }
    int r0 = row_base + col16, r1 = row_base + 16 + col16;
    const int rows4 = NF * 16 * 4;

    for (int c = c0; c < c0 + 25; ++c) {
        int k0 = c * 32;
        for (int i = t; i < rows4; i += 256) {
            int nl = i >> 2, part_i = i & 3;
            int n = NF0 * 16 + nl;
            *(halfx8*)&Bs[nl * 40 + part_i * 8] =
                *(const halfx8*)&Wt[(size_t)n * FLATSZ + k0 + part_i * 8];
        }
        __syncthreads();
        int koff = k0 + quad * 8;
        halfx8 a0 = *(const halfx8*)&Ph[(size_t)r0 * FLATSZ + koff];
        halfx8 a1 = *(const halfx8*)&Ph[(size_t)r1 * FLATSZ + koff];
#pragma unroll
        for (int nf = 0; nf < NF; ++nf) {
            halfx8 b = *(const halfx8*)&Bs[(nf * 16 + col16) * 40 + quad * 8];
            acc[nf][0] = __builtin_amdgcn_mfma_f32_16x16x32_f16(a0, b, acc[nf][0], 0, 0, 0);
            acc[nf][1] = __builtin_amdgcn_mfma_f32_16x16x32_f16(a1, b, acc[nf][1], 0, 0, 0);
        }
        __syncthreads();
    }
    float* out = part + (size_t)ky * (NB * 200);
#pragma unroll
    for (int nf = 0; nf < NF; ++nf) {
        int colg = NF0 * 16 + nf * 16 + col16;
        if (colg >= 200) continue;
#pragma unroll
        for (int h = 0; h < 2; ++h) {
            int rbase = row_base + h * 16 + quad * 4;
#pragma unroll
            for (int j = 0; j < 4; ++j)
                out[(size_t)(rbase + j) * 200 + colg] = acc[nf][h][j];
        }
    }
}

__global__ __launch_bounds__(256) void fc_gemm(
    const _Float16* __restrict__ Ph, const _Float16* __restrict__ Wt,
    float* __restrict__ part)
{
    __shared__ _Float16 Bs[112 * 40];
    int ky = blockIdx.y >> 1;
    if ((blockIdx.y & 1) == 0)
        fc_gemm_body<0, 7>(Ph, Wt, part, ky, Bs);
    else
        fc_gemm_body<7, 6>(Ph, Wt, part, ky, Bs);
}

__global__ __launch_bounds__(256) void fc_reduce(
    const float* __restrict__ part, const float* __restrict__ bias,
    float* __restrict__ hfc)
{
    int i = blockIdx.x * 256 + threadIdx.x;
    float acc = bias[i % 200];
#pragma unroll
    for (int y = 0; y < 49; ++y) acc += part[(size_t)y * (NB * 200) + i];
    hfc[i] = acc;
}

// ---------------------------------------------------------------- stats / bn
__global__ __launch_bounds__(256) void colstats(
    const float* __restrict__ X, int M, int rpb,
    double* __restrict__ s1, double* __restrict__ s2)
{
    int c = threadIdx.x;
    if (c >= 200) return;
    int r0 = blockIdx.x * rpb;
    int r1 = min(r0 + rpb, M);
    float sum = 0.f, sq = 0.f;
    for (int rr = r0; rr < r1; ++rr) {
        float v = X[(size_t)rr * 200 + c];
        sum += v; sq += v * v;
    }
    gAtomicAdd(&s1[c], (double)sum);
    gAtomicAdd(&s2[c], (double)sq);
}

__global__ void finalize_stats(const double* __restrict__ s1, const double* __restrict__ s2,
                               const float* __restrict__ g, const float* __restrict__ bb,
                               float* __restrict__ sc, float* __restrict__ sh,
                               int ncols, double count)
{
    int c = threadIdx.x;
    if (c >= ncols) return;
    double m = s1[c] / count;
    double v = s2[c] / count - m * m;
    double scd = (double)g[c] / sqrt(v + 1e-5);
    sc[c] = (float)scd;
    sh[c] = (float)((double)bb[c] - m * scd);
}

// bn + tanh, fp32 in -> fp16 out (layer-1 x for gather + gemm A2)
__global__ __launch_bounds__(256) void bn_tanh_f16(
    const float* __restrict__ X, const float* __restrict__ sc,
    const float* __restrict__ sh, _Float16* __restrict__ Y, long n4)
{
    long stride = (long)gridDim.x * blockDim.x;
    for (long i = (long)blockIdx.x * blockDim.x + threadIdx.x; i < n4; i += stride) {
        int c4 = (int)(i % 50) * 4;
        float4 v = ((const float4*)X)[i];
        halfx4 h;
        h[0] = (_Float16)tanhf(v.x * sc[c4 + 0] + sh[c4 + 0]);
        h[1] = (_Float16)tanhf(v.y * sc[c4 + 1] + sh[c4 + 1]);
        h[2] = (_Float16)tanhf(v.z * sc[c4 + 2] + sh[c4 + 2]);
        h[3] = (_Float16)tanhf(v.w * sc[c4 + 3] + sh[c4 + 3]);
        ((halfx4*)Y)[i] = h;
    }
}

__global__ __launch_bounds__(256) void bn_act_200(
    float* __restrict__ X, const float* __restrict__ sc, const float* __restrict__ sh,
    long n4, int act)
{
    long stride = (long)gridDim.x * blockDim.x;
    for (long i = (long)blockIdx.x * blockDim.x + threadIdx.x; i < n4; i += stride) {
        int c4 = (int)(i % 50) * 4;
        float4 v = ((const float4*)X)[i];
        float a0 = v.x * sc[c4 + 0] + sh[c4 + 0];
        float a1 = v.y * sc[c4 + 1] + sh[c4 + 1];
        float a2 = v.z * sc[c4 + 2] + sh[c4 + 2];
        float a3 = v.w * sc[c4 + 3] + sh[c4 + 3];
        if (act == 0) { a0 = tanhf(a0); a1 = tanhf(a1); a2 = tanhf(a2); a3 = tanhf(a3); }
        else { a0 = fmaxf(a0, 0.f); a1 = fmaxf(a1, 0.f); a2 = fmaxf(a2, 0.f); a3 = fmaxf(a3, 0.f); }
        ((float4*)X)[i] = make_float4(a0, a1, a2, a3);
    }
}

__global__ __launch_bounds__(256) void rel_mm(
    const float* __restrict__ R, const float* __restrict__ W, float* __restrict__ O)
{
    int idx = blockIdx.x * blockDim.x + threadIdx.x;
    if (idx >= 200 * 200) return;
    int row = idx / 200, col = idx - row * 200;
    float acc = 0.f;
    for (int k = 0; k < 200; ++k) acc = fmaf(R[row * 200 + k], W[k * 200 + col], acc);
    O[idx] = acc;
}

__global__ __launch_bounds__(256) void build_stk(
    const float* __restrict__ x2c, const float* __restrict__ r2,
    const int* __restrict__ subj, const int* __restrict__ ridx,
    const int* __restrict__ map,
    float* __restrict__ stk, double* __restrict__ s1, double* __restrict__ s2)
{
    __shared__ float wsum[4], wsq[4];
    int b = blockIdx.x, t = threadIdx.x;
    const float* se = x2c + (size_t)map[subj[b]] * DIM;
    const float* re = r2 + (size_t)ridx[b] * DIM;
    float sum = 0.f, sq = 0.f;
    for (int i = t; i < 400; i += 256) {
        float v = (i < 200) ? se[i] : re[i - 200];
        stk[(size_t)b * 400 + i] = v;
        sum += v; sq += v * v;
    }
    for (int off = 32; off > 0; off >>= 1) {
        sum += __shfl_down(sum, off);
        sq  += __shfl_down(sq, off);
    }
    if ((t & 63) == 0) { wsum[t >> 6] = sum; wsq[t >> 6] = sq; }
    __syncthreads();
    if (t == 0) {
        float S = wsum[0] + wsum[1] + wsum[2] + wsum[3];
        float Q = wsq[0] + wsq[1] + wsq[2] + wsq[3];
        gAtomicAdd(&s1[0], (double)S);
        gAtomicAdd(&s2[0], (double)Q);
    }
}

__global__ __launch_bounds__(256) void conv_fwd(
    const float* __restrict__ stk, const float* __restrict__ conv_w,
    const float* __restrict__ conv_b, const float* __restrict__ sc0,
    const float* __restrict__ sh0, _Float16* __restrict__ Ph,
    double* __restrict__ s1, double* __restrict__ s2)
{
    __shared__ float img[400];
    __shared__ float wsm[9800];
    __shared__ float bsm[200];
    __shared__ float fsum[200];
    __shared__ float fsq[200];
    int b = blockIdx.x, t = threadIdx.x;
    float scale0 = sc0[0], shift0 = sh0[0];
    if (t < 200) { fsum[t] = 0.f; fsq[t] = 0.f; bsm[t] = conv_b[t]; }
    for (int i = t; i < 400; i += 256) img[i] = stk[(size_t)b * 400 + i] * scale0 + shift0;
    for (int i = t; i < 9800; i += 256) wsm[i] = conv_w[i];
    __syncthreads();
    for (int fy = t; fy < 2800; fy += 256) {
        int f = fy / 14, y = fy - (fy / 14) * 14;
        const float* wf = &wsm[f * 49];
        float acc[14];
        float bias = bsm[f];
#pragma unroll
        for (int xx = 0; xx < 14; ++xx) acc[xx] = bias;
#pragma unroll
        for (int i = 0; i < 7; ++i) {
            const float* rowp = &img[(y + i) * 20];
            float rv[20];
#pragma unroll
            for (int c = 0; c < 20; ++c) rv[c] = rowp[c];
#pragma unroll
            for (int j = 0; j < 7; ++j) {
                float wv = wf[i * 7 + j];
#pragma unroll
                for (int xx = 0; xx < 14; ++xx) acc[xx] = fmaf(rv[xx + j], wv, acc[xx]);
            }
        }
        float ls = 0.f, lq = 0.f;
        _Float16* pp = Ph + (size_t)b * FLATSZ + (size_t)f * 196 + y * 14;
#pragma unroll
        for (int xx = 0; xx < 14; ++xx) {
            float v = acc[xx];
            pp[xx] = (_Float16)v;
            ls += v; lq += v * v;
        }
        atomicAdd(&fsum[f], ls);
        atomicAdd(&fsq[f], lq);
    }
    __syncthreads();
    if (t < 200) {
        gAtomicAdd(&s1[t], (double)fsum[t]);
        gAtomicAdd(&s2[t], (double)fsq[t]);
    }
}

__global__ __launch_bounds__(256) void bn1_relu_f16(
    _Float16* __restrict__ Ph, const float* __restrict__ sc, const float* __restrict__ sh)
{
    long n4 = (long)NB * (FLATSZ / 4);
    long stride = (long)gridDim.x * blockDim.x;
    for (long i = (long)blockIdx.x * blockDim.x + threadIdx.x; i < n4; i += stride) {
        int k4 = (int)(i % (FLATSZ / 4));
        int f = k4 / 49;
        float s = sc[f], h = sh[f];
        halfx4 v = ((const halfx4*)Ph)[i];
#pragma unroll
        for (int e = 0; e < 4; ++e) {
            float x = (float)v[e];
            x = fmaxf(x * s + h, 0.f);
            v[e] = (_Float16)x;
        }
        ((halfx4*)Ph)[i] = v;
    }
}

__global__ __launch_bounds__(256) void score_mm(
    const float* __restrict__ Hn, const float* __restrict__ x2c,
    const int* __restrict__ obj, const int* __restrict__ map,
    float* __restrict__ out)
{
    __shared__ float Asm[16][17];
    __shared__ float Bsm[16][17];
    int tx = threadIdx.x & 15, ty = threadIdx.x >> 4;
    int row = blockIdx.y * 16 + ty;
    int col = blockIdx.x * 16 + tx;
    int oj = map[obj[blockIdx.x * 16 + ty]];
    float acc = 0.f;
    for (int k0 = 0; k0 < 200; k0 += 16) {
        int k = k0 + tx;
        Asm[ty][tx] = (k < 200) ? Hn[(size_t)row * 200 + k] : 0.f;
        Bsm[ty][tx] = (k < 200) ? x2c[(size_t)oj * 200 + k] : 0.f;
        __syncthreads();
#pragma unroll
        for (int kk = 0; kk < 16; ++kk) acc = fmaf(Asm[ty][kk], Bsm[tx][kk], acc);
        __syncthreads();
    }
    out[(size_t)row * NB + col] = 1.f / (1.f + expf(-acc));
}

// ---------------------------------------------------------------- driver
extern "C" void kernel_launch(void* const* d_in, const int* in_sizes, int n_in,
                              void* d_out, int out_size, void* d_ws, size_t ws_size,
                              hipStream_t stream)
{
    (void)in_sizes; (void)n_in; (void)out_size;
    const float* init_embed = (const float*)d_in[0];
    const float* init_rel   = (const float*)d_in[1];
    const float* edge_norm  = (const float*)d_in[2];
    const float* w_in1  = (const float*)d_in[3];
    const float* w_out1 = (const float*)d_in[4];
    const float* w_loop1= (const float*)d_in[5];
    const float* w_rel1 = (const float*)d_in[6];
    const float* lrel1  = (const float*)d_in[7];
    const float* b1     = (const float*)d_in[8];
    const float* gm1    = (const float*)d_in[9];
    const float* be1    = (const float*)d_in[10];
    const float* w_in2  = (const float*)d_in[11];
    const float* w_out2 = (const float*)d_in[12];
    const float* w_loop2= (const float*)d_in[13];
    const float* w_rel2 = (const float*)d_in[14];
    const float* lrel2  = (const float*)d_in[15];
    const float* b2     = (const float*)d_in[16];
    const float* gm2    = (const float*)d_in[17];
    const float* be2    = (const float*)d_in[18];
    const float* conv_w = (const float*)d_in[19];
    const float* conv_b = (const float*)d_in[20];
    const float* fc_w   = (const float*)d_in[21];
    const float* fc_b   = (const float*)d_in[22];
    const float* bn0_g  = (const float*)d_in[23];
    const float* bn0_b  = (const float*)d_in[24];
    const float* bn1_g  = (const float*)d_in[25];
    const float* bn1_b  = (const float*)d_in[26];
    const float* bn2_g  = (const float*)d_in[27];
    const float* bn2_b  = (const float*)d_in[28];
    const int* subj   = (const int*)d_in[29];
    const int* relidx = (const int*)d_in[30];
    const int* obj    = (const int*)d_in[31];
    const int* src    = (const int*)d_in[32];
    const int* dst    = (const int*)d_in[33];
    const int* etype  = (const int*)d_in[34];

    float* ws = (float*)d_ws;
    float* R0 = ws;                 // L1: ie16 then x1f (C); L2: aggI; head: Ph
    float* R1 = ws + REGF;          // L1: aggI; then x1h (fp16)
    float* R2 = ws + 2 * REGF;      // aggO; head: fch + fpart
    float* p = ws + 3 * REGF;       // tail
    float* r1v = p;            p += 40000;
    float* r2v = p;            p += 40000;
    float* stk = p;            p += 409600;
    float* hfc = p;            p += 204800;
    float* x2c = p;            p += 409600;
    float* fsc = p;            p += 256;
    float* fsh = p;            p += 256;
    double* ds1 = (double*)p;  p += 512;
    double* ds2 = (double*)p;  p += 512;
    short* Wp = (short*)p;     p += (6 * WPLANE) / 2;
    int* map = (int*)p;        p += NENT;
    int* hist = (int*)p;       p += NENT;
    int* offs = (int*)p;       p += NENT + 4;
    int* cursor = (int*)p;     p += NENT;
    int* bsum = (int*)p;       p += 512;
    int4* recs = (int4*)p;     p += (size_t)NEDGE * 4;

    _Float16* ie16 = (_Float16*)R0;   // fp16 init_embed (dead after L1 gather)
    float* x1f = R0;                  // L1 gemm C (clobbers ie16 -- ok)
    short* aggI1 = (short*)R1;        // L1 agg split-bf16 (NENT x 400 shorts)
    short* aggOs = (short*)R2;        // agg-out split-bf16 (both layers)
    _Float16* x1h = (_Float16*)R1;    // fp16 x1 (aggI1 dead after L1 gemm)
    short* aggI2 = (short*)R0;        // L2 aggI (x1f dead after bn_tanh_f16)
    _Float16* Ph  = (_Float16*)R0;
    _Float16* fch = (_Float16*)R2;
    float* fpart = R2 + 4200000;

    const size_t NEED = (size_t)(p - ws) * sizeof(float);
    if (ws_size < NEED) return;

    const int NBLK = (NENT + 255) / 256;
    const size_t DSBYTES = 512 * sizeof(double);

    // -------- CSR build + slot map --------
    hipMemsetAsync(hist, 0, NENT * sizeof(int), stream);
    hipMemsetAsync(map, 0xFF, NENT * sizeof(int), stream);
    edge_hist<<<1024, 256, 0, stream>>>(dst, hist);
    scan1<<<NBLK, 256, 0, stream>>>(hist, offs, bsum);
    scan2<<<1, 512, 0, stream>>>(bsum, NBLK);
    scan3<<<NBLK, 256, 0, stream>>>(hist, offs, bsum, cursor);
    edge_fill<<<1024, 256, 0, stream>>>(src, dst, etype, edge_norm, cursor, recs);
    build_map<<<(2 * NB + 255) / 256, 256, 0, stream>>>(subj, obj, map);

    dim3 gGemm((NENT + 127) / 128);

    // -------- layer 1 --------
    pack_w3<<<(3 * WPLANE + 255) / 256, 256, 0, stream>>>(w_in1, w_out1, w_loop1, lrel1, Wp);
    to_f16<<<4096, 256, 0, stream>>>(init_embed, ie16, (long)NENT * 50);
    gather_nodes<<<(NENT + 3) / 4, 256, 0, stream>>>(ie16, init_rel, offs, recs,
                                                     aggI1, aggOs);
    hipMemsetAsync(ds1, 0, DSBYTES, stream);
    gemm_mfma<0><<<gGemm, 256, 0, stream>>>(
        aggI1, aggOs, init_embed, nullptr, Wp, Wp + 3 * WPLANE,
        x1f, b1, nullptr, 1.f / 3.f, NENT, ds1, ds2);
    finalize_stats<<<1, 256, 0, stream>>>(ds1, ds2, gm1, be1, fsc, fsh, 200, (double)NENT);
    bn_tanh_f16<<<4096, 256, 0, stream>>>(x1f, fsc, fsh, x1h, (long)NENT * 50);
    rel_mm<<<(40000 + 255) / 256, 256, 0, stream>>>(init_rel, w_rel1, r1v);

    // -------- layer 2 (fp16 x; compact output) --------
    pack_w3<<<(3 * WPLANE + 255) / 256, 256, 0, stream>>>(w_in2, w_out2, w_loop2, lrel2, Wp);
    gather_nodes<<<(NENT + 3) / 4, 256, 0, stream>>>(x1h, r1v, offs, recs,
                                                     aggI2, aggOs);
    hipMemsetAsync(ds1, 0, DSBYTES, stream);
    gemm_mfma<1><<<gGemm, 256, 0, stream>>>(
        aggI2, aggOs, nullptr, x1h, Wp, Wp + 3 * WPLANE,
        x2c, b2, map, 1.f / 3.f, NENT, ds1, ds2);
    finalize_stats<<<1, 256, 0, stream>>>(ds1, ds2, gm2, be2, fsc, fsh, 200, (double)NENT);
    bn_act_200<<<400, 256, 0, stream>>>(x2c, fsc, fsh, (long)2 * NB * 50, 0);
    rel_mm<<<(40000 + 255) / 256, 256, 0, stream>>>(r1v, w_rel2, r2v);

    // -------- ConvE head --------
    hipMemsetAsync(ds1, 0, DSBYTES, stream);
    build_stk<<<NB, 256, 0, stream>>>(x2c, r2v, subj, relidx, map, stk, ds1, ds2);
    finalize_stats<<<1, 256, 0, stream>>>(ds1, ds2, bn0_g, bn0_b, fsc, fsh, 1,
                                          (double)((long)NB * 400));
    hipMemsetAsync(ds1, 0, DSBYTES, stream);
    conv_fwd<<<NB, 256, 0, stream>>>(stk, conv_w, conv_b, fsc, fsh, Ph, ds1, ds2);
    finalize_stats<<<1, 256, 0, stream>>>(ds1, ds2, bn1_g, bn1_b, fsc, fsh, 200,
                                          (double)((long)NB * 196));
    bn1_relu_f16<<<4096, 256, 0, stream>>>(Ph, fsc, fsh);
    pack_fcw<<<(int)(((long)208 * FLATSZ + 255) / 256), 256, 0, stream>>>(fc_w, fch);
    fc_gemm<<<dim3(8, 98), 256, 0, stream>>>(Ph, fch, fpart);
    fc_reduce<<<800, 256, 0, stream>>>(fpart, fc_b, hfc);
    hipMemsetAsync(ds1, 0, DSBYTES, stream);
    colstats<<<4, 256, 0, stream>>>(hfc, NB, 256, ds1, ds2);
    finalize_stats<<<1, 256, 0, stream>>>(ds1, ds2, bn2_g, bn2_b, fsc, fsh, 200, (double)NB);
    bn_act_200<<<200, 256, 0, stream>>>(hfc, fsc, fsh, (long)NB * 50, 1);
    score_mm<<<dim3(NB / 16, NB / 16), 256, 0, stream>>>(hfc, x2c, obj, map, (float*)d_out);
}

// Round 5
// 1336.006 us; speedup vs baseline: 1.3890x; 1.3890x over previous
//
#include <hip/hip_runtime.h>

#define DIM 200
#define NENT 100000
#define NEDGE 1000000
#define EHALF 500000
#define NB 1024
#define NFILT 200
#define FLATSZ 39200

#define NDF ((size_t)NENT * DIM)
#define REGF ((size_t)20100000)

// Wp panel layout: [seg:3][kc:7][y:2][plane:2][row:112][chunk:4][e:8] shorts,
// with chunk index XOR-swizzled by ((row>>1)&3) for bank-balanced ds_read_b128.
#define SEG_SH 100352          // shorts per seg   (7 * 14336)
#define KC_SH  14336           // shorts per kc    (2 * 7168)
#define HALF_SH 7168           // shorts per y-half panel (2 planes * 3584)
#define PLANE_SH 3584          // shorts per plane (112 rows * 32)
#define WP_TOTAL_SH 301056     // 3 * SEG_SH

typedef float floatx4 __attribute__((ext_vector_type(4)));
typedef short bf16x8 __attribute__((ext_vector_type(8)));
typedef short bf16x4 __attribute__((ext_vector_type(4)));
typedef _Float16 halfx8 __attribute__((ext_vector_type(8)));
typedef _Float16 halfx4 __attribute__((ext_vector_type(4)));

__device__ __forceinline__ void gAtomicAdd(float* p, float v) { unsafeAtomicAdd(p, v); }
__device__ __forceinline__ void gAtomicAdd(double* p, double v) { unsafeAtomicAdd(p, v); }

__device__ __forceinline__ short f2bf(float f) {
    union { float f; unsigned u; } v; v.f = f;
    unsigned r = v.u + 0x7fffu + ((v.u >> 16) & 1u);
    return (short)(r >> 16);
}
__device__ __forceinline__ float bf2f(short s) {
    union { float f; unsigned u; } v; v.u = ((unsigned)(unsigned short)s) << 16;
    return v.f;
}
// truncation split: hi = trunc-to-bf16(v), lo = trunc-to-bf16(v - hi).
__device__ __forceinline__ short f2bf_t(float f) {
    union { float f; unsigned u; } v; v.f = f;
    return (short)(v.u >> 16);
}
__device__ __forceinline__ void split8t(const floatx4& lo4, const floatx4& hi4,
                                        bf16x8& h, bf16x8& l) {
#pragma unroll
    for (int e = 0; e < 4; ++e) {
        short hh = f2bf_t(lo4[e]); h[e] = hh; l[e] = f2bf_t(lo4[e] - bf2f(hh));
        short hh2 = f2bf_t(hi4[e]); h[e + 4] = hh2; l[e + 4] = f2bf_t(hi4[e] - bf2f(hh2));
    }
}
// rounding split for producer-side split (matches original numerics)
__device__ __forceinline__ void split4r(const float4& v, bf16x4& h, bf16x4& l) {
    float a0 = v.x, a1 = v.y, a2 = v.z, a3 = v.w;
    short h0 = f2bf(a0), h1 = f2bf(a1), h2 = f2bf(a2), h3 = f2bf(a3);
    h[0] = h0; h[1] = h1; h[2] = h2; h[3] = h3;
    l[0] = f2bf(a0 - bf2f(h0)); l[1] = f2bf(a1 - bf2f(h1));
    l[2] = f2bf(a2 - bf2f(h2)); l[3] = f2bf(a3 - bf2f(h3));
}

// async global -> LDS, 16B per lane (wave-uniform LDS base + lane*16)
__device__ __forceinline__ void gload16(const short* g, short* l) {
    __builtin_amdgcn_global_load_lds(
        (const __attribute__((address_space(1))) void*)g,
        (__attribute__((address_space(3))) void*)l,
        16, 0, 0);
}

// ---------------------------------------------------------------- CSR build
__global__ __launch_bounds__(256) void edge_hist(
    const int* __restrict__ dst, int* __restrict__ hist)
{
    int stride = gridDim.x * blockDim.x;
    for (int e = blockIdx.x * 256 + threadIdx.x; e < NEDGE; e += stride)
        atomicAdd(&hist[dst[e]], 1);
}

__global__ __launch_bounds__(256) void scan1(
    const int* __restrict__ hist, int* __restrict__ incl, int* __restrict__ bsum)
{
    __shared__ int sm[256];
    int i = blockIdx.x * 256 + threadIdx.x;
    int t = threadIdx.x;
    sm[t] = (i < NENT) ? hist[i] : 0;
    __syncthreads();
    for (int off = 1; off < 256; off <<= 1) {
        int v = (t >= off) ? sm[t - off] : 0;
        __syncthreads();
        sm[t] += v;
        __syncthreads();
    }
    if (i < NENT) incl[i] = sm[t];
    if (t == 255) bsum[blockIdx.x] = sm[255];
}

__global__ __launch_bounds__(512) void scan2(int* bsum, int nb)
{
    __shared__ int sm[512];
    int t = threadIdx.x;
    int v = (t < nb) ? bsum[t] : 0;
    sm[t] = v;
    __syncthreads();
    for (int off = 1; off < 512; off <<= 1) {
        int u = (t >= off) ? sm[t - off] : 0;
        __syncthreads();
        sm[t] += u;
        __syncthreads();
    }
    if (t < nb) bsum[t] = sm[t] - v;
}

__global__ __launch_bounds__(256) void scan3(
    const int* __restrict__ hist, int* __restrict__ offs,
    const int* __restrict__ bsum, int* __restrict__ cursor)
{
    int i = blockIdx.x * 256 + threadIdx.x;
    if (i < NENT) {
        int excl = offs[i] - hist[i] + bsum[blockIdx.x];
        offs[i] = excl;
        cursor[i] = excl;
    }
    if (i == 0) offs[NENT] = NEDGE;
}

__global__ __launch_bounds__(256) void edge_fill(
    const int* __restrict__ src, const int* __restrict__ dst,
    const int* __restrict__ etype, const float* __restrict__ enorm,
    int* __restrict__ cursor, int4* __restrict__ recs)
{
    int stride = gridDim.x * blockDim.x;
    for (int e = blockIdx.x * 256 + threadIdx.x; e < NEDGE; e += stride) {
        int pos = atomicAdd(&cursor[dst[e]], 1);
        recs[pos] = make_int4(src[e], etype[e] | ((e >= EHALF) ? 0x10000 : 0),
                              __float_as_int(enorm[e]), 0);
    }
}

__global__ __launch_bounds__(256) void build_map(
    const int* __restrict__ subj, const int* __restrict__ obj, int* __restrict__ map)
{
    int i = blockIdx.x * 256 + threadIdx.x;
    if (i < NB) map[subj[i]] = i;
    else if (i < 2 * NB) map[obj[i - NB]] = i;
}

// fp32 -> fp16 elementwise (x rows for the gathers)
__global__ __launch_bounds__(256) void to_f16(
    const float* __restrict__ X, _Float16* __restrict__ Y, long n4)
{
    long stride = (long)gridDim.x * blockDim.x;
    for (long i = (long)blockIdx.x * blockDim.x + threadIdx.x; i < n4; i += stride) {
        float4 v = ((const float4*)X)[i];
        halfx4 h;
        h[0] = (_Float16)v.x; h[1] = (_Float16)v.y;
        h[2] = (_Float16)v.z; h[3] = (_Float16)v.w;
        ((halfx4*)Y)[i] = h;
    }
}

// ---------------------------------------------------------------- gather (2-deep pipelined, fp16 x rows)
// outputs pre-split bf16 hi/lo planes: row = 400 shorts (hi[0..200), lo[200..400))
__global__ __launch_bounds__(256) void gather_nodes(
    const _Float16* __restrict__ x16, const float* __restrict__ r,
    const int* __restrict__ offs, const int4* __restrict__ recs,
    short* __restrict__ aggI, short* __restrict__ aggO)
{
    int node = blockIdx.x * 4 + (threadIdx.x >> 6);
    int lane = threadIdx.x & 63;
    if (node >= NENT) return;
    int beg = offs[node], end = offs[node + 1];
    bool act = lane < 50;
    int lane_c = min(lane, 49);
    const float4* rb = (const float4*)r;
    float4 aI = make_float4(0.f, 0.f, 0.f, 0.f);
    float4 aO = make_float4(0.f, 0.f, 0.f, 0.f);

    auto ld_x = [&](int s) -> float4 {
        halfx4 v = *(const halfx4*)&x16[(size_t)s * 200 + lane_c * 4];
        return make_float4((float)v[0], (float)v[1], (float)v[2], (float)v[3]);
    };

    if (beg < end) {
        int i1 = min(beg + 1, end - 1);
        int4 rcA = recs[beg];
        int4 rcB = recs[i1];
        float4 xvA = ld_x(rcA.x);
        float4 rvA = rb[(size_t)(rcA.y & 0xffff) * 50 + lane_c];
        for (int i = beg; i < end; ++i) {
            int i2 = min(i + 2, end - 1);
            int4 rcC = recs[i2];
            float4 xvB = ld_x(rcB.x);
            float4 rvB = rb[(size_t)(rcB.y & 0xffff) * 50 + lane_c];
            float w = __int_as_float(rcA.z);
            float wI = (rcA.y & 0x10000) ? 0.f : w;
            float wO = w - wI;
            float px = xvA.x * rvA.x, py = xvA.y * rvA.y,
                  pz = xvA.z * rvA.z, pw = xvA.w * rvA.w;
            aI.x += px * wI; aI.y += py * wI; aI.z += pz * wI; aI.w += pw * wI;
            aO.x += px * wO; aO.y += py * wO; aO.z += pz * wO; aO.w += pw * wO;
            rcA = rcB; rcB = rcC; xvA = xvB; rvA = rvB;
        }
    }
    if (act) {
        bf16x4 hI, lI, hO, lO;
        split4r(aI, hI, lI);
        split4r(aO, hO, lO);
        size_t base = (size_t)node * 400 + lane * 4;
        *(bf16x4*)&aggI[base] = hI;
        *(bf16x4*)&aggI[base + 200] = lI;
        *(bf16x4*)&aggO[base] = hO;
        *(bf16x4*)&aggO[base + 200] = lO;
    }
}

// ---------------------------------------------------------------- weight packing (panel + swizzle)
// Decodes the LDS-image position back to (n,k) and stores the weight there, so
// global_load_lds copies panels linearly and ds_read_b128 at
//   short_idx = row*32 + (quad ^ ((row>>1)&3))*8
// is the correct, bank-balanced fragment.
__global__ __launch_bounds__(256) void pack_w3(
    const float* __restrict__ w0, const float* __restrict__ w1,
    const float* __restrict__ w2, const float* __restrict__ lrel,
    short* __restrict__ WpP)
{
    int i = blockIdx.x * 256 + threadIdx.x;
    if (i >= WP_TOTAL_SH) return;
    int seg = i / SEG_SH, rem = i % SEG_SH;
    int c = rem / KC_SH;  rem %= KC_SH;
    int y = rem / HALF_SH; rem %= HALF_SH;
    int plane = rem / PLANE_SH;
    int sp = rem % PLANE_SH;
    int rl = sp >> 5;                  // row within half-panel (0..111)
    int qx = (sp >> 3) & 3;            // stored 16B-chunk slot
    int e = sp & 7;
    int q = qx ^ ((rl >> 1) & 3);      // logical k-quad held in this slot
    int n = y * 112 + rl;
    int k = c * 32 + q * 8 + e;
    const float* W = (seg == 0) ? w0 : (seg == 1) ? w1 : w2;
    float v = (n < 200 && k < 200) ? W[k * 200 + n] : 0.f;
    if (seg == 2 && n < 200 && k < 200) v *= lrel[k];
    short hi = f2bf(v);
    WpP[i] = plane ? f2bf(v - bf2f(hi)) : hi;
}

__global__ __launch_bounds__(256) void pack_fcw(
    const float* __restrict__ W, _Float16* __restrict__ Wt)
{
    long i = (long)blockIdx.x * 256 + threadIdx.x;
    if (i >= (long)208 * FLATSZ) return;
    int n = (int)(i / FLATSZ);
    Wt[i] = (n < 200) ? (_Float16)W[i] : (_Float16)0.f;
}

// ---------------------------------------------------------------- split-bf16 MFMA GEMM
// m97-style pipeline: B panel (14336 B) double-buffered in LDS via
// global_load_lds (14 x 1024B wave-chunks, no reg staging, no ds_write),
// ONE __syncthreads per kc (its vmcnt drain publishes panel kc+1, which was
// issued before the MFMA cluster and hides under it). y-split keeps LDS at
// 28.7 KB -> 4-5 blocks/CU. Bank swizzle baked into pack_w3.
template<int NF0, int NF, int A2MODE>
__device__ __forceinline__ void gemm_body(
    const short* __restrict__ A0s, const short* __restrict__ A1s,
    const float* __restrict__ A2f, const _Float16* __restrict__ A2h,
    const short* __restrict__ WpP,
    float* C, const float* __restrict__ bias, const int* __restrict__ map,
    float alpha, int M, double* __restrict__ s1, double* __restrict__ s2,
    short* Bs, float* fsum, float* fsq)
{
    constexpr int Y = (NF0 == 0) ? 0 : 1;
    int t = threadIdx.x;
    int lane = t & 63, wave = t >> 6;
    int col16 = lane & 15, quad = lane >> 4;
    int row_base = blockIdx.x * 128 + wave * 32;
    if (t < 112) { fsum[t] = 0.f; fsq[t] = 0.f; }
    floatx4 acc[NF][2];
#pragma unroll
    for (int nf = 0; nf < NF; ++nf) { acc[nf][0] = (floatx4)0.f; acc[nf][1] = (floatx4)0.f; }
    int r0 = row_base + col16, r1 = row_base + 16 + col16;
    int r0c = min(r0, M - 1), r1c = min(r1, M - 1);
    size_t b0 = (size_t)r0c * 400, b1 = (size_t)r1c * 400;

    bf16x8 ch0, cl0, ch1, cl1;                 // current A frags
    bf16x8 nh0, nl0v, nh1, nl1v;               // next A frags

    auto gload = [&](int kc, int bufi) {
        int seg = kc / 7, c = kc - seg * 7;
        const short* g = WpP + seg * SEG_SH + c * KC_SH + Y * HALF_SH + lane * 8;
        short* l = Bs + bufi * HALF_SH;
        for (int cc = wave; cc < 14; cc += 4)
            gload16(g + cc * 512, l + cc * 512);
    };
    auto loadA = [&](int kc, bf16x8& h0, bf16x8& l0, bf16x8& h1, bf16x8& l1) {
        int seg = kc / 7, c = kc - seg * 7;
        int koff = c * 32 + quad * 8;
        if (koff < 200) {
            if (seg < 2) {
                const short* A = seg ? A1s : A0s;
                h0 = *(const bf16x8*)&A[b0 + koff];
                l0 = *(const bf16x8*)&A[b0 + 200 + koff];
                h1 = *(const bf16x8*)&A[b1 + koff];
                l1 = *(const bf16x8*)&A[b1 + 200 + koff];
            } else {
                size_t o0 = (size_t)r0c * 200 + koff, o1 = (size_t)r1c * 200 + koff;
                floatx4 x0, x1v, y0, y1v;
                if (A2MODE == 0) {
                    x0 = *(const floatx4*)&A2f[o0];
                    x1v = *(const floatx4*)&A2f[o0 + 4];
                    y0 = *(const floatx4*)&A2f[o1];
                    y1v = *(const floatx4*)&A2f[o1 + 4];
                } else {
                    halfx8 v0 = *(const halfx8*)&A2h[o0];
                    halfx8 v1 = *(const halfx8*)&A2h[o1];
#pragma unroll
                    for (int e = 0; e < 4; ++e) {
                        x0[e] = (float)v0[e]; x1v[e] = (float)v0[e + 4];
                        y0[e] = (float)v1[e]; y1v[e] = (float)v1[e + 4];
                    }
                }
                split8t(x0, x1v, h0, l0);
                split8t(y0, y1v, h1, l1);
            }
        } else {
            h0 = (bf16x8)0; l0 = (bf16x8)0; h1 = (bf16x8)0; l1 = (bf16x8)0;
        }
    };
    auto do_mfma = [&](int bufi) {
        const short* P = Bs + bufi * HALF_SH;
        __builtin_amdgcn_s_setprio(1);
#pragma unroll
        for (int nf = 0; nf < NF; ++nf) {
            int rl = nf * 16 + col16;
            int qs = quad ^ ((rl >> 1) & 3);
            bf16x8 bh = *(const bf16x8*)&P[rl * 32 + qs * 8];
            bf16x8 bl = *(const bf16x8*)&P[PLANE_SH + rl * 32 + qs * 8];
            acc[nf][0] = __builtin_amdgcn_mfma_f32_16x16x32_bf16(ch0, bh, acc[nf][0], 0, 0, 0);
            acc[nf][0] = __builtin_amdgcn_mfma_f32_16x16x32_bf16(ch0, bl, acc[nf][0], 0, 0, 0);
            acc[nf][0] = __builtin_amdgcn_mfma_f32_16x16x32_bf16(cl0, bh, acc[nf][0], 0, 0, 0);
            acc[nf][1] = __builtin_amdgcn_mfma_f32_16x16x32_bf16(ch1, bh, acc[nf][1], 0, 0, 0);
            acc[nf][1] = __builtin_amdgcn_mfma_f32_16x16x32_bf16(ch1, bl, acc[nf][1], 0, 0, 0);
            acc[nf][1] = __builtin_amdgcn_mfma_f32_16x16x32_bf16(cl1, bh, acc[nf][1], 0, 0, 0);
        }
        __builtin_amdgcn_s_setprio(0);
    };

    // prologue: panel 0 -> buf 0, A(0) -> regs; barrier publishes both
    gload(0, 0);
    loadA(0, ch0, cl0, ch1, cl1);
    __syncthreads();

    for (int kc = 0; kc < 21; ++kc) {
        if (kc < 20) {
            gload(kc + 1, (kc + 1) & 1);           // async into other buffer
            loadA(kc + 1, nh0, nl0v, nh1, nl1v);   // HBM prefetch into regs
        }
        do_mfma(kc & 1);
        __syncthreads();   // publishes panel kc+1; proves buf free for kc+2
        ch0 = nh0; cl0 = nl0v; ch1 = nh1; cl1 = nl1v;
    }

    int slot[2][4];
    if (map) {
#pragma unroll
        for (int h = 0; h < 2; ++h)
#pragma unroll
            for (int j = 0; j < 4; ++j) {
                int rr = row_base + h * 16 + quad * 4 + j;
                slot[h][j] = (rr < M) ? map[rr] : -1;
            }
    }
#pragma unroll
    for (int nf = 0; nf < NF; ++nf) {
        int lc = nf * 16 + col16;
        int colg = NF0 * 16 + lc;
        if (colg >= 200) continue;
        float bv = bias[colg];
        float ls = 0.f, lq = 0.f;
#pragma unroll
        for (int h = 0; h < 2; ++h) {
            int rbase = row_base + h * 16 + quad * 4;
#pragma unroll
            for (int j = 0; j < 4; ++j) {
                int rr = rbase + j;
                if (rr < M) {
                    float v = acc[nf][h][j] * alpha + bv;
                    ls += v; lq += v * v;
                    if (!map) {
                        C[(size_t)rr * 200 + colg] = v;
                    } else {
                        int s = slot[h][j];
                        if (s >= 0) C[(size_t)s * 200 + colg] = v;
                    }
                }
            }
        }
        ls += __shfl_down(ls, 32); ls += __shfl_down(ls, 16);
        lq += __shfl_down(lq, 32); lq += __shfl_down(lq, 16);
        if (quad == 0) {
            atomicAdd(&fsum[lc], ls);
            atomicAdd(&fsq[lc], lq);
        }
    }
    __syncthreads();
    if (t < NF * 16) {
        int colg = NF0 * 16 + t;
        if (colg < 200) {
            gAtomicAdd(&s1[colg], (double)fsum[t]);
            gAtomicAdd(&s2[colg], (double)fsq[t]);
        }
    }
}

template<int A2MODE>
__global__ __launch_bounds__(256) void gemm_mfma(
    const short* __restrict__ A0s, const short* __restrict__ A1s,
    const float* __restrict__ A2f, const _Float16* __restrict__ A2h,
    const short* __restrict__ WpP,
    float* C, const float* __restrict__ bias, const int* __restrict__ map,
    float alpha, int M, double* __restrict__ s1, double* __restrict__ s2)
{
    __shared__ short Bs[2 * HALF_SH];   // 28672 B
    __shared__ float fsum[112];
    __shared__ float fsq[112];
    if (blockIdx.y == 0)
        gemm_body<0, 7, A2MODE>(A0s, A1s, A2f, A2h, WpP, C, bias, map,
                                alpha, M, s1, s2, Bs, fsum, fsq);
    else
        gemm_body<7, 6, A2MODE>(A0s, A1s, A2f, A2h, WpP, C, bias, map,
                                alpha, M, s1, s2, Bs, fsum, fsq);
}

// ---------------------------------------------------------------- fc MFMA GEMM body (fp16)
template<int NF0, int NF>
__device__ __forceinline__ void fc_gemm_body(
    const _Float16* __restrict__ Ph, const _Float16* __restrict__ Wt,
    float* __restrict__ part, int ky, _Float16* Bs)
{
    int t = threadIdx.x;
    int lane = t & 63, wave = t >> 6;
    int col16 = lane & 15, quad = lane >> 4;
    int row_base = blockIdx.x * 128 + wave * 32;
    int c0 = ky * 25;
    floatx4 acc[NF][2];
#pragma unroll
    for (int nf = 0; nf < NF; ++nf) { acc[nf][0] = (floatx4)0.f; acc[nf][1] = (floatx4)0.f; }
    int r0 = row_base + col16, r1 = row_base + 16 + col16;
    const int rows4 = NF * 16 * 4;

    for (int c = c0; c < c0 + 25; ++c) {
        int k0 = c * 32;
        for (int i = t; i < rows4; i += 256) {
            int nl = i >> 2, part_i = i & 3;
            int n = NF0 * 16 + nl;
            *(halfx8*)&Bs[nl * 40 + part_i * 8] =
                *(const halfx8*)&Wt[(size_t)n * FLATSZ + k0 + part_i * 8];
        }
        __syncthreads();
        int koff = k0 + quad * 8;
        halfx8 a0 = *(const halfx8*)&Ph[(size_t)r0 * FLATSZ + koff];
        halfx8 a1 = *(const halfx8*)&Ph[(size_t)r1 * FLATSZ + koff];
#pragma unroll
        for (int nf = 0; nf < NF; ++nf) {
            halfx8 b = *(const halfx8*)&Bs[(nf * 16 + col16) * 40 + quad * 8];
            acc[nf][0] = __builtin_amdgcn_mfma_f32_16x16x32_f16(a0, b, acc[nf][0], 0, 0, 0);
            acc[nf][1] = __builtin_amdgcn_mfma_f32_16x16x32_f16(a1, b, acc[nf][1], 0, 0, 0);
        }
        __syncthreads();
    }
    float* out = part + (size_t)ky * (NB * 200);
#pragma unroll
    for (int nf = 0; nf < NF; ++nf) {
        int colg = NF0 * 16 + nf * 16 + col16;
        if (colg >= 200) continue;
#pragma unroll
        for (int h = 0; h < 2; ++h) {
            int rbase = row_base + h * 16 + quad * 4;
#pragma unroll
            for (int j = 0; j < 4; ++j)
                out[(size_t)(rbase + j) * 200 + colg] = acc[nf][h][j];
        }
    }
}

__global__ __launch_bounds__(256) void fc_gemm(
    const _Float16* __restrict__ Ph, const _Float16* __restrict__ Wt,
    float* __restrict__ part)
{
    __shared__ _Float16 Bs[112 * 40];
    int ky = blockIdx.y >> 1;
    if ((blockIdx.y & 1) == 0)
        fc_gemm_body<0, 7>(Ph, Wt, part, ky, Bs);
    else
        fc_gemm_body<7, 6>(Ph, Wt, part, ky, Bs);
}

__global__ __launch_bounds__(256) void fc_reduce(
    const float* __restrict__ part, const float* __restrict__ bias,
    float* __restrict__ hfc)
{
    int i = blockIdx.x * 256 + threadIdx.x;
    float acc = bias[i % 200];
#pragma unroll
    for (int y = 0; y < 49; ++y) acc += part[(size_t)y * (NB * 200) + i];
    hfc[i] = acc;
}

// ---------------------------------------------------------------- stats / bn
__global__ __launch_bounds__(256) void colstats(
    const float* __restrict__ X, int M, int rpb,
    double* __restrict__ s1, double* __restrict__ s2)
{
    int c = threadIdx.x;
    if (c >= 200) return;
    int r0 = blockIdx.x * rpb;
    int r1 = min(r0 + rpb, M);
    float sum = 0.f, sq = 0.f;
    for (int rr = r0; rr < r1; ++rr) {
        float v = X[(size_t)rr * 200 + c];
        sum += v; sq += v * v;
    }
    gAtomicAdd(&s1[c], (double)sum);
    gAtomicAdd(&s2[c], (double)sq);
}

__global__ void finalize_stats(const double* __restrict__ s1, const double* __restrict__ s2,
                               const float* __restrict__ g, const float* __restrict__ bb,
                               float* __restrict__ sc, float* __restrict__ sh,
                               int ncols, double count)
{
    int c = threadIdx.x;
    if (c >= ncols) return;
    double m = s1[c] / count;
    double v = s2[c] / count - m * m;
    double scd = (double)g[c] / sqrt(v + 1e-5);
    sc[c] = (float)scd;
    sh[c] = (float)((double)bb[c] - m * scd);
}

// bn + tanh, fp32 in -> fp16 out (layer-1 x for gather + gemm A2)
__global__ __launch_bounds__(256) void bn_tanh_f16(
    const float* __restrict__ X, const float* __restrict__ sc,
    const float* __restrict__ sh, _Float16* __restrict__ Y, long n4)
{
    long stride = (long)gridDim.x * blockDim.x;
    for (long i = (long)blockIdx.x * blockDim.x + threadIdx.x; i < n4; i += stride) {
        int c4 = (int)(i % 50) * 4;
        float4 v = ((const float4*)X)[i];
        halfx4 h;
        h[0] = (_Float16)tanhf(v.x * sc[c4 + 0] + sh[c4 + 0]);
        h[1] = (_Float16)tanhf(v.y * sc[c4 + 1] + sh[c4 + 1]);
        h[2] = (_Float16)tanhf(v.z * sc[c4 + 2] + sh[c4 + 2]);
        h[3] = (_Float16)tanhf(v.w * sc[c4 + 3] + sh[c4 + 3]);
        ((halfx4*)Y)[i] = h;
    }
}

__global__ __launch_bounds__(256) void bn_act_200(
    float* __restrict__ X, const float* __restrict__ sc, const float* __restrict__ sh,
    long n4, int act)
{
    long stride = (long)gridDim.x * blockDim.x;
    for (long i = (long)blockIdx.x * blockDim.x + threadIdx.x; i < n4; i += stride) {
        int c4 = (int)(i % 50) * 4;
        float4 v = ((const float4*)X)[i];
        float a0 = v.x * sc[c4 + 0] + sh[c4 + 0];
        float a1 = v.y * sc[c4 + 1] + sh[c4 + 1];
        float a2 = v.z * sc[c4 + 2] + sh[c4 + 2];
        float a3 = v.w * sc[c4 + 3] + sh[c4 + 3];
        if (act == 0) { a0 = tanhf(a0); a1 = tanhf(a1); a2 = tanhf(a2); a3 = tanhf(a3); }
        else { a0 = fmaxf(a0, 0.f); a1 = fmaxf(a1, 0.f); a2 = fmaxf(a2, 0.f); a3 = fmaxf(a3, 0.f); }
        ((float4*)X)[i] = make_float4(a0, a1, a2, a3);
    }
}

__global__ __launch_bounds__(256) void rel_mm(
    const float* __restrict__ R, const float* __restrict__ W, float* __restrict__ O)
{
    int idx = blockIdx.x * blockDim.x + threadIdx.x;
    if (idx >= 200 * 200) return;
    int row = idx / 200, col = idx - row * 200;
    float acc = 0.f;
    for (int k = 0; k < 200; ++k) acc = fmaf(R[row * 200 + k], W[k * 200 + col], acc);
    O[idx] = acc;
}

__global__ __launch_bounds__(256) void build_stk(
    const float* __restrict__ x2c, const float* __restrict__ r2,
    const int* __restrict__ subj, const int* __restrict__ ridx,
    const int* __restrict__ map,
    float* __restrict__ stk, double* __restrict__ s1, double* __restrict__ s2)
{
    __shared__ float wsum[4], wsq[4];
    int b = blockIdx.x, t = threadIdx.x;
    const float* se = x2c + (size_t)map[subj[b]] * DIM;
    const float* re = r2 + (size_t)ridx[b] * DIM;
    float sum = 0.f, sq = 0.f;
    for (int i = t; i < 400; i += 256) {
        float v = (i < 200) ? se[i] : re[i - 200];
        stk[(size_t)b * 400 + i] = v;
        sum += v; sq += v * v;
    }
    for (int off = 32; off > 0; off >>= 1) {
        sum += __shfl_down(sum, off);
        sq  += __shfl_down(sq, off);
    }
    if ((t & 63) == 0) { wsum[t >> 6] = sum; wsq[t >> 6] = sq; }
    __syncthreads();
    if (t == 0) {
        float S = wsum[0] + wsum[1] + wsum[2] + wsum[3];
        float Q = wsq[0] + wsq[1] + wsq[2] + wsq[3];
        gAtomicAdd(&s1[0], (double)S);
        gAtomicAdd(&s2[0], (double)Q);
    }
}

__global__ __launch_bounds__(256) void conv_fwd(
    const float* __restrict__ stk, const float* __restrict__ conv_w,
    const float* __restrict__ conv_b, const float* __restrict__ sc0,
    const float* __restrict__ sh0, _Float16* __restrict__ Ph,
    double* __restrict__ s1, double* __restrict__ s2)
{
    __shared__ float img[400];
    __shared__ float wsm[9800];
    __shared__ float bsm[200];
    __shared__ float fsum[200];
    __shared__ float fsq[200];
    int b = blockIdx.x, t = threadIdx.x;
    float scale0 = sc0[0], shift0 = sh0[0];
    if (t < 200) { fsum[t] = 0.f; fsq[t] = 0.f; bsm[t] = conv_b[t]; }
    for (int i = t; i < 400; i += 256) img[i] = stk[(size_t)b * 400 + i] * scale0 + shift0;
    for (int i = t; i < 9800; i += 256) wsm[i] = conv_w[i];
    __syncthreads();
    for (int fy = t; fy < 2800; fy += 256) {
        int f = fy / 14, y = fy - (fy / 14) * 14;
        const float* wf = &wsm[f * 49];
        float acc[14];
        float bias = bsm[f];
#pragma unroll
        for (int xx = 0; xx < 14; ++xx) acc[xx] = bias;
#pragma unroll
        for (int i = 0; i < 7; ++i) {
            const float* rowp = &img[(y + i) * 20];
            float rv[20];
#pragma unroll
            for (int c = 0; c < 20; ++c) rv[c] = rowp[c];
#pragma unroll
            for (int j = 0; j < 7; ++j) {
                float wv = wf[i * 7 + j];
#pragma unroll
                for (int xx = 0; xx < 14; ++xx) acc[xx] = fmaf(rv[xx + j], wv, acc[xx]);
            }
        }
        float ls = 0.f, lq = 0.f;
        _Float16* pp = Ph + (size_t)b * FLATSZ + (size_t)f * 196 + y * 14;
#pragma unroll
        for (int xx = 0; xx < 14; ++xx) {
            float v = acc[xx];
            pp[xx] = (_Float16)v;
            ls += v; lq += v * v;
        }
        atomicAdd(&fsum[f], ls);
        atomicAdd(&fsq[f], lq);
    }
    __syncthreads();
    if (t < 200) {
        gAtomicAdd(&s1[t], (double)fsum[t]);
        gAtomicAdd(&s2[t], (double)fsq[t]);
    }
}

__global__ __launch_bounds__(256) void bn1_relu_f16(
    _Float16* __restrict__ Ph, const float* __restrict__ sc, const float* __restrict__ sh)
{
    long n4 = (long)NB * (FLATSZ / 4);
    long stride = (long)gridDim.x * blockDim.x;
    for (long i = (long)blockIdx.x * blockDim.x + threadIdx.x; i < n4; i += stride) {
        int k4 = (int)(i % (FLATSZ / 4));
        int f = k4 / 49;
        float s = sc[f], h = sh[f];
        halfx4 v = ((const halfx4*)Ph)[i];
#pragma unroll
        for (int e = 0; e < 4; ++e) {
            float x = (float)v[e];
            x = fmaxf(x * s + h, 0.f);
            v[e] = (_Float16)x;
        }
        ((halfx4*)Ph)[i] = v;
    }
}

__global__ __launch_bounds__(256) void score_mm(
    const float* __restrict__ Hn, const float* __restrict__ x2c,
    const int* __restrict__ obj, const int* __restrict__ map,
    float* __restrict__ out)
{
    __shared__ float Asm[16][17];
    __shared__ float Bsm[16][17];
    int tx = threadIdx.x & 15, ty = threadIdx.x >> 4;
    int row = blockIdx.y * 16 + ty;
    int col = blockIdx.x * 16 + tx;
    int oj = map[obj[blockIdx.x * 16 + ty]];
    float acc = 0.f;
    for (int k0 = 0; k0 < 200; k0 += 16) {
        int k = k0 + tx;
        Asm[ty][tx] = (k < 200) ? Hn[(size_t)row * 200 + k] : 0.f;
        Bsm[ty][tx] = (k < 200) ? x2c[(size_t)oj * 200 + k] : 0.f;
        __syncthreads();
#pragma unroll
        for (int kk = 0; kk < 16; ++kk) acc = fmaf(Asm[ty][kk], Bsm[tx][kk], acc);
        __syncthreads();
    }
    out[(size_t)row * NB + col] = 1.f / (1.f + expf(-acc));
}

// ---------------------------------------------------------------- driver
extern "C" void kernel_launch(void* const* d_in, const int* in_sizes, int n_in,
                              void* d_out, int out_size, void* d_ws, size_t ws_size,
                              hipStream_t stream)
{
    (void)in_sizes; (void)n_in; (void)out_size;
    const float* init_embed = (const float*)d_in[0];
    const float* init_rel   = (const float*)d_in[1];
    const float* edge_norm  = (const float*)d_in[2];
    const float* w_in1  = (const float*)d_in[3];
    const float* w_out1 = (const float*)d_in[4];
    const float* w_loop1= (const float*)d_in[5];
    const float* w_rel1 = (const float*)d_in[6];
    const float* lrel1  = (const float*)d_in[7];
    const float* b1     = (const float*)d_in[8];
    const float* gm1    = (const float*)d_in[9];
    const float* be1    = (const float*)d_in[10];
    const float* w_in2  = (const float*)d_in[11];
    const float* w_out2 = (const float*)d_in[12];
    const float* w_loop2= (const float*)d_in[13];
    const float* w_rel2 = (const float*)d_in[14];
    const float* lrel2  = (const float*)d_in[15];
    const float* b2     = (const float*)d_in[16];
    const float* gm2    = (const float*)d_in[17];
    const float* be2    = (const float*)d_in[18];
    const float* conv_w = (const float*)d_in[19];
    const float* conv_b = (const float*)d_in[20];
    const float* fc_w   = (const float*)d_in[21];
    const float* fc_b   = (const float*)d_in[22];
    const float* bn0_g  = (const float*)d_in[23];
    const float* bn0_b  = (const float*)d_in[24];
    const float* bn1_g  = (const float*)d_in[25];
    const float* bn1_b  = (const float*)d_in[26];
    const float* bn2_g  = (const float*)d_in[27];
    const float* bn2_b  = (const float*)d_in[28];
    const int* subj   = (const int*)d_in[29];
    const int* relidx = (const int*)d_in[30];
    const int* obj    = (const int*)d_in[31];
    const int* src    = (const int*)d_in[32];
    const int* dst    = (const int*)d_in[33];
    const int* etype  = (const int*)d_in[34];

    float* ws = (float*)d_ws;
    float* R0 = ws;                 // L1: ie16 then x1f (C); L2: aggI; head: Ph
    float* R1 = ws + REGF;          // L1: aggI; then x1h (fp16)
    float* R2 = ws + 2 * REGF;      // aggO; head: fch + fpart
    float* p = ws + 3 * REGF;       // tail
    float* r1v = p;            p += 40000;
    float* r2v = p;            p += 40000;
    float* stk = p;            p += 409600;
    float* hfc = p;            p += 204800;
    float* x2c = p;            p += 409600;
    float* fsc = p;            p += 256;
    float* fsh = p;            p += 256;
    double* ds1 = (double*)p;  p += 512;
    double* ds2 = (double*)p;  p += 512;
    short* Wp = (short*)p;     p += (WP_TOTAL_SH + 1) / 2;
    int* map = (int*)p;        p += NENT;
    int* hist = (int*)p;       p += NENT;
    int* offs = (int*)p;       p += NENT + 4;
    int* cursor = (int*)p;     p += NENT;
    int* bsum = (int*)p;       p += 512;
    int4* recs = (int4*)p;     p += (size_t)NEDGE * 4;

    _Float16* ie16 = (_Float16*)R0;   // fp16 init_embed (dead after L1 gather)
    float* x1f = R0;                  // L1 gemm C (clobbers ie16 -- ok)
    short* aggI1 = (short*)R1;        // L1 agg split-bf16 (NENT x 400 shorts)
    short* aggOs = (short*)R2;        // agg-out split-bf16 (both layers)
    _Float16* x1h = (_Float16*)R1;    // fp16 x1 (aggI1 dead after L1 gemm)
    short* aggI2 = (short*)R0;        // L2 aggI (x1f dead after bn_tanh_f16)
    _Float16* Ph  = (_Float16*)R0;
    _Float16* fch = (_Float16*)R2;
    float* fpart = R2 + 4200000;

    const size_t NEED = (size_t)(p - ws) * sizeof(float);
    if (ws_size < NEED) return;

    const int NBLK = (NENT + 255) / 256;
    const size_t DSBYTES = 512 * sizeof(double);

    // -------- CSR build + slot map --------
    hipMemsetAsync(hist, 0, NENT * sizeof(int), stream);
    hipMemsetAsync(map, 0xFF, NENT * sizeof(int), stream);
    edge_hist<<<1024, 256, 0, stream>>>(dst, hist);
    scan1<<<NBLK, 256, 0, stream>>>(hist, offs, bsum);
    scan2<<<1, 512, 0, stream>>>(bsum, NBLK);
    scan3<<<NBLK, 256, 0, stream>>>(hist, offs, bsum, cursor);
    edge_fill<<<1024, 256, 0, stream>>>(src, dst, etype, edge_norm, cursor, recs);
    build_map<<<(2 * NB + 255) / 256, 256, 0, stream>>>(subj, obj, map);

    dim3 gGemm((NENT + 127) / 128, 2);
    const int PACK_BLKS = (WP_TOTAL_SH + 255) / 256;

    // -------- layer 1 --------
    pack_w3<<<PACK_BLKS, 256, 0, stream>>>(w_in1, w_out1, w_loop1, lrel1, Wp);
    to_f16<<<4096, 256, 0, stream>>>(init_embed, ie16, (long)NENT * 50);
    gather_nodes<<<(NENT + 3) / 4, 256, 0, stream>>>(ie16, init_rel, offs, recs,
                                                     aggI1, aggOs);
    hipMemsetAsync(ds1, 0, DSBYTES, stream);
    gemm_mfma<0><<<gGemm, 256, 0, stream>>>(
        aggI1, aggOs, init_embed, nullptr, Wp,
        x1f, b1, nullptr, 1.f / 3.f, NENT, ds1, ds2);
    finalize_stats<<<1, 256, 0, stream>>>(ds1, ds2, gm1, be1, fsc, fsh, 200, (double)NENT);
    bn_tanh_f16<<<4096, 256, 0, stream>>>(x1f, fsc, fsh, x1h, (long)NENT * 50);
    rel_mm<<<(40000 + 255) / 256, 256, 0, stream>>>(init_rel, w_rel1, r1v);

    // -------- layer 2 (fp16 x; compact output) --------
    pack_w3<<<PACK_BLKS, 256, 0, stream>>>(w_in2, w_out2, w_loop2, lrel2, Wp);
    gather_nodes<<<(NENT + 3) / 4, 256, 0, stream>>>(x1h, r1v, offs, recs,
                                                     aggI2, aggOs);
    hipMemsetAsync(ds1, 0, DSBYTES, stream);
    gemm_mfma<1><<<gGemm, 256, 0, stream>>>(
        aggI2, aggOs, nullptr, x1h, Wp,
        x2c, b2, map, 1.f / 3.f, NENT, ds1, ds2);
    finalize_stats<<<1, 256, 0, stream>>>(ds1, ds2, gm2, be2, fsc, fsh, 200, (double)NENT);
    bn_act_200<<<400, 256, 0, stream>>>(x2c, fsc, fsh, (long)2 * NB * 50, 0);
    rel_mm<<<(40000 + 255) / 256, 256, 0, stream>>>(r1v, w_rel2, r2v);

    // -------- ConvE head --------
    hipMemsetAsync(ds1, 0, DSBYTES, stream);
    build_stk<<<NB, 256, 0, stream>>>(x2c, r2v, subj, relidx, map, stk, ds1, ds2);
    finalize_stats<<<1, 256, 0, stream>>>(ds1, ds2, bn0_g, bn0_b, fsc, fsh, 1,
                                          (double)((long)NB * 400));
    hipMemsetAsync(ds1, 0, DSBYTES, stream);
    conv_fwd<<<NB, 256, 0, stream>>>(stk, conv_w, conv_b, fsc, fsh, Ph, ds1, ds2);
    finalize_stats<<<1, 256, 0, stream>>>(ds1, ds2, bn1_g, bn1_b, fsc, fsh, 200,
                                          (double)((long)NB * 196));
    bn1_relu_f16<<<4096, 256, 0, stream>>>(Ph, fsc, fsh);
    pack_fcw<<<(int)(((long)208 * FLATSZ + 255) / 256), 256, 0, stream>>>(fc_w, fch);
    fc_gemm<<<dim3(8, 98), 256, 0, stream>>>(Ph, fch, fpart);
    fc_reduce<<<800, 256, 0, stream>>>(fpart, fc_b, hfc);
    hipMemsetAsync(ds1, 0, DSBYTES, stream);
    colstats<<<4, 256, 0, stream>>>(hfc, NB, 256, ds1, ds2);
    finalize_stats<<<1, 256, 0, stream>>>(ds1, ds2, bn2_g, bn2_b, fsc, fsh, 200, (double)NB);
    bn_act_200<<<200, 256, 0, stream>>>(hfc, fsc, fsh, (long)NB * 50, 1);
    score_mm<<<dim3(NB / 16, NB / 16), 256, 0, stream>>>(hfc, x2c, obj, map, (float*)d_out);
}

// Round 6
// 1312.385 us; speedup vs baseline: 1.4140x; 1.0180x over previous
//
#include <hip/hip_runtime.h>

#define DIM 200
#define NENT 100000
#define NEDGE 1000000
#define EHALF 500000
#define NB 1024
#define NFILT 200
#define FLATSZ 39200

#define NDF ((size_t)NENT * DIM)
#define REGF ((size_t)20100000)

// fp16 weight panel layout: [seg:3][kc:7][row:208][chunk:4][e:8] halves,
// chunk XOR-swizzled by ((row>>1)&3) -> bank-balanced ds_read_b128 (round-5
// verified: SQ_LDS_BANK_CONFLICT == 0 with this scheme).
#define KC_H 6656              // halves per kc panel (208 rows * 32)
#define SEG_H 46592            // 7 * KC_H
#define WT_TOTAL_H 139776      // 3 * SEG_H

typedef float floatx4 __attribute__((ext_vector_type(4)));
typedef short bf16x8 __attribute__((ext_vector_type(8)));
typedef _Float16 halfx8 __attribute__((ext_vector_type(8)));
typedef _Float16 halfx4 __attribute__((ext_vector_type(4)));

__device__ __forceinline__ void gAtomicAdd(float* p, float v) { unsafeAtomicAdd(p, v); }
__device__ __forceinline__ void gAtomicAdd(double* p, double v) { unsafeAtomicAdd(p, v); }

// async global -> LDS, 16B per lane (wave-uniform LDS base + lane*16)
__device__ __forceinline__ void gload16h(const _Float16* g, _Float16* l) {
    __builtin_amdgcn_global_load_lds(
        (const __attribute__((address_space(1))) void*)g,
        (__attribute__((address_space(3))) void*)l,
        16, 0, 0);
}

// ---------------------------------------------------------------- CSR build
__global__ __launch_bounds__(256) void edge_hist(
    const int* __restrict__ dst, int* __restrict__ hist)
{
    int stride = gridDim.x * blockDim.x;
    for (int e = blockIdx.x * 256 + threadIdx.x; e < NEDGE; e += stride)
        atomicAdd(&hist[dst[e]], 1);
}

__global__ __launch_bounds__(256) void scan1(
    const int* __restrict__ hist, int* __restrict__ incl, int* __restrict__ bsum)
{
    __shared__ int sm[256];
    int i = blockIdx.x * 256 + threadIdx.x;
    int t = threadIdx.x;
    sm[t] = (i < NENT) ? hist[i] : 0;
    __syncthreads();
    for (int off = 1; off < 256; off <<= 1) {
        int v = (t >= off) ? sm[t - off] : 0;
        __syncthreads();
        sm[t] += v;
        __syncthreads();
    }
    if (i < NENT) incl[i] = sm[t];
    if (t == 255) bsum[blockIdx.x] = sm[255];
}

__global__ __launch_bounds__(512) void scan2(int* bsum, int nb)
{
    __shared__ int sm[512];
    int t = threadIdx.x;
    int v = (t < nb) ? bsum[t] : 0;
    sm[t] = v;
    __syncthreads();
    for (int off = 1; off < 512; off <<= 1) {
        int u = (t >= off) ? sm[t - off] : 0;
        __syncthreads();
        sm[t] += u;
        __syncthreads();
    }
    if (t < nb) bsum[t] = sm[t] - v;
}

__global__ __launch_bounds__(256) void scan3(
    const int* __restrict__ hist, int* __restrict__ offs,
    const int* __restrict__ bsum, int* __restrict__ cursor)
{
    int i = blockIdx.x * 256 + threadIdx.x;
    if (i < NENT) {
        int excl = offs[i] - hist[i] + bsum[blockIdx.x];
        offs[i] = excl;
        cursor[i] = excl;
    }
    if (i == 0) offs[NENT] = NEDGE;
}

__global__ __launch_bounds__(256) void edge_fill(
    const int* __restrict__ src, const int* __restrict__ dst,
    const int* __restrict__ etype, const float* __restrict__ enorm,
    int* __restrict__ cursor, int4* __restrict__ recs)
{
    int stride = gridDim.x * blockDim.x;
    for (int e = blockIdx.x * 256 + threadIdx.x; e < NEDGE; e += stride) {
        int pos = atomicAdd(&cursor[dst[e]], 1);
        recs[pos] = make_int4(src[e], etype[e] | ((e >= EHALF) ? 0x10000 : 0),
                              __float_as_int(enorm[e]), 0);
    }
}

__global__ __launch_bounds__(256) void build_map(
    const int* __restrict__ subj, const int* __restrict__ obj, int* __restrict__ map)
{
    int i = blockIdx.x * 256 + threadIdx.x;
    if (i < NB) map[subj[i]] = i;
    else if (i < 2 * NB) map[obj[i - NB]] = i;
}

// fp32 -> fp16 elementwise (x rows for the gathers / A2)
__global__ __launch_bounds__(256) void to_f16(
    const float* __restrict__ X, _Float16* __restrict__ Y, long n4)
{
    long stride = (long)gridDim.x * blockDim.x;
    for (long i = (long)blockIdx.x * blockDim.x + threadIdx.x; i < n4; i += stride) {
        float4 v = ((const float4*)X)[i];
        halfx4 h;
        h[0] = (_Float16)v.x; h[1] = (_Float16)v.y;
        h[2] = (_Float16)v.z; h[3] = (_Float16)v.w;
        ((halfx4*)Y)[i] = h;
    }
}

// ---------------------------------------------------------------- gather (2-deep pipelined, fp16 x rows)
// outputs fp16 rows (200 halves) -- GEMM A operand is fp16 now.
__global__ __launch_bounds__(256) void gather_nodes(
    const _Float16* __restrict__ x16, const float* __restrict__ r,
    const int* __restrict__ offs, const int4* __restrict__ recs,
    _Float16* __restrict__ aggI, _Float16* __restrict__ aggO)
{
    int node = blockIdx.x * 4 + (threadIdx.x >> 6);
    int lane = threadIdx.x & 63;
    if (node >= NENT) return;
    int beg = offs[node], end = offs[node + 1];
    bool act = lane < 50;
    int lane_c = min(lane, 49);
    const float4* rb = (const float4*)r;
    float4 aI = make_float4(0.f, 0.f, 0.f, 0.f);
    float4 aO = make_float4(0.f, 0.f, 0.f, 0.f);

    auto ld_x = [&](int s) -> float4 {
        halfx4 v = *(const halfx4*)&x16[(size_t)s * 200 + lane_c * 4];
        return make_float4((float)v[0], (float)v[1], (float)v[2], (float)v[3]);
    };

    if (beg < end) {
        int i1 = min(beg + 1, end - 1);
        int4 rcA = recs[beg];
        int4 rcB = recs[i1];
        float4 xvA = ld_x(rcA.x);
        float4 rvA = rb[(size_t)(rcA.y & 0xffff) * 50 + lane_c];
        for (int i = beg; i < end; ++i) {
            int i2 = min(i + 2, end - 1);
            int4 rcC = recs[i2];
            float4 xvB = ld_x(rcB.x);
            float4 rvB = rb[(size_t)(rcB.y & 0xffff) * 50 + lane_c];
            float w = __int_as_float(rcA.z);
            float wI = (rcA.y & 0x10000) ? 0.f : w;
            float wO = w - wI;
            float px = xvA.x * rvA.x, py = xvA.y * rvA.y,
                  pz = xvA.z * rvA.z, pw = xvA.w * rvA.w;
            aI.x += px * wI; aI.y += py * wI; aI.z += pz * wI; aI.w += pw * wI;
            aO.x += px * wO; aO.y += py * wO; aO.z += pz * wO; aO.w += pw * wO;
            rcA = rcB; rcB = rcC; xvA = xvB; rvA = rvB;
        }
    }
    if (act) {
        halfx4 hI, hO;
        hI[0] = (_Float16)aI.x; hI[1] = (_Float16)aI.y;
        hI[2] = (_Float16)aI.z; hI[3] = (_Float16)aI.w;
        hO[0] = (_Float16)aO.x; hO[1] = (_Float16)aO.y;
        hO[2] = (_Float16)aO.z; hO[3] = (_Float16)aO.w;
        size_t base = (size_t)node * 200 + lane * 4;
        *(halfx4*)&aggI[base] = hI;
        *(halfx4*)&aggO[base] = hO;
    }
}

// ---------------------------------------------------------------- weight packing (fp16 panel + swizzle)
// Decodes LDS-image position back to (n,k); global_load_lds copies panels
// linearly; ds_read at half_idx = row*32 + (quad ^ ((row>>1)&3))*8 is the
// correct, bank-balanced fragment.
__global__ __launch_bounds__(256) void pack_w3(
    const float* __restrict__ w0, const float* __restrict__ w1,
    const float* __restrict__ w2, const float* __restrict__ lrel,
    _Float16* __restrict__ WpP)
{
    int i = blockIdx.x * 256 + threadIdx.x;
    if (i >= WT_TOTAL_H) return;
    int seg = i / SEG_H, rem = i % SEG_H;
    int c = rem / KC_H;
    int sp = rem % KC_H;
    int rl = sp >> 5;                  // row (0..207)
    int qx = (sp >> 3) & 3;            // stored 16B-chunk slot
    int e = sp & 7;
    int q = qx ^ ((rl >> 1) & 3);      // logical k-quad held in this slot
    int n = rl;
    int k = c * 32 + q * 8 + e;
    const float* W = (seg == 0) ? w0 : (seg == 1) ? w1 : w2;
    float v = (n < 200 && k < 200) ? W[k * 200 + n] : 0.f;
    if (seg == 2 && n < 200 && k < 200) v *= lrel[k];
    WpP[i] = (_Float16)v;
}

__global__ __launch_bounds__(256) void pack_fcw(
    const float* __restrict__ W, _Float16* __restrict__ Wt)
{
    long i = (long)blockIdx.x * 256 + threadIdx.x;
    if (i >= (long)208 * FLATSZ) return;
    int n = (int)(i / FLATSZ);
    Wt[i] = (n < 200) ? (_Float16)W[i] : (_Float16)0.f;
}

// ---------------------------------------------------------------- fp16 MFMA GEMM
// Single column pass (NF=13), A read once (fp16 rows, all three segs uniform
// [row*200] layout). B panel (13312 B) double-buffered via global_load_lds
// (13 x 1024B wave-chunks), ONE __syncthreads per kc. Swizzle in pack_w3.
__global__ __launch_bounds__(256) void gemm_mfma(
    const _Float16* __restrict__ A0h, const _Float16* __restrict__ A1h,
    const _Float16* __restrict__ A2h, const _Float16* __restrict__ WpP,
    float* C, const float* __restrict__ bias, const int* __restrict__ map,
    float alpha, int M, double* __restrict__ s1, double* __restrict__ s2)
{
    constexpr int NF = 13;
    __shared__ _Float16 Bs[2 * KC_H];   // 26624 B
    __shared__ float fsum[208];
    __shared__ float fsq[208];

    int t = threadIdx.x;
    int lane = t & 63, wave = t >> 6;
    int col16 = lane & 15, quad = lane >> 4;
    int row_base = blockIdx.x * 128 + wave * 32;
    if (t < 208) { fsum[t] = 0.f; fsq[t] = 0.f; }

    floatx4 acc[NF][2];
#pragma unroll
    for (int nf = 0; nf < NF; ++nf) { acc[nf][0] = (floatx4)0.f; acc[nf][1] = (floatx4)0.f; }
    int r0 = row_base + col16, r1 = row_base + 16 + col16;
    int r0c = min(r0, M - 1), r1c = min(r1, M - 1);
    size_t b0 = (size_t)r0c * 200, b1 = (size_t)r1c * 200;

    halfx8 ca0, ca1, na0, na1;

    auto gload = [&](int kc, int bufi) {
        int seg = kc / 7, c = kc - seg * 7;
        const _Float16* g = WpP + seg * SEG_H + c * KC_H + lane * 8;
        _Float16* l = Bs + bufi * KC_H;
        for (int cc = wave; cc < 13; cc += 4)
            gload16h(g + cc * 512, l + cc * 512);
    };
    auto loadA = [&](int kc, halfx8& a0, halfx8& a1) {
        int seg = kc / 7, c = kc - seg * 7;
        int koff = c * 32 + quad * 8;
        if (koff < 200) {
            const _Float16* A = (seg == 0) ? A0h : (seg == 1) ? A1h : A2h;
            a0 = *(const halfx8*)&A[b0 + koff];
            a1 = *(const halfx8*)&A[b1 + koff];
        } else {
            a0 = (halfx8)0; a1 = (halfx8)0;
        }
    };
    auto do_mfma = [&](int bufi) {
        const _Float16* P = Bs + bufi * KC_H;
        __builtin_amdgcn_s_setprio(1);
#pragma unroll
        for (int nf = 0; nf < NF; ++nf) {
            int rl = nf * 16 + col16;
            int qs = quad ^ ((rl >> 1) & 3);
            halfx8 b = *(const halfx8*)&P[rl * 32 + qs * 8];
            acc[nf][0] = __builtin_amdgcn_mfma_f32_16x16x32_f16(ca0, b, acc[nf][0], 0, 0, 0);
            acc[nf][1] = __builtin_amdgcn_mfma_f32_16x16x32_f16(ca1, b, acc[nf][1], 0, 0, 0);
        }
        __builtin_amdgcn_s_setprio(0);
    };

    // prologue: panel 0 -> buf 0, A(0) -> regs; barrier publishes panel 0
    gload(0, 0);
    loadA(0, ca0, ca1);
    __syncthreads();

    for (int kc = 0; kc < 21; ++kc) {
        if (kc < 20) {
            gload(kc + 1, (kc + 1) & 1);    // async into other buffer
            loadA(kc + 1, na0, na1);        // HBM prefetch into regs
        }
        do_mfma(kc & 1);
        __syncthreads();   // publishes panel kc+1; proves buf free for kc+2
        ca0 = na0; ca1 = na1;
    }

    int slot[2][4];
    if (map) {
#pragma unroll
        for (int h = 0; h < 2; ++h)
#pragma unroll
            for (int j = 0; j < 4; ++j) {
                int rr = row_base + h * 16 + quad * 4 + j;
                slot[h][j] = (rr < M) ? map[rr] : -1;
            }
    }
#pragma unroll
    for (int nf = 0; nf < NF; ++nf) {
        int lc = nf * 16 + col16;
        int colg = lc;
        if (colg >= 200) continue;
        float bv = bias[colg];
        float ls = 0.f, lq = 0.f;
#pragma unroll
        for (int h = 0; h < 2; ++h) {
            int rbase = row_base + h * 16 + quad * 4;
#pragma unroll
            for (int j = 0; j < 4; ++j) {
                int rr = rbase + j;
                if (rr < M) {
                    float v = acc[nf][h][j] * alpha + bv;
                    ls += v; lq += v * v;
                    if (!map) {
                        C[(size_t)rr * 200 + colg] = v;
                    } else {
                        int s = slot[h][j];
                        if (s >= 0) C[(size_t)s * 200 + colg] = v;
                    }
                }
            }
        }
        ls += __shfl_down(ls, 32); ls += __shfl_down(ls, 16);
        lq += __shfl_down(lq, 32); lq += __shfl_down(lq, 16);
        if (quad == 0) {
            atomicAdd(&fsum[lc], ls);
            atomicAdd(&fsq[lc], lq);
        }
    }
    __syncthreads();
    if (t < 200) {
        gAtomicAdd(&s1[t], (double)fsum[t]);
        gAtomicAdd(&s2[t], (double)fsq[t]);
    }
}

// ---------------------------------------------------------------- fc MFMA GEMM body (fp16)
template<int NF0, int NF>
__device__ __forceinline__ void fc_gemm_body(
    const _Float16* __restrict__ Ph, const _Float16* __restrict__ Wt,
    float* __restrict__ part, int ky, _Float16* Bs)
{
    int t = threadIdx.x;
    int lane = t & 63, wave = t >> 6;
    int col16 = lane & 15, quad = lane >> 4;
    int row_base = blockIdx.x * 128 + wave * 32;
    int c0 = ky * 25;
    floatx4 acc[NF][2];
#pragma unroll
    for (int nf = 0; nf < NF; ++nf) { acc[nf][0] = (floatx4)0.f; acc[nf][1] = (floatx4)0.f; }
    int r0 = row_base + col16, r1 = row_base + 16 + col16;
    const int rows4 = NF * 16 * 4;

    for (int c = c0; c < c0 + 25; ++c) {
        int k0 = c * 32;
        for (int i = t; i < rows4; i += 256) {
            int nl = i >> 2, part_i = i & 3;
            int n = NF0 * 16 + nl;
            *(halfx8*)&Bs[nl * 40 + part_i * 8] =
                *(const halfx8*)&Wt[(size_t)n * FLATSZ + k0 + part_i * 8];
        }
        __syncthreads();
        int koff = k0 + quad * 8;
        halfx8 a0 = *(const halfx8*)&Ph[(size_t)r0 * FLATSZ + koff];
        halfx8 a1 = *(const halfx8*)&Ph[(size_t)r1 * FLATSZ + koff];
#pragma unroll
        for (int nf = 0; nf < NF; ++nf) {
            halfx8 b = *(const halfx8*)&Bs[(nf * 16 + col16) * 40 + quad * 8];
            acc[nf][0] = __builtin_amdgcn_mfma_f32_16x16x32_f16(a0, b, acc[nf][0], 0, 0, 0);
            acc[nf][1] = __builtin_amdgcn_mfma_f32_16x16x32_f16(a1, b, acc[nf][1], 0, 0, 0);
        }
        __syncthreads();
    }
    float* out = part + (size_t)ky * (NB * 200);
#pragma unroll
    for (int nf = 0; nf < NF; ++nf) {
        int colg = NF0 * 16 + nf * 16 + col16;
        if (colg >= 200) continue;
#pragma unroll
        for (int h = 0; h < 2; ++h) {
            int rbase = row_base + h * 16 + quad * 4;
#pragma unroll
            for (int j = 0; j < 4; ++j)
                out[(size_t)(rbase + j) * 200 + colg] = acc[nf][h][j];
        }
    }
}

__global__ __launch_bounds__(256) void fc_gemm(
    const _Float16* __restrict__ Ph, const _Float16* __restrict__ Wt,
    float* __restrict__ part)
{
    __shared__ _Float16 Bs[112 * 40];
    int ky = blockIdx.y >> 1;
    if ((blockIdx.y & 1) == 0)
        fc_gemm_body<0, 7>(Ph, Wt, part, ky, Bs);
    else
        fc_gemm_body<7, 6>(Ph, Wt, part, ky, Bs);
}

__global__ __launch_bounds__(256) void fc_reduce(
    const float* __restrict__ part, const float* __restrict__ bias,
    float* __restrict__ hfc)
{
    int i = blockIdx.x * 256 + threadIdx.x;
    float acc = bias[i % 200];
#pragma unroll
    for (int y = 0; y < 49; ++y) acc += part[(size_t)y * (NB * 200) + i];
    hfc[i] = acc;
}

// ---------------------------------------------------------------- stats / bn
__global__ __launch_bounds__(256) void colstats(
    const float* __restrict__ X, int M, int rpb,
    double* __restrict__ s1, double* __restrict__ s2)
{
    int c = threadIdx.x;
    if (c >= 200) return;
    int r0 = blockIdx.x * rpb;
    int r1 = min(r0 + rpb, M);
    float sum = 0.f, sq = 0.f;
    for (int rr = r0; rr < r1; ++rr) {
        float v = X[(size_t)rr * 200 + c];
        sum += v; sq += v * v;
    }
    gAtomicAdd(&s1[c], (double)sum);
    gAtomicAdd(&s2[c], (double)sq);
}

__global__ void finalize_stats(const double* __restrict__ s1, const double* __restrict__ s2,
                               const float* __restrict__ g, const float* __restrict__ bb,
                               float* __restrict__ sc, float* __restrict__ sh,
                               int ncols, double count)
{
    int c = threadIdx.x;
    if (c >= ncols) return;
    double m = s1[c] / count;
    double v = s2[c] / count - m * m;
    double scd = (double)g[c] / sqrt(v + 1e-5);
    sc[c] = (float)scd;
    sh[c] = (float)((double)bb[c] - m * scd);
}

// bn + tanh, fp32 in -> fp16 out (layer-1 x for gather + gemm A2)
__global__ __launch_bounds__(256) void bn_tanh_f16(
    const float* __restrict__ X, const float* __restrict__ sc,
    const float* __restrict__ sh, _Float16* __restrict__ Y, long n4)
{
    long stride = (long)gridDim.x * blockDim.x;
    for (long i = (long)blockIdx.x * blockDim.x + threadIdx.x; i < n4; i += stride) {
        int c4 = (int)(i % 50) * 4;
        float4 v = ((const float4*)X)[i];
        halfx4 h;
        h[0] = (_Float16)tanhf(v.x * sc[c4 + 0] + sh[c4 + 0]);
        h[1] = (_Float16)tanhf(v.y * sc[c4 + 1] + sh[c4 + 1]);
        h[2] = (_Float16)tanhf(v.z * sc[c4 + 2] + sh[c4 + 2]);
        h[3] = (_Float16)tanhf(v.w * sc[c4 + 3] + sh[c4 + 3]);
        ((halfx4*)Y)[i] = h;
    }
}

__global__ __launch_bounds__(256) void bn_act_200(
    float* __restrict__ X, const float* __restrict__ sc, const float* __restrict__ sh,
    long n4, int act)
{
    long stride = (long)gridDim.x * blockDim.x;
    for (long i = (long)blockIdx.x * blockDim.x + threadIdx.x; i < n4; i += stride) {
        int c4 = (int)(i % 50) * 4;
        float4 v = ((const float4*)X)[i];
        float a0 = v.x * sc[c4 + 0] + sh[c4 + 0];
        float a1 = v.y * sc[c4 + 1] + sh[c4 + 1];
        float a2 = v.z * sc[c4 + 2] + sh[c4 + 2];
        float a3 = v.w * sc[c4 + 3] + sh[c4 + 3];
        if (act == 0) { a0 = tanhf(a0); a1 = tanhf(a1); a2 = tanhf(a2); a3 = tanhf(a3); }
        else { a0 = fmaxf(a0, 0.f); a1 = fmaxf(a1, 0.f); a2 = fmaxf(a2, 0.f); a3 = fmaxf(a3, 0.f); }
        ((float4*)X)[i] = make_float4(a0, a1, a2, a3);
    }
}

__global__ __launch_bounds__(256) void rel_mm(
    const float* __restrict__ R, const float* __restrict__ W, float* __restrict__ O)
{
    int idx = blockIdx.x * blockDim.x + threadIdx.x;
    if (idx >= 200 * 200) return;
    int row = idx / 200, col = idx - row * 200;
    float acc = 0.f;
    for (int k = 0; k < 200; ++k) acc = fmaf(R[row * 200 + k], W[k * 200 + col], acc);
    O[idx] = acc;
}

__global__ __launch_bounds__(256) void build_stk(
    const float* __restrict__ x2c, const float* __restrict__ r2,
    const int* __restrict__ subj, const int* __restrict__ ridx,
    const int* __restrict__ map,
    float* __restrict__ stk, double* __restrict__ s1, double* __restrict__ s2)
{
    __shared__ float wsum[4], wsq[4];
    int b = blockIdx.x, t = threadIdx.x;
    const float* se = x2c + (size_t)map[subj[b]] * DIM;
    const float* re = r2 + (size_t)ridx[b] * DIM;
    float sum = 0.f, sq = 0.f;
    for (int i = t; i < 400; i += 256) {
        float v = (i < 200) ? se[i] : re[i - 200];
        stk[(size_t)b * 400 + i] = v;
        sum += v; sq += v * v;
    }
    for (int off = 32; off > 0; off >>= 1) {
        sum += __shfl_down(sum, off);
        sq  += __shfl_down(sq, off);
    }
    if ((t & 63) == 0) { wsum[t >> 6] = sum; wsq[t >> 6] = sq; }
    __syncthreads();
    if (t == 0) {
        float S = wsum[0] + wsum[1] + wsum[2] + wsum[3];
        float Q = wsq[0] + wsq[1] + wsq[2] + wsq[3];
        gAtomicAdd(&s1[0], (double)S);
        gAtomicAdd(&s2[0], (double)Q);
    }
}

__global__ __launch_bounds__(256) void conv_fwd(
    const float* __restrict__ stk, const float* __restrict__ conv_w,
    const float* __restrict__ conv_b, const float* __restrict__ sc0,
    const float* __restrict__ sh0, _Float16* __restrict__ Ph,
    double* __restrict__ s1, double* __restrict__ s2)
{
    __shared__ float img[400];
    __shared__ float wsm[9800];
    __shared__ float bsm[200];
    __shared__ float fsum[200];
    __shared__ float fsq[200];
    int b = blockIdx.x, t = threadIdx.x;
    float scale0 = sc0[0], shift0 = sh0[0];
    if (t < 200) { fsum[t] = 0.f; fsq[t] = 0.f; bsm[t] = conv_b[t]; }
    for (int i = t; i < 400; i += 256) img[i] = stk[(size_t)b * 400 + i] * scale0 + shift0;
    for (int i = t; i < 9800; i += 256) wsm[i] = conv_w[i];
    __syncthreads();
    for (int fy = t; fy < 2800; fy += 256) {
        int f = fy / 14, y = fy - (fy / 14) * 14;
        const float* wf = &wsm[f * 49];
        float acc[14];
        float bias = bsm[f];
#pragma unroll
        for (int xx = 0; xx < 14; ++xx) acc[xx] = bias;
#pragma unroll
        for (int i = 0; i < 7; ++i) {
            const float* rowp = &img[(y + i) * 20];
            float rv[20];
#pragma unroll
            for (int c = 0; c < 20; ++c) rv[c] = rowp[c];
#pragma unroll
            for (int j = 0; j < 7; ++j) {
                float wv = wf[i * 7 + j];
#pragma unroll
                for (int xx = 0; xx < 14; ++xx) acc[xx] = fmaf(rv[xx + j], wv, acc[xx]);
            }
        }
        float ls = 0.f, lq = 0.f;
        _Float16* pp = Ph + (size_t)b * FLATSZ + (size_t)f * 196 + y * 14;
#pragma unroll
        for (int xx = 0; xx < 14; ++xx) {
            float v = acc[xx];
            pp[xx] = (_Float16)v;
            ls += v; lq += v * v;
        }
        atomicAdd(&fsum[f], ls);
        atomicAdd(&fsq[f], lq);
    }
    __syncthreads();
    if (t < 200) {
        gAtomicAdd(&s1[t], (double)fsum[t]);
        gAtomicAdd(&s2[t], (double)fsq[t]);
    }
}

__global__ __launch_bounds__(256) void bn1_relu_f16(
    _Float16* __restrict__ Ph, const float* __restrict__ sc, const float* __restrict__ sh)
{
    long n4 = (long)NB * (FLATSZ / 4);
    long stride = (long)gridDim.x * blockDim.x;
    for (long i = (long)blockIdx.x * blockDim.x + threadIdx.x; i < n4; i += stride) {
        int k4 = (int)(i % (FLATSZ / 4));
        int f = k4 / 49;
        float s = sc[f], h = sh[f];
        halfx4 v = ((const halfx4*)Ph)[i];
#pragma unroll
        for (int e = 0; e < 4; ++e) {
            float x = (float)v[e];
            x = fmaxf(x * s + h, 0.f);
            v[e] = (_Float16)x;
        }
        ((halfx4*)Ph)[i] = v;
    }
}

__global__ __launch_bounds__(256) void score_mm(
    const float* __restrict__ Hn, const float* __restrict__ x2c,
    const int* __restrict__ obj, const int* __restrict__ map,
    float* __restrict__ out)
{
    __shared__ float Asm[16][17];
    __shared__ float Bsm[16][17];
    int tx = threadIdx.x & 15, ty = threadIdx.x >> 4;
    int row = blockIdx.y * 16 + ty;
    int col = blockIdx.x * 16 + tx;
    int oj = map[obj[blockIdx.x * 16 + ty]];
    float acc = 0.f;
    for (int k0 = 0; k0 < 200; k0 += 16) {
        int k = k0 + tx;
        Asm[ty][tx] = (k < 200) ? Hn[(size_t)row * 200 + k] : 0.f;
        Bsm[ty][tx] = (k < 200) ? x2c[(size_t)oj * 200 + k] : 0.f;
        __syncthreads();
#pragma unroll
        for (int kk = 0; kk < 16; ++kk) acc = fmaf(Asm[ty][kk], Bsm[tx][kk], acc);
        __syncthreads();
    }
    out[(size_t)row * NB + col] = 1.f / (1.f + expf(-acc));
}

// ---------------------------------------------------------------- driver
extern "C" void kernel_launch(void* const* d_in, const int* in_sizes, int n_in,
                              void* d_out, int out_size, void* d_ws, size_t ws_size,
                              hipStream_t stream)
{
    (void)in_sizes; (void)n_in; (void)out_size;
    const float* init_embed = (const float*)d_in[0];
    const float* init_rel   = (const float*)d_in[1];
    const float* edge_norm  = (const float*)d_in[2];
    const float* w_in1  = (const float*)d_in[3];
    const float* w_out1 = (const float*)d_in[4];
    const float* w_loop1= (const float*)d_in[5];
    const float* w_rel1 = (const float*)d_in[6];
    const float* lrel1  = (const float*)d_in[7];
    const float* b1     = (const float*)d_in[8];
    const float* gm1    = (const float*)d_in[9];
    const float* be1    = (const float*)d_in[10];
    const float* w_in2  = (const float*)d_in[11];
    const float* w_out2 = (const float*)d_in[12];
    const float* w_loop2= (const float*)d_in[13];
    const float* w_rel2 = (const float*)d_in[14];
    const float* lrel2  = (const float*)d_in[15];
    const float* b2     = (const float*)d_in[16];
    const float* gm2    = (const float*)d_in[17];
    const float* be2    = (const float*)d_in[18];
    const float* conv_w = (const float*)d_in[19];
    const float* conv_b = (const float*)d_in[20];
    const float* fc_w   = (const float*)d_in[21];
    const float* fc_b   = (const float*)d_in[22];
    const float* bn0_g  = (const float*)d_in[23];
    const float* bn0_b  = (const float*)d_in[24];
    const float* bn1_g  = (const float*)d_in[25];
    const float* bn1_b  = (const float*)d_in[26];
    const float* bn2_g  = (const float*)d_in[27];
    const float* bn2_b  = (const float*)d_in[28];
    const int* subj   = (const int*)d_in[29];
    const int* relidx = (const int*)d_in[30];
    const int* obj    = (const int*)d_in[31];
    const int* src    = (const int*)d_in[32];
    const int* dst    = (const int*)d_in[33];
    const int* etype  = (const int*)d_in[34];

    float* ws = (float*)d_ws;
    float* R0 = ws;                 // L1: x1f (C); L2: aggI2; head: Ph
    float* R1 = ws + REGF;          // L1: aggI1 (1st half) + ie16 (2nd half); then x1h
    float* R2 = ws + 2 * REGF;      // aggO (both layers); head: fch + fpart
    float* p = ws + 3 * REGF;       // tail
    float* r1v = p;            p += 40000;
    float* r2v = p;            p += 40000;
    float* stk = p;            p += 409600;
    float* hfc = p;            p += 204800;
    float* x2c = p;            p += 409600;
    float* fsc = p;            p += 256;
    float* fsh = p;            p += 256;
    double* ds1 = (double*)p;  p += 512;
    double* ds2 = (double*)p;  p += 512;
    _Float16* Wp = (_Float16*)p; p += (WT_TOTAL_H + 1) / 2;
    int* map = (int*)p;        p += NENT;
    int* hist = (int*)p;       p += NENT;
    int* offs = (int*)p;       p += NENT + 4;
    int* cursor = (int*)p;     p += NENT;
    int* bsum = (int*)p;       p += 512;
    int4* recs = (int4*)p;     p += (size_t)NEDGE * 4;

    float* x1f = R0;                           // L1 gemm C (fp32)
    _Float16* aggI1 = (_Float16*)R1;           // L1 aggI (fp16, 20M halves)
    _Float16* ie16  = (_Float16*)(R1 + 10050000); // fp16 init_embed (A2 for L1)
    _Float16* aggOh = (_Float16*)R2;           // agg-out fp16 (both layers)
    _Float16* x1h = (_Float16*)R1;             // fp16 x1 (aggI1/ie16 dead after L1 gemm)
    _Float16* aggI2 = (_Float16*)R0;           // L2 aggI (x1f dead after bn_tanh_f16)
    _Float16* Ph  = (_Float16*)R0;
    _Float16* fch = (_Float16*)R2;
    float* fpart = R2 + 4200000;

    const size_t NEED = (size_t)(p - ws) * sizeof(float);
    if (ws_size < NEED) return;

    const int NBLK = (NENT + 255) / 256;
    const size_t DSBYTES = 512 * sizeof(double);

    // -------- CSR build + slot map --------
    hipMemsetAsync(hist, 0, NENT * sizeof(int), stream);
    hipMemsetAsync(map, 0xFF, NENT * sizeof(int), stream);
    edge_hist<<<1024, 256, 0, stream>>>(dst, hist);
    scan1<<<NBLK, 256, 0, stream>>>(hist, offs, bsum);
    scan2<<<1, 512, 0, stream>>>(bsum, NBLK);
    scan3<<<NBLK, 256, 0, stream>>>(hist, offs, bsum, cursor);
    edge_fill<<<1024, 256, 0, stream>>>(src, dst, etype, edge_norm, cursor, recs);
    build_map<<<(2 * NB + 255) / 256, 256, 0, stream>>>(subj, obj, map);

    dim3 gGemm((NENT + 127) / 128);
    const int PACK_BLKS = (WT_TOTAL_H + 255) / 256;

    // -------- layer 1 --------
    pack_w3<<<PACK_BLKS, 256, 0, stream>>>(w_in1, w_out1, w_loop1, lrel1, Wp);
    to_f16<<<4096, 256, 0, stream>>>(init_embed, ie16, (long)NENT * 50);
    gather_nodes<<<(NENT + 3) / 4, 256, 0, stream>>>(ie16, init_rel, offs, recs,
                                                     aggI1, aggOh);
    hipMemsetAsync(ds1, 0, DSBYTES, stream);
    gemm_mfma<<<gGemm, 256, 0, stream>>>(
        aggI1, aggOh, ie16, Wp,
        x1f, b1, nullptr, 1.f / 3.f, NENT, ds1, ds2);
    finalize_stats<<<1, 256, 0, stream>>>(ds1, ds2, gm1, be1, fsc, fsh, 200, (double)NENT);
    bn_tanh_f16<<<4096, 256, 0, stream>>>(x1f, fsc, fsh, x1h, (long)NENT * 50);
    rel_mm<<<(40000 + 255) / 256, 256, 0, stream>>>(init_rel, w_rel1, r1v);

    // -------- layer 2 (fp16 x; compact output) --------
    pack_w3<<<PACK_BLKS, 256, 0, stream>>>(w_in2, w_out2, w_loop2, lrel2, Wp);
    gather_nodes<<<(NENT + 3) / 4, 256, 0, stream>>>(x1h, r1v, offs, recs,
                                                     aggI2, aggOh);
    hipMemsetAsync(ds1, 0, DSBYTES, stream);
    gemm_mfma<<<gGemm, 256, 0, stream>>>(
        aggI2, aggOh, x1h, Wp,
        x2c, b2, map, 1.f / 3.f, NENT, ds1, ds2);
    finalize_stats<<<1, 256, 0, stream>>>(ds1, ds2, gm2, be2, fsc, fsh, 200, (double)NENT);
    bn_act_200<<<400, 256, 0, stream>>>(x2c, fsc, fsh, (long)2 * NB * 50, 0);
    rel_mm<<<(40000 + 255) / 256, 256, 0, stream>>>(r1v, w_rel2, r2v);

    // -------- ConvE head --------
    hipMemsetAsync(ds1, 0, DSBYTES, stream);
    build_stk<<<NB, 256, 0, stream>>>(x2c, r2v, subj, relidx, map, stk, ds1, ds2);
    finalize_stats<<<1, 256, 0, stream>>>(ds1, ds2, bn0_g, bn0_b, fsc, fsh, 1,
                                          (double)((long)NB * 400));
    hipMemsetAsync(ds1, 0, DSBYTES, stream);
    conv_fwd<<<NB, 256, 0, stream>>>(stk, conv_w, conv_b, fsc, fsh, Ph, ds1, ds2);
    finalize_stats<<<1, 256, 0, stream>>>(ds1, ds2, bn1_g, bn1_b, fsc, fsh, 200,
                                          (double)((long)NB * 196));
    bn1_relu_f16<<<4096, 256, 0, stream>>>(Ph, fsc, fsh);
    pack_fcw<<<(int)(((long)208 * FLATSZ + 255) / 256), 256, 0, stream>>>(fc_w, fch);
    fc_gemm<<<dim3(8, 98), 256, 0, stream>>>(Ph, fch, fpart);
    fc_reduce<<<800, 256, 0, stream>>>(fpart, fc_b, hfc);
    hipMemsetAsync(ds1, 0, DSBYTES, stream);
    colstats<<<4, 256, 0, stream>>>(hfc, NB, 256, ds1, ds2);
    finalize_stats<<<1, 256, 0, stream>>>(ds1, ds2, bn2_g, bn2_b, fsc, fsh, 200, (double)NB);
    bn_act_200<<<200, 256, 0, stream>>>(hfc, fsc, fsh, (long)NB * 50, 1);
    score_mm<<<dim3(NB / 16, NB / 16), 256, 0, stream>>>(hfc, x2c, obj, map, (float*)d_out);
}

// Round 7
// 1071.146 us; speedup vs baseline: 1.7325x; 1.2252x over previous
//
#include <hip/hip_runtime.h>

#define DIM 200
#define NENT 100000
#define NEDGE 1000000
#define EHALF 500000
#define NB 1024
#define NFILT 200
#define FLATSZ 39200

#define NDF ((size_t)NENT * DIM)
#define REGF ((size_t)20100000)

// fp16 weight panel image: 21 panels (seg*7+c), each 6656 halves:
//   [y0: rows 0..111][y1: rows 0..95], row = 32 halves, 16B-chunk index
//   XOR-swizzled by ((row>>1)&3)  (round-5/6 verified: 0 bank conflicts).
#define PANEL_TOT_H 6656
#define Y1OFF_H 3584
#define WT_TOTAL_H 139776      // 21 * 6656

typedef float floatx4 __attribute__((ext_vector_type(4)));
typedef _Float16 halfx8 __attribute__((ext_vector_type(8)));
typedef _Float16 halfx4 __attribute__((ext_vector_type(4)));

__device__ __forceinline__ void gAtomicAdd(float* p, float v) { unsafeAtomicAdd(p, v); }
__device__ __forceinline__ void gAtomicAdd(double* p, double v) { unsafeAtomicAdd(p, v); }

// async global -> LDS, 16B per lane (wave-uniform LDS base + lane*16)
__device__ __forceinline__ void gload16h(const _Float16* g, _Float16* l) {
    __builtin_amdgcn_global_load_lds(
        (const __attribute__((address_space(1))) void*)g,
        (__attribute__((address_space(3))) void*)l,
        16, 0, 0);
}

// ---------------------------------------------------------------- CSR build
__global__ __launch_bounds__(256) void edge_hist(
    const int* __restrict__ dst, int* __restrict__ hist)
{
    int stride = gridDim.x * blockDim.x;
    for (int e = blockIdx.x * 256 + threadIdx.x; e < NEDGE; e += stride)
        atomicAdd(&hist[dst[e]], 1);
}

__global__ __launch_bounds__(256) void scan1(
    const int* __restrict__ hist, int* __restrict__ incl, int* __restrict__ bsum)
{
    __shared__ int sm[256];
    int i = blockIdx.x * 256 + threadIdx.x;
    int t = threadIdx.x;
    sm[t] = (i < NENT) ? hist[i] : 0;
    __syncthreads();
    for (int off = 1; off < 256; off <<= 1) {
        int v = (t >= off) ? sm[t - off] : 0;
        __syncthreads();
        sm[t] += v;
        __syncthreads();
    }
    if (i < NENT) incl[i] = sm[t];
    if (t == 255) bsum[blockIdx.x] = sm[255];
}

__global__ __launch_bounds__(512) void scan2(int* bsum, int nb)
{
    __shared__ int sm[512];
    int t = threadIdx.x;
    int v = (t < nb) ? bsum[t] : 0;
    sm[t] = v;
    __syncthreads();
    for (int off = 1; off < 512; off <<= 1) {
        int u = (t >= off) ? sm[t - off] : 0;
        __syncthreads();
        sm[t] += u;
        __syncthreads();
    }
    if (t < nb) bsum[t] = sm[t] - v;
}

__global__ __launch_bounds__(256) void scan3(
    const int* __restrict__ hist, int* __restrict__ offs,
    const int* __restrict__ bsum, int* __restrict__ cursor)
{
    int i = blockIdx.x * 256 + threadIdx.x;
    if (i < NENT) {
        int excl = offs[i] - hist[i] + bsum[blockIdx.x];
        offs[i] = excl;
        cursor[i] = excl;
    }
    if (i == 0) offs[NENT] = NEDGE;
}

__global__ __launch_bounds__(256) void edge_fill(
    const int* __restrict__ src, const int* __restrict__ dst,
    const int* __restrict__ etype, const float* __restrict__ enorm,
    int* __restrict__ cursor, int4* __restrict__ recs)
{
    int stride = gridDim.x * blockDim.x;
    for (int e = blockIdx.x * 256 + threadIdx.x; e < NEDGE; e += stride) {
        int pos = atomicAdd(&cursor[dst[e]], 1);
        recs[pos] = make_int4(src[e], etype[e] | ((e >= EHALF) ? 0x10000 : 0),
                              __float_as_int(enorm[e]), 0);
    }
}

__global__ __launch_bounds__(256) void build_map(
    const int* __restrict__ subj, const int* __restrict__ obj, int* __restrict__ map)
{
    int i = blockIdx.x * 256 + threadIdx.x;
    if (i < NB) map[subj[i]] = i;
    else if (i < 2 * NB) map[obj[i - NB]] = i;
}

// fp32 -> fp16 elementwise (x rows for the gathers / A2)
__global__ __launch_bounds__(256) void to_f16(
    const float* __restrict__ X, _Float16* __restrict__ Y, long n4)
{
    long stride = (long)gridDim.x * blockDim.x;
    for (long i = (long)blockIdx.x * blockDim.x + threadIdx.x; i < n4; i += stride) {
        float4 v = ((const float4*)X)[i];
        halfx4 h;
        h[0] = (_Float16)v.x; h[1] = (_Float16)v.y;
        h[2] = (_Float16)v.z; h[3] = (_Float16)v.w;
        ((halfx4*)Y)[i] = h;
    }
}

// ---------------------------------------------------------------- gather (2-deep pipelined, fp16 x rows)
__global__ __launch_bounds__(256) void gather_nodes(
    const _Float16* __restrict__ x16, const float* __restrict__ r,
    const int* __restrict__ offs, const int4* __restrict__ recs,
    _Float16* __restrict__ aggI, _Float16* __restrict__ aggO)
{
    int node = blockIdx.x * 4 + (threadIdx.x >> 6);
    int lane = threadIdx.x & 63;
    if (node >= NENT) return;
    int beg = offs[node], end = offs[node + 1];
    bool act = lane < 50;
    int lane_c = min(lane, 49);
    const float4* rb = (const float4*)r;
    float4 aI = make_float4(0.f, 0.f, 0.f, 0.f);
    float4 aO = make_float4(0.f, 0.f, 0.f, 0.f);

    auto ld_x = [&](int s) -> float4 {
        halfx4 v = *(const halfx4*)&x16[(size_t)s * 200 + lane_c * 4];
        return make_float4((float)v[0], (float)v[1], (float)v[2], (float)v[3]);
    };

    if (beg < end) {
        int i1 = min(beg + 1, end - 1);
        int4 rcA = recs[beg];
        int4 rcB = recs[i1];
        float4 xvA = ld_x(rcA.x);
        float4 rvA = rb[(size_t)(rcA.y & 0xffff) * 50 + lane_c];
        for (int i = beg; i < end; ++i) {
            int i2 = min(i + 2, end - 1);
            int4 rcC = recs[i2];
            float4 xvB = ld_x(rcB.x);
            float4 rvB = rb[(size_t)(rcB.y & 0xffff) * 50 + lane_c];
            float w = __int_as_float(rcA.z);
            float wI = (rcA.y & 0x10000) ? 0.f : w;
            float wO = w - wI;
            float px = xvA.x * rvA.x, py = xvA.y * rvA.y,
                  pz = xvA.z * rvA.z, pw = xvA.w * rvA.w;
            aI.x += px * wI; aI.y += py * wI; aI.z += pz * wI; aI.w += pw * wI;
            aO.x += px * wO; aO.y += py * wO; aO.z += pz * wO; aO.w += pw * wO;
            rcA = rcB; rcB = rcC; xvA = xvB; rvA = rvB;
        }
    }
    if (act) {
        halfx4 hI, hO;
        hI[0] = (_Float16)aI.x; hI[1] = (_Float16)aI.y;
        hI[2] = (_Float16)aI.z; hI[3] = (_Float16)aI.w;
        hO[0] = (_Float16)aO.x; hO[1] = (_Float16)aO.y;
        hO[2] = (_Float16)aO.z; hO[3] = (_Float16)aO.w;
        size_t base = (size_t)node * 200 + lane * 4;
        *(halfx4*)&aggI[base] = hI;
        *(halfx4*)&aggO[base] = hO;
    }
}

// ---------------------------------------------------------------- weight packing (fp16 panel + swizzle)
__global__ __launch_bounds__(256) void pack_w3(
    const float* __restrict__ w0, const float* __restrict__ w1,
    const float* __restrict__ w2, const float* __restrict__ lrel,
    _Float16* __restrict__ WpP)
{
    int i = blockIdx.x * 256 + threadIdx.x;
    if (i >= WT_TOTAL_H) return;
    int p = i / PANEL_TOT_H;
    int r = i % PANEL_TOT_H;
    int y = (r >= Y1OFF_H) ? 1 : 0;
    int rr = y ? (r - Y1OFF_H) : r;
    int rl = rr >> 5;
    int qx = (rr >> 3) & 3;
    int e = rr & 7;
    int q = qx ^ ((rl >> 1) & 3);
    int n = y * 112 + rl;
    int seg = p / 7, c = p - seg * 7;
    int k = c * 32 + q * 8 + e;
    const float* W = (seg == 0) ? w0 : (seg == 1) ? w1 : w2;
    float v = (n < 200 && k < 200) ? W[k * 200 + n] : 0.f;
    if (seg == 2 && n < 200 && k < 200) v *= lrel[k];
    WpP[i] = (_Float16)v;
}

__global__ __launch_bounds__(256) void pack_fcw(
    const float* __restrict__ W, _Float16* __restrict__ Wt)
{
    long i = (long)blockIdx.x * 256 + threadIdx.x;
    if (i >= (long)208 * FLATSZ) return;
    int n = (int)(i / FLATSZ);
    Wt[i] = (n < 200) ? (_Float16)W[i] : (_Float16)0.f;
}

// ---------------------------------------------------------------- fp16 MFMA GEMM, barrier-free K loop
// One block per CU (grid 256), 16 waves, one column-half (Y=0: cols 0-111
// NF=7; Y=1: cols 112-207 NF=6). Block stages one SEG of its half (50/43 KB)
// into LDS, double-buffered across segs (3 barriers total). Each wave owns at
// most ONE 32-row tile (4096 waves >= 3125 tiles), acc lives across the whole
// kernel, A register-prefetched 1 kc ahead. No per-kc barriers at all.
template<int Y>
__global__ __launch_bounds__(1024) void gemm_big(
    const _Float16* __restrict__ A0h, const _Float16* __restrict__ A1h,
    const _Float16* __restrict__ A2h, const _Float16* __restrict__ WpP,
    float* __restrict__ C, const float* __restrict__ bias,
    const int* __restrict__ map, float alpha,
    double* __restrict__ s1, double* __restrict__ s2)
{
    constexpr int NF = Y ? 6 : 7;
    constexpr int PC = NF;                   // 1KB chunks per panel
    constexpr int PANEL_H = NF * 512;        // halves per panel (3584/3072)
    constexpr int YOFF_H = Y ? Y1OFF_H : 0;
    constexpr int SEG_LDS_H = 7 * PANEL_H;   // halves per seg buffer
    __shared__ _Float16 Sb[2 * SEG_LDS_H];   // 100352 B (Y=0) / 86016 B (Y=1)
    __shared__ float fsum[NF * 16];
    __shared__ float fsq[NF * 16];

    int tid = threadIdx.x;
    int lane = tid & 63, wave = tid >> 6;
    int col16 = lane & 15, quad = lane >> 4;
    if (tid < NF * 16) { fsum[tid] = 0.f; fsq[tid] = 0.f; }

    int gw = blockIdx.x * 16 + wave;         // 0..4095
    bool act = gw < 3125;                    // 3125 * 32 == 100000 exactly
    int t = act ? gw : 0;
    int r0 = t * 32 + col16, r1 = r0 + 16;
    size_t b0 = (size_t)r0 * 200, b1 = (size_t)r1 * 200;

    floatx4 acc[NF][2];
#pragma unroll
    for (int nf = 0; nf < NF; ++nf) { acc[nf][0] = (floatx4)0.f; acc[nf][1] = (floatx4)0.f; }

    halfx8 ca0, ca1, na0, na1;

    auto stage = [&](int seg, int bufi) {
        for (int cc = wave; cc < 7 * PC; cc += 16) {
            int p7 = cc / PC, sub = cc - p7 * PC;
            const _Float16* g = WpP + (size_t)(seg * 7 + p7) * PANEL_TOT_H
                              + YOFF_H + sub * 512 + lane * 8;
            gload16h(g, Sb + bufi * SEG_LDS_H + cc * 512);
        }
    };
    auto loadA = [&](int kc, halfx8& a0, halfx8& a1) {
        int seg = kc / 7, c = kc - seg * 7;
        int koff = c * 32 + quad * 8;
        if (koff < 200) {
            const _Float16* A = (seg == 0) ? A0h : (seg == 1) ? A1h : A2h;
            a0 = *(const halfx8*)&A[b0 + koff];
            a1 = *(const halfx8*)&A[b1 + koff];
        } else {
            a0 = (halfx8)0; a1 = (halfx8)0;
        }
    };

    stage(0, 0);
    if (act) loadA(0, ca0, ca1);
    __syncthreads();                         // publishes seg0 panel

    int buf = 0;
    for (int seg = 0; seg < 3; ++seg) {
        if (seg < 2) stage(seg + 1, buf ^ 1);   // async, overlaps MFMAs below
        if (act) {
#pragma unroll
            for (int c = 0; c < 7; ++c) {
                int kc = seg * 7 + c;
                if (kc < 20) loadA(kc + 1, na0, na1);
                const _Float16* P = Sb + buf * SEG_LDS_H + c * PANEL_H;
                __builtin_amdgcn_s_setprio(1);
#pragma unroll
                for (int nf = 0; nf < NF; ++nf) {
                    int rl = nf * 16 + col16;
                    int qs = quad ^ ((rl >> 1) & 3);
                    halfx8 b = *(const halfx8*)&P[rl * 32 + qs * 8];
                    acc[nf][0] = __builtin_amdgcn_mfma_f32_16x16x32_f16(ca0, b, acc[nf][0], 0, 0, 0);
                    acc[nf][1] = __builtin_amdgcn_mfma_f32_16x16x32_f16(ca1, b, acc[nf][1], 0, 0, 0);
                }
                __builtin_amdgcn_s_setprio(0);
                ca0 = na0; ca1 = na1;
            }
        }
        __syncthreads();                     // seg done; next-seg panel published
        buf ^= 1;
    }

    int slot[2][4];
    if (map && act) {
#pragma unroll
        for (int h = 0; h < 2; ++h)
#pragma unroll
            for (int j = 0; j < 4; ++j)
                slot[h][j] = map[t * 32 + h * 16 + quad * 4 + j];
    }
    if (act) {
#pragma unroll
        for (int nf = 0; nf < NF; ++nf) {
            int lc = nf * 16 + col16;
            int colg = Y * 112 + lc;
            float ls = 0.f, lq = 0.f;
            if (colg < 200) {
                float bv = bias[colg];
#pragma unroll
                for (int h = 0; h < 2; ++h) {
                    int rbase = t * 32 + h * 16 + quad * 4;
#pragma unroll
                    for (int j = 0; j < 4; ++j) {
                        float v = acc[nf][h][j] * alpha + bv;
                        ls += v; lq += v * v;
                        if (!map) {
                            C[(size_t)(rbase + j) * 200 + colg] = v;
                        } else {
                            int s = slot[h][j];
                            if (s >= 0) C[(size_t)s * 200 + colg] = v;
                        }
                    }
                }
            }
            ls += __shfl_down(ls, 32); ls += __shfl_down(ls, 16);
            lq += __shfl_down(lq, 32); lq += __shfl_down(lq, 16);
            if (quad == 0 && colg < 200) {
                atomicAdd(&fsum[lc], ls);
                atomicAdd(&fsq[lc], lq);
            }
        }
    }
    __syncthreads();
    if (tid < NF * 16) {
        int colg = Y * 112 + tid;
        if (colg < 200) {
            gAtomicAdd(&s1[colg], (double)fsum[tid]);
            gAtomicAdd(&s2[colg], (double)fsq[tid]);
        }
    }
}

// ---------------------------------------------------------------- fc MFMA GEMM body (fp16)
template<int NF0, int NF>
__device__ __forceinline__ void fc_gemm_body(
    const _Float16* __restrict__ Ph, const _Float16* __restrict__ Wt,
    float* __restrict__ part, int ky, _Float16* Bs)
{
    int t = threadIdx.x;
    int lane = t & 63, wave = t >> 6;
    int col16 = lane & 15, quad = lane >> 4;
    int row_base = blockIdx.x * 128 + wave * 32;
    int c0 = ky * 25;
    floatx4 acc[NF][2];
#pragma unroll
    for (int nf = 0; nf < NF; ++nf) { acc[nf][0] = (floatx4)0.f; acc[nf][1] = (floatx4)0.f; }
    int r0 = row_base + col16, r1 = row_base + 16 + col16;
    const int rows4 = NF * 16 * 4;

    for (int c = c0; c < c0 + 25; ++c) {
        int k0 = c * 32;
        for (int i = t; i < rows4; i += 256) {
            int nl = i >> 2, part_i = i & 3;
            int n = NF0 * 16 + nl;
            *(halfx8*)&Bs[nl * 40 + part_i * 8] =
                *(const halfx8*)&Wt[(size_t)n * FLATSZ + k0 + part_i * 8];
        }
        __syncthreads();
        int koff = k0 + quad * 8;
        halfx8 a0 = *(const halfx8*)&Ph[(size_t)r0 * FLATSZ + koff];
        halfx8 a1 = *(const halfx8*)&Ph[(size_t)r1 * FLATSZ + koff];
#pragma unroll
        for (int nf = 0; nf < NF; ++nf) {
            halfx8 b = *(const halfx8*)&Bs[(nf * 16 + col16) * 40 + quad * 8];
            acc[nf][0] = __builtin_amdgcn_mfma_f32_16x16x32_f16(a0, b, acc[nf][0], 0, 0, 0);
            acc[nf][1] = __builtin_amdgcn_mfma_f32_16x16x32_f16(a1, b, acc[nf][1], 0, 0, 0);
        }
        __syncthreads();
    }
    float* out = part + (size_t)ky * (NB * 200);
#pragma unroll
    for (int nf = 0; nf < NF; ++nf) {
        int colg = NF0 * 16 + nf * 16 + col16;
        if (colg >= 200) continue;
#pragma unroll
        for (int h = 0; h < 2; ++h) {
            int rbase = row_base + h * 16 + quad * 4;
#pragma unroll
            for (int j = 0; j < 4; ++j)
                out[(size_t)(rbase + j) * 200 + colg] = acc[nf][h][j];
        }
    }
}

__global__ __launch_bounds__(256) void fc_gemm(
    const _Float16* __restrict__ Ph, const _Float16* __restrict__ Wt,
    float* __restrict__ part)
{
    __shared__ _Float16 Bs[112 * 40];
    int ky = blockIdx.y >> 1;
    if ((blockIdx.y & 1) == 0)
        fc_gemm_body<0, 7>(Ph, Wt, part, ky, Bs);
    else
        fc_gemm_body<7, 6>(Ph, Wt, part, ky, Bs);
}

__global__ __launch_bounds__(256) void fc_reduce(
    const float* __restrict__ part, const float* __restrict__ bias,
    float* __restrict__ hfc)
{
    int i = blockIdx.x * 256 + threadIdx.x;
    float acc = bias[i % 200];
#pragma unroll
    for (int y = 0; y < 49; ++y) acc += part[(size_t)y * (NB * 200) + i];
    hfc[i] = acc;
}

// ---------------------------------------------------------------- stats / bn
__global__ __launch_bounds__(256) void colstats(
    const float* __restrict__ X, int M, int rpb,
    double* __restrict__ s1, double* __restrict__ s2)
{
    int c = threadIdx.x;
    if (c >= 200) return;
    int r0 = blockIdx.x * rpb;
    int r1 = min(r0 + rpb, M);
    float sum = 0.f, sq = 0.f;
    for (int rr = r0; rr < r1; ++rr) {
        float v = X[(size_t)rr * 200 + c];
        sum += v; sq += v * v;
    }
    gAtomicAdd(&s1[c], (double)sum);
    gAtomicAdd(&s2[c], (double)sq);
}

__global__ void finalize_stats(const double* __restrict__ s1, const double* __restrict__ s2,
                               const float* __restrict__ g, const float* __restrict__ bb,
                               float* __restrict__ sc, float* __restrict__ sh,
                               int ncols, double count)
{
    int c = threadIdx.x;
    if (c >= ncols) return;
    double m = s1[c] / count;
    double v = s2[c] / count - m * m;
    double scd = (double)g[c] / sqrt(v + 1e-5);
    sc[c] = (float)scd;
    sh[c] = (float)((double)bb[c] - m * scd);
}

// bn + tanh, fp32 in -> fp16 out (layer-1 x for gather + gemm A2)
__global__ __launch_bounds__(256) void bn_tanh_f16(
    const float* __restrict__ X, const float* __restrict__ sc,
    const float* __restrict__ sh, _Float16* __restrict__ Y, long n4)
{
    long stride = (long)gridDim.x * blockDim.x;
    for (long i = (long)blockIdx.x * blockDim.x + threadIdx.x; i < n4; i += stride) {
        int c4 = (int)(i % 50) * 4;
        float4 v = ((const float4*)X)[i];
        halfx4 h;
        h[0] = (_Float16)tanhf(v.x * sc[c4 + 0] + sh[c4 + 0]);
        h[1] = (_Float16)tanhf(v.y * sc[c4 + 1] + sh[c4 + 1]);
        h[2] = (_Float16)tanhf(v.z * sc[c4 + 2] + sh[c4 + 2]);
        h[3] = (_Float16)tanhf(v.w * sc[c4 + 3] + sh[c4 + 3]);
        ((halfx4*)Y)[i] = h;
    }
}

__global__ __launch_bounds__(256) void bn_act_200(
    float* __restrict__ X, const float* __restrict__ sc, const float* __restrict__ sh,
    long n4, int act)
{
    long stride = (long)gridDim.x * blockDim.x;
    for (long i = (long)blockIdx.x * blockDim.x + threadIdx.x; i < n4; i += stride) {
        int c4 = (int)(i % 50) * 4;
        float4 v = ((const float4*)X)[i];
        float a0 = v.x * sc[c4 + 0] + sh[c4 + 0];
        float a1 = v.y * sc[c4 + 1] + sh[c4 + 1];
        float a2 = v.z * sc[c4 + 2] + sh[c4 + 2];
        float a3 = v.w * sc[c4 + 3] + sh[c4 + 3];
        if (act == 0) { a0 = tanhf(a0); a1 = tanhf(a1); a2 = tanhf(a2); a3 = tanhf(a3); }
        else { a0 = fmaxf(a0, 0.f); a1 = fmaxf(a1, 0.f); a2 = fmaxf(a2, 0.f); a3 = fmaxf(a3, 0.f); }
        ((float4*)X)[i] = make_float4(a0, a1, a2, a3);
    }
}

__global__ __launch_bounds__(256) void rel_mm(
    const float* __restrict__ R, const float* __restrict__ W, float* __restrict__ O)
{
    int idx = blockIdx.x * blockDim.x + threadIdx.x;
    if (idx >= 200 * 200) return;
    int row = idx / 200, col = idx - row * 200;
    float acc = 0.f;
    for (int k = 0; k < 200; ++k) acc = fmaf(R[row * 200 + k], W[k * 200 + col], acc);
    O[idx] = acc;
}

__global__ __launch_bounds__(256) void build_stk(
    const float* __restrict__ x2c, const float* __restrict__ r2,
    const int* __restrict__ subj, const int* __restrict__ ridx,
    const int* __restrict__ map,
    float* __restrict__ stk, double* __restrict__ s1, double* __restrict__ s2)
{
    __shared__ float wsum[4], wsq[4];
    int b = blockIdx.x, t = threadIdx.x;
    const float* se = x2c + (size_t)map[subj[b]] * DIM;
    const float* re = r2 + (size_t)ridx[b] * DIM;
    float sum = 0.f, sq = 0.f;
    for (int i = t; i < 400; i += 256) {
        float v = (i < 200) ? se[i] : re[i - 200];
        stk[(size_t)b * 400 + i] = v;
        sum += v; sq += v * v;
    }
    for (int off = 32; off > 0; off >>= 1) {
        sum += __shfl_down(sum, off);
        sq  += __shfl_down(sq, off);
    }
    if ((t & 63) == 0) { wsum[t >> 6] = sum; wsq[t >> 6] = sq; }
    __syncthreads();
    if (t == 0) {
        float S = wsum[0] + wsum[1] + wsum[2] + wsum[3];
        float Q = wsq[0] + wsq[1] + wsq[2] + wsq[3];
        gAtomicAdd(&s1[0], (double)S);
        gAtomicAdd(&s2[0], (double)Q);
    }
}

__global__ __launch_bounds__(256) void conv_fwd(
    const float* __restrict__ stk, const float* __restrict__ conv_w,
    const float* __restrict__ conv_b, const float* __restrict__ sc0,
    const float* __restrict__ sh0, _Float16* __restrict__ Ph,
    double* __restrict__ s1, double* __restrict__ s2)
{
    __shared__ float img[400];
    __shared__ float wsm[9800];
    __shared__ float bsm[200];
    __shared__ float fsum[200];
    __shared__ float fsq[200];
    int b = blockIdx.x, t = threadIdx.x;
    float scale0 = sc0[0], shift0 = sh0[0];
    if (t < 200) { fsum[t] = 0.f; fsq[t] = 0.f; bsm[t] = conv_b[t]; }
    for (int i = t; i < 400; i += 256) img[i] = stk[(size_t)b * 400 + i] * scale0 + shift0;
    for (int i = t; i < 9800; i += 256) wsm[i] = conv_w[i];
    __syncthreads();
    for (int fy = t; fy < 2800; fy += 256) {
        int f = fy / 14, y = fy - (fy / 14) * 14;
        const float* wf = &wsm[f * 49];
        float acc[14];
        float bias = bsm[f];
#pragma unroll
        for (int xx = 0; xx < 14; ++xx) acc[xx] = bias;
#pragma unroll
        for (int i = 0; i < 7; ++i) {
            const float* rowp = &img[(y + i) * 20];
            float rv[20];
#pragma unroll
            for (int c = 0; c < 20; ++c) rv[c] = rowp[c];
#pragma unroll
            for (int j = 0; j < 7; ++j) {
                float wv = wf[i * 7 + j];
#pragma unroll
                for (int xx = 0; xx < 14; ++xx) acc[xx] = fmaf(rv[xx + j], wv, acc[xx]);
            }
        }
        float ls = 0.f, lq = 0.f;
        _Float16* pp = Ph + (size_t)b * FLATSZ + (size_t)f * 196 + y * 14;
#pragma unroll
        for (int xx = 0; xx < 14; ++xx) {
            float v = acc[xx];
            pp[xx] = (_Float16)v;
            ls += v; lq += v * v;
        }
        atomicAdd(&fsum[f], ls);
        atomicAdd(&fsq[f], lq);
    }
    __syncthreads();
    if (t < 200) {
        gAtomicAdd(&s1[t], (double)fsum[t]);
        gAtomicAdd(&s2[t], (double)fsq[t]);
    }
}

__global__ __launch_bounds__(256) void bn1_relu_f16(
    _Float16* __restrict__ Ph, const float* __restrict__ sc, const float* __restrict__ sh)
{
    long n4 = (long)NB * (FLATSZ / 4);
    long stride = (long)gridDim.x * blockDim.x;
    for (long i = (long)blockIdx.x * blockDim.x + threadIdx.x; i < n4; i += stride) {
        int k4 = (int)(i % (FLATSZ / 4));
        int f = k4 / 49;
        float s = sc[f], h = sh[f];
        halfx4 v = ((const halfx4*)Ph)[i];
#pragma unroll
        for (int e = 0; e < 4; ++e) {
            float x = (float)v[e];
            x = fmaxf(x * s + h, 0.f);
            v[e] = (_Float16)x;
        }
        ((halfx4*)Ph)[i] = v;
    }
}

__global__ __launch_bounds__(256) void score_mm(
    const float* __restrict__ Hn, const float* __restrict__ x2c,
    const int* __restrict__ obj, const int* __restrict__ map,
    float* __restrict__ out)
{
    __shared__ float Asm[16][17];
    __shared__ float Bsm[16][17];
    int tx = threadIdx.x & 15, ty = threadIdx.x >> 4;
    int row = blockIdx.y * 16 + ty;
    int col = blockIdx.x * 16 + tx;
    int oj = map[obj[blockIdx.x * 16 + ty]];
    float acc = 0.f;
    for (int k0 = 0; k0 < 200; k0 += 16) {
        int k = k0 + tx;
        Asm[ty][tx] = (k < 200) ? Hn[(size_t)row * 200 + k] : 0.f;
        Bsm[ty][tx] = (k < 200) ? x2c[(size_t)oj * 200 + k] : 0.f;
        __syncthreads();
#pragma unroll
        for (int kk = 0; kk < 16; ++kk) acc = fmaf(Asm[ty][kk], Bsm[tx][kk], acc);
        __syncthreads();
    }
    out[(size_t)row * NB + col] = 1.f / (1.f + expf(-acc));
}

// ---------------------------------------------------------------- driver
extern "C" void kernel_launch(void* const* d_in, const int* in_sizes, int n_in,
                              void* d_out, int out_size, void* d_ws, size_t ws_size,
                              hipStream_t stream)
{
    (void)in_sizes; (void)n_in; (void)out_size;
    const float* init_embed = (const float*)d_in[0];
    const float* init_rel   = (const float*)d_in[1];
    const float* edge_norm  = (const float*)d_in[2];
    const float* w_in1  = (const float*)d_in[3];
    const float* w_out1 = (const float*)d_in[4];
    const float* w_loop1= (const float*)d_in[5];
    const float* w_rel1 = (const float*)d_in[6];
    const float* lrel1  = (const float*)d_in[7];
    const float* b1     = (const float*)d_in[8];
    const float* gm1    = (const float*)d_in[9];
    const float* be1    = (const float*)d_in[10];
    const float* w_in2  = (const float*)d_in[11];
    const float* w_out2 = (const float*)d_in[12];
    const float* w_loop2= (const float*)d_in[13];
    const float* w_rel2 = (const float*)d_in[14];
    const float* lrel2  = (const float*)d_in[15];
    const float* b2     = (const float*)d_in[16];
    const float* gm2    = (const float*)d_in[17];
    const float* be2    = (const float*)d_in[18];
    const float* conv_w = (const float*)d_in[19];
    const float* conv_b = (const float*)d_in[20];
    const float* fc_w   = (const float*)d_in[21];
    const float* fc_b   = (const float*)d_in[22];
    const float* bn0_g  = (const float*)d_in[23];
    const float* bn0_b  = (const float*)d_in[24];
    const float* bn1_g  = (const float*)d_in[25];
    const float* bn1_b  = (const float*)d_in[26];
    const float* bn2_g  = (const float*)d_in[27];
    const float* bn2_b  = (const float*)d_in[28];
    const int* subj   = (const int*)d_in[29];
    const int* relidx = (const int*)d_in[30];
    const int* obj    = (const int*)d_in[31];
    const int* src    = (const int*)d_in[32];
    const int* dst    = (const int*)d_in[33];
    const int* etype  = (const int*)d_in[34];

    float* ws = (float*)d_ws;
    float* R0 = ws;                 // L1: x1f (C); L2: aggI2; head: Ph
    float* R1 = ws + REGF;          // L1: aggI1 (1st half) + ie16 (2nd half); then x1h
    float* R2 = ws + 2 * REGF;      // aggO (both layers); head: fch + fpart
    float* p = ws + 3 * REGF;       // tail
    float* r1v = p;            p += 40000;
    float* r2v = p;            p += 40000;
    float* stk = p;            p += 409600;
    float* hfc = p;            p += 204800;
    float* x2c = p;            p += 409600;
    float* fsc = p;            p += 256;
    float* fsh = p;            p += 256;
    double* ds1 = (double*)p;  p += 512;
    double* ds2 = (double*)p;  p += 512;
    _Float16* Wp = (_Float16*)p; p += (WT_TOTAL_H + 1) / 2;
    int* map = (int*)p;        p += NENT;
    int* hist = (int*)p;       p += NENT;
    int* offs = (int*)p;       p += NENT + 4;
    int* cursor = (int*)p;     p += NENT;
    int* bsum = (int*)p;       p += 512;
    int4* recs = (int4*)p;     p += (size_t)NEDGE * 4;

    float* x1f = R0;                           // L1 gemm C (fp32)
    _Float16* aggI1 = (_Float16*)R1;           // L1 aggI (fp16, 20M halves)
    _Float16* ie16  = (_Float16*)(R1 + 10050000); // fp16 init_embed (A2 for L1)
    _Float16* aggOh = (_Float16*)R2;           // agg-out fp16 (both layers)
    _Float16* x1h = (_Float16*)R1;             // fp16 x1 (aggI1/ie16 dead after L1 gemm)
    _Float16* aggI2 = (_Float16*)R0;           // L2 aggI (x1f dead after bn_tanh_f16)
    _Float16* Ph  = (_Float16*)R0;
    _Float16* fch = (_Float16*)R2;
    float* fpart = R2 + 4200000;

    const size_t NEED = (size_t)(p - ws) * sizeof(float);
    if (ws_size < NEED) return;

    const int NBLK = (NENT + 255) / 256;
    const size_t DSBYTES = 512 * sizeof(double);

    // -------- CSR build + slot map --------
    hipMemsetAsync(hist, 0, NENT * sizeof(int), stream);
    hipMemsetAsync(map, 0xFF, NENT * sizeof(int), stream);
    edge_hist<<<1024, 256, 0, stream>>>(dst, hist);
    scan1<<<NBLK, 256, 0, stream>>>(hist, offs, bsum);
    scan2<<<1, 512, 0, stream>>>(bsum, NBLK);
    scan3<<<NBLK, 256, 0, stream>>>(hist, offs, bsum, cursor);
    edge_fill<<<1024, 256, 0, stream>>>(src, dst, etype, edge_norm, cursor, recs);
    build_map<<<(2 * NB + 255) / 256, 256, 0, stream>>>(subj, obj, map);

    const int PACK_BLKS = (WT_TOTAL_H + 255) / 256;

    // -------- layer 1 --------
    pack_w3<<<PACK_BLKS, 256, 0, stream>>>(w_in1, w_out1, w_loop1, lrel1, Wp);
    to_f16<<<4096, 256, 0, stream>>>(init_embed, ie16, (long)NENT * 50);
    gather_nodes<<<(NENT + 3) / 4, 256, 0, stream>>>(ie16, init_rel, offs, recs,
                                                     aggI1, aggOh);
    hipMemsetAsync(ds1, 0, DSBYTES, stream);
    gemm_big<0><<<256, 1024, 0, stream>>>(aggI1, aggOh, ie16, Wp,
                                          x1f, b1, nullptr, 1.f / 3.f, ds1, ds2);
    gemm_big<1><<<256, 1024, 0, stream>>>(aggI1, aggOh, ie16, Wp,
                                          x1f, b1, nullptr, 1.f / 3.f, ds1, ds2);
    finalize_stats<<<1, 256, 0, stream>>>(ds1, ds2, gm1, be1, fsc, fsh, 200, (double)NENT);
    bn_tanh_f16<<<4096, 256, 0, stream>>>(x1f, fsc, fsh, x1h, (long)NENT * 50);
    rel_mm<<<(40000 + 255) / 256, 256, 0, stream>>>(init_rel, w_rel1, r1v);

    // -------- layer 2 (fp16 x; compact output) --------
    pack_w3<<<PACK_BLKS, 256, 0, stream>>>(w_in2, w_out2, w_loop2, lrel2, Wp);
    gather_nodes<<<(NENT + 3) / 4, 256, 0, stream>>>(x1h, r1v, offs, recs,
                                                     aggI2, aggOh);
    hipMemsetAsync(ds1, 0, DSBYTES, stream);
    gemm_big<0><<<256, 1024, 0, stream>>>(aggI2, aggOh, x1h, Wp,
                                          x2c, b2, map, 1.f / 3.f, ds1, ds2);
    gemm_big<1><<<256, 1024, 0, stream>>>(aggI2, aggOh, x1h, Wp,
                                          x2c, b2, map, 1.f / 3.f, ds1, ds2);
    finalize_stats<<<1, 256, 0, stream>>>(ds1, ds2, gm2, be2, fsc, fsh, 200, (double)NENT);
    bn_act_200<<<400, 256, 0, stream>>>(x2c, fsc, fsh, (long)2 * NB * 50, 0);
    rel_mm<<<(40000 + 255) / 256, 256, 0, stream>>>(r1v, w_rel2, r2v);

    // -------- ConvE head --------
    hipMemsetAsync(ds1, 0, DSBYTES, stream);
    build_stk<<<NB, 256, 0, stream>>>(x2c, r2v, subj, relidx, map, stk, ds1, ds2);
    finalize_stats<<<1, 256, 0, stream>>>(ds1, ds2, bn0_g, bn0_b, fsc, fsh, 1,
                                          (double)((long)NB * 400));
    hipMemsetAsync(ds1, 0, DSBYTES, stream);
    conv_fwd<<<NB, 256, 0, stream>>>(stk, conv_w, conv_b, fsc, fsh, Ph, ds1, ds2);
    finalize_stats<<<1, 256, 0, stream>>>(ds1, ds2, bn1_g, bn1_b, fsc, fsh, 200,
                                          (double)((long)NB * 196));
    bn1_relu_f16<<<4096, 256, 0, stream>>>(Ph, fsc, fsh);
    pack_fcw<<<(int)(((long)208 * FLATSZ + 255) / 256), 256, 0, stream>>>(fc_w, fch);
    fc_gemm<<<dim3(8, 98), 256, 0, stream>>>(Ph, fch, fpart);
    fc_reduce<<<800, 256, 0, stream>>>(fpart, fc_b, hfc);
    hipMemsetAsync(ds1, 0, DSBYTES, stream);
    colstats<<<4, 256, 0, stream>>>(hfc, NB, 256, ds1, ds2);
    finalize_stats<<<1, 256, 0, stream>>>(ds1, ds2, bn2_g, bn2_b, fsc, fsh, 200, (double)NB);
    bn_act_200<<<200, 256, 0, stream>>>(hfc, fsc, fsh, (long)NB * 50, 1);
    score_mm<<<dim3(NB / 16, NB / 16), 256, 0, stream>>>(hfc, x2c, obj, map, (float*)d_out);
}

// Round 8
// 1065.897 us; speedup vs baseline: 1.7410x; 1.0049x over previous
//
#include <hip/hip_runtime.h>

#define DIM 200
#define NENT 100000
#define NEDGE 1000000
#define EHALF 500000
#define NB 1024
#define NFILT 200
#define FLATSZ 39200

#define NDF ((size_t)NENT * DIM)
#define REGF ((size_t)20100000)

// fp16 weight panel image: 21 panels (seg*7+c), each 6656 halves:
//   [y0: rows 0..111][y1: rows 0..95], row = 32 halves, 16B-chunk index
//   XOR-swizzled by ((row>>1)&3)  (round-5/6 verified: 0 bank conflicts).
#define PANEL_TOT_H 6656
#define Y1OFF_H 3584
#define WT_TOTAL_H 139776      // 21 * 6656

typedef float floatx4 __attribute__((ext_vector_type(4)));
typedef _Float16 halfx8 __attribute__((ext_vector_type(8)));
typedef _Float16 halfx4 __attribute__((ext_vector_type(4)));

__device__ __forceinline__ void gAtomicAdd(float* p, float v) { unsafeAtomicAdd(p, v); }
__device__ __forceinline__ void gAtomicAdd(double* p, double v) { unsafeAtomicAdd(p, v); }

// async global -> LDS, 16B per lane (wave-uniform LDS base + lane*16)
__device__ __forceinline__ void gload16h(const _Float16* g, _Float16* l) {
    __builtin_amdgcn_global_load_lds(
        (const __attribute__((address_space(1))) void*)g,
        (__attribute__((address_space(3))) void*)l,
        16, 0, 0);
}

// ---------------------------------------------------------------- CSR build
__global__ __launch_bounds__(256) void edge_hist(
    const int* __restrict__ dst, int* __restrict__ hist)
{
    int stride = gridDim.x * blockDim.x;
    for (int e = blockIdx.x * 256 + threadIdx.x; e < NEDGE; e += stride)
        atomicAdd(&hist[dst[e]], 1);
}

__global__ __launch_bounds__(256) void scan1(
    const int* __restrict__ hist, int* __restrict__ incl, int* __restrict__ bsum)
{
    __shared__ int sm[256];
    int i = blockIdx.x * 256 + threadIdx.x;
    int t = threadIdx.x;
    sm[t] = (i < NENT) ? hist[i] : 0;
    __syncthreads();
    for (int off = 1; off < 256; off <<= 1) {
        int v = (t >= off) ? sm[t - off] : 0;
        __syncthreads();
        sm[t] += v;
        __syncthreads();
    }
    if (i < NENT) incl[i] = sm[t];
    if (t == 255) bsum[blockIdx.x] = sm[255];
}

__global__ __launch_bounds__(512) void scan2(int* bsum, int nb)
{
    __shared__ int sm[512];
    int t = threadIdx.x;
    int v = (t < nb) ? bsum[t] : 0;
    sm[t] = v;
    __syncthreads();
    for (int off = 1; off < 512; off <<= 1) {
        int u = (t >= off) ? sm[t - off] : 0;
        __syncthreads();
        sm[t] += u;
        __syncthreads();
    }
    if (t < nb) bsum[t] = sm[t] - v;
}

__global__ __launch_bounds__(256) void scan3(
    const int* __restrict__ hist, int* __restrict__ offs,
    const int* __restrict__ bsum, int* __restrict__ cursor)
{
    int i = blockIdx.x * 256 + threadIdx.x;
    if (i < NENT) {
        int excl = offs[i] - hist[i] + bsum[blockIdx.x];
        offs[i] = excl;
        cursor[i] = excl;
    }
    if (i == 0) offs[NENT] = NEDGE;
}

__global__ __launch_bounds__(256) void edge_fill(
    const int* __restrict__ src, const int* __restrict__ dst,
    const int* __restrict__ etype, const float* __restrict__ enorm,
    int* __restrict__ cursor, int4* __restrict__ recs)
{
    int stride = gridDim.x * blockDim.x;
    for (int e = blockIdx.x * 256 + threadIdx.x; e < NEDGE; e += stride) {
        int pos = atomicAdd(&cursor[dst[e]], 1);
        recs[pos] = make_int4(src[e], etype[e] | ((e >= EHALF) ? 0x10000 : 0),
                              __float_as_int(enorm[e]), 0);
    }
}

__global__ __launch_bounds__(256) void build_map(
    const int* __restrict__ subj, const int* __restrict__ obj, int* __restrict__ map)
{
    int i = blockIdx.x * 256 + threadIdx.x;
    if (i < NB) map[subj[i]] = i;
    else if (i < 2 * NB) map[obj[i - NB]] = i;
}

// fp32 -> fp16 elementwise
__global__ __launch_bounds__(256) void to_f16(
    const float* __restrict__ X, _Float16* __restrict__ Y, long n4)
{
    long stride = (long)gridDim.x * blockDim.x;
    for (long i = (long)blockIdx.x * blockDim.x + threadIdx.x; i < n4; i += stride) {
        float4 v = ((const float4*)X)[i];
        halfx4 h;
        h[0] = (_Float16)v.x; h[1] = (_Float16)v.y;
        h[2] = (_Float16)v.z; h[3] = (_Float16)v.w;
        ((halfx4*)Y)[i] = h;
    }
}

// ---------------------------------------------------------------- gather (3-deep pipelined, packed-fp16 math)
// x rows fp16, r table fp16 (80 KB, L2-resident). Per 4 dims per edge:
// 2 v_pk_mul + 4 v_pk_fma (fp16 accumulate) -- no converts, half the r BW.
__global__ __launch_bounds__(256) void gather_nodes(
    const _Float16* __restrict__ x16, const _Float16* __restrict__ r16,
    const int* __restrict__ offs, const int4* __restrict__ recs,
    _Float16* __restrict__ aggI, _Float16* __restrict__ aggO)
{
    int node = blockIdx.x * 4 + (threadIdx.x >> 6);
    int lane = threadIdx.x & 63;
    if (node >= NENT) return;
    int beg = offs[node], end = offs[node + 1];
    bool act = lane < 50;
    int lane_c = min(lane, 49);
    halfx4 aI = (halfx4)0, aO = (halfx4)0;

    auto ld_x = [&](int s) -> halfx4 {
        return *(const halfx4*)&x16[(size_t)s * 200 + lane_c * 4];
    };
    auto ld_r = [&](int et) -> halfx4 {
        return *(const halfx4*)&r16[(size_t)et * 200 + lane_c * 4];
    };

    if (beg < end) {
        int i1 = min(beg + 1, end - 1);
        int i2 = min(beg + 2, end - 1);
        int4 rcA = recs[beg];
        int4 rcB = recs[i1];
        int4 rcC = recs[i2];
        halfx4 xvA = ld_x(rcA.x), xvB = ld_x(rcB.x);
        halfx4 rvA = ld_r(rcA.y & 0xffff), rvB = ld_r(rcB.y & 0xffff);
        for (int i = beg; i < end; ++i) {
            int i3 = min(i + 3, end - 1);
            int4 rcD = recs[i3];
            halfx4 xvC = ld_x(rcC.x);
            halfx4 rvC = ld_r(rcC.y & 0xffff);
            float w = __int_as_float(rcA.z);
            float wI = (rcA.y & 0x10000) ? 0.f : w;
            float wO = w - wI;
            _Float16 wIh = (_Float16)wI, wOh = (_Float16)wO;
            halfx4 wI4 = {wIh, wIh, wIh, wIh};
            halfx4 wO4 = {wOh, wOh, wOh, wOh};
            halfx4 comp = xvA * rvA;
            aI += comp * wI4;
            aO += comp * wO4;
            rcA = rcB; rcB = rcC; rcC = rcD;
            xvA = xvB; xvB = xvC;
            rvA = rvB; rvB = rvC;
        }
    }
    if (act) {
        size_t base = (size_t)node * 200 + lane * 4;
        *(halfx4*)&aggI[base] = aI;
        *(halfx4*)&aggO[base] = aO;
    }
}

// ---------------------------------------------------------------- weight packing (fp16 panel + swizzle)
__global__ __launch_bounds__(256) void pack_w3(
    const float* __restrict__ w0, const float* __restrict__ w1,
    const float* __restrict__ w2, const float* __restrict__ lrel,
    _Float16* __restrict__ WpP)
{
    int i = blockIdx.x * 256 + threadIdx.x;
    if (i >= WT_TOTAL_H) return;
    int p = i / PANEL_TOT_H;
    int r = i % PANEL_TOT_H;
    int y = (r >= Y1OFF_H) ? 1 : 0;
    int rr = y ? (r - Y1OFF_H) : r;
    int rl = rr >> 5;
    int qx = (rr >> 3) & 3;
    int e = rr & 7;
    int q = qx ^ ((rl >> 1) & 3);
    int n = y * 112 + rl;
    int seg = p / 7, c = p - seg * 7;
    int k = c * 32 + q * 8 + e;
    const float* W = (seg == 0) ? w0 : (seg == 1) ? w1 : w2;
    float v = (n < 200 && k < 200) ? W[k * 200 + n] : 0.f;
    if (seg == 2 && n < 200 && k < 200) v *= lrel[k];
    WpP[i] = (_Float16)v;
}

__global__ __launch_bounds__(256) void pack_fcw(
    const float* __restrict__ W, _Float16* __restrict__ Wt)
{
    long i = (long)blockIdx.x * 256 + threadIdx.x;
    if (i >= (long)208 * FLATSZ) return;
    int n = (int)(i / FLATSZ);
    Wt[i] = (n < 200) ? (_Float16)W[i] : (_Float16)0.f;
}

// ---------------------------------------------------------------- fp16 MFMA GEMM, barrier-free K loop
// One block per CU (grid 256), 16 waves, one column-half (Y=0: cols 0-111
// NF=7; Y=1: cols 112-207 NF=6). Block stages one SEG of its half (50/43 KB)
// into LDS, double-buffered across segs (3 barriers total). Each wave owns at
// most ONE 32-row tile (4096 waves >= 3125 tiles), acc lives across the whole
// kernel, A register-prefetched 1 kc ahead. No per-kc barriers at all.
template<int Y>
__global__ __launch_bounds__(1024) void gemm_big(
    const _Float16* __restrict__ A0h, const _Float16* __restrict__ A1h,
    const _Float16* __restrict__ A2h, const _Float16* __restrict__ WpP,
    float* __restrict__ C, const float* __restrict__ bias,
    const int* __restrict__ map, float alpha,
    double* __restrict__ s1, double* __restrict__ s2)
{
    constexpr int NF = Y ? 6 : 7;
    constexpr int PC = NF;                   // 1KB chunks per panel
    constexpr int PANEL_H = NF * 512;        // halves per panel (3584/3072)
    constexpr int YOFF_H = Y ? Y1OFF_H : 0;
    constexpr int SEG_LDS_H = 7 * PANEL_H;   // halves per seg buffer
    __shared__ _Float16 Sb[2 * SEG_LDS_H];   // 100352 B (Y=0) / 86016 B (Y=1)
    __shared__ float fsum[NF * 16];
    __shared__ float fsq[NF * 16];

    int tid = threadIdx.x;
    int lane = tid & 63, wave = tid >> 6;
    int col16 = lane & 15, quad = lane >> 4;
    if (tid < NF * 16) { fsum[tid] = 0.f; fsq[tid] = 0.f; }

    int gw = blockIdx.x * 16 + wave;         // 0..4095
    bool act = gw < 3125;                    // 3125 * 32 == 100000 exactly
    int t = act ? gw : 0;
    int r0 = t * 32 + col16, r1 = r0 + 16;
    size_t b0 = (size_t)r0 * 200, b1 = (size_t)r1 * 200;

    floatx4 acc[NF][2];
#pragma unroll
    for (int nf = 0; nf < NF; ++nf) { acc[nf][0] = (floatx4)0.f; acc[nf][1] = (floatx4)0.f; }

    halfx8 ca0, ca1, na0, na1;

    auto stage = [&](int seg, int bufi) {
        for (int cc = wave; cc < 7 * PC; cc += 16) {
            int p7 = cc / PC, sub = cc - p7 * PC;
            const _Float16* g = WpP + (size_t)(seg * 7 + p7) * PANEL_TOT_H
                              + YOFF_H + sub * 512 + lane * 8;
            gload16h(g, Sb + bufi * SEG_LDS_H + cc * 512);
        }
    };
    auto loadA = [&](int kc, halfx8& a0, halfx8& a1) {
        int seg = kc / 7, c = kc - seg * 7;
        int koff = c * 32 + quad * 8;
        if (koff < 200) {
            const _Float16* A = (seg == 0) ? A0h : (seg == 1) ? A1h : A2h;
            a0 = *(const halfx8*)&A[b0 + koff];
            a1 = *(const halfx8*)&A[b1 + koff];
        } else {
            a0 = (halfx8)0; a1 = (halfx8)0;
        }
    };

    stage(0, 0);
    if (act) loadA(0, ca0, ca1);
    __syncthreads();                         // publishes seg0 panel

    int buf = 0;
    for (int seg = 0; seg < 3; ++seg) {
        if (seg < 2) stage(seg + 1, buf ^ 1);   // async, overlaps MFMAs below
        if (act) {
#pragma unroll
            for (int c = 0; c < 7; ++c) {
                int kc = seg * 7 + c;
                if (kc < 20) loadA(kc + 1, na0, na1);
                const _Float16* P = Sb + buf * SEG_LDS_H + c * PANEL_H;
                __builtin_amdgcn_s_setprio(1);
#pragma unroll
                for (int nf = 0; nf < NF; ++nf) {
                    int rl = nf * 16 + col16;
                    int qs = quad ^ ((rl >> 1) & 3);
                    halfx8 b = *(const halfx8*)&P[rl * 32 + qs * 8];
                    acc[nf][0] = __builtin_amdgcn_mfma_f32_16x16x32_f16(ca0, b, acc[nf][0], 0, 0, 0);
                    acc[nf][1] = __builtin_amdgcn_mfma_f32_16x16x32_f16(ca1, b, acc[nf][1], 0, 0, 0);
                }
                __builtin_amdgcn_s_setprio(0);
                ca0 = na0; ca1 = na1;
            }
        }
        __syncthreads();                     // seg done; next-seg panel published
        buf ^= 1;
    }

    int slot[2][4];
    if (map && act) {
#pragma unroll
        for (int h = 0; h < 2; ++h)
#pragma unroll
            for (int j = 0; j < 4; ++j)
                slot[h][j] = map[t * 32 + h * 16 + quad * 4 + j];
    }
    if (act) {
#pragma unroll
        for (int nf = 0; nf < NF; ++nf) {
            int lc = nf * 16 + col16;
            int colg = Y * 112 + lc;
            float ls = 0.f, lq = 0.f;
            if (colg < 200) {
                float bv = bias[colg];
#pragma unroll
                for (int h = 0; h < 2; ++h) {
                    int rbase = t * 32 + h * 16 + quad * 4;
#pragma unroll
                    for (int j = 0; j < 4; ++j) {
                        float v = acc[nf][h][j] * alpha + bv;
                        ls += v; lq += v * v;
                        if (!map) {
                            C[(size_t)(rbase + j) * 200 + colg] = v;
                        } else {
                            int s = slot[h][j];
                            if (s >= 0) C[(size_t)s * 200 + colg] = v;
                        }
                    }
                }
            }
            ls += __shfl_down(ls, 32); ls += __shfl_down(ls, 16);
            lq += __shfl_down(lq, 32); lq += __shfl_down(lq, 16);
            if (quad == 0 && colg < 200) {
                atomicAdd(&fsum[lc], ls);
                atomicAdd(&fsq[lc], lq);
            }
        }
    }
    __syncthreads();
    if (tid < NF * 16) {
        int colg = Y * 112 + tid;
        if (colg < 200) {
            gAtomicAdd(&s1[colg], (double)fsum[tid]);
            gAtomicAdd(&s2[colg], (double)fsq[tid]);
        }
    }
}

// ---------------------------------------------------------------- fc MFMA GEMM body (fp16)
template<int NF0, int NF>
__device__ __forceinline__ void fc_gemm_body(
    const _Float16* __restrict__ Ph, const _Float16* __restrict__ Wt,
    float* __restrict__ part, int ky, _Float16* Bs)
{
    int t = threadIdx.x;
    int lane = t & 63, wave = t >> 6;
    int col16 = lane & 15, quad = lane >> 4;
    int row_base = blockIdx.x * 128 + wave * 32;
    int c0 = ky * 25;
    floatx4 acc[NF][2];
#pragma unroll
    for (int nf = 0; nf < NF; ++nf) { acc[nf][0] = (floatx4)0.f; acc[nf][1] = (floatx4)0.f; }
    int r0 = row_base + col16, r1 = row_base + 16 + col16;
    const int rows4 = NF * 16 * 4;

    for (int c = c0; c < c0 + 25; ++c) {
        int k0 = c * 32;
        for (int i = t; i < rows4; i += 256) {
            int nl = i >> 2, part_i = i & 3;
            int n = NF0 * 16 + nl;
            *(halfx8*)&Bs[nl * 40 + part_i * 8] =
                *(const halfx8*)&Wt[(size_t)n * FLATSZ + k0 + part_i * 8];
        }
        __syncthreads();
        int koff = k0 + quad * 8;
        halfx8 a0 = *(const halfx8*)&Ph[(size_t)r0 * FLATSZ + koff];
        halfx8 a1 = *(const halfx8*)&Ph[(size_t)r1 * FLATSZ + koff];
#pragma unroll
        for (int nf = 0; nf < NF; ++nf) {
            halfx8 b = *(const halfx8*)&Bs[(nf * 16 + col16) * 40 + quad * 8];
            acc[nf][0] = __builtin_amdgcn_mfma_f32_16x16x32_f16(a0, b, acc[nf][0], 0, 0, 0);
            acc[nf][1] = __builtin_amdgcn_mfma_f32_16x16x32_f16(a1, b, acc[nf][1], 0, 0, 0);
        }
        __syncthreads();
    }
    float* out = part + (size_t)ky * (NB * 200);
#pragma unroll
    for (int nf = 0; nf < NF; ++nf) {
        int colg = NF0 * 16 + nf * 16 + col16;
        if (colg >= 200) continue;
#pragma unroll
        for (int h = 0; h < 2; ++h) {
            int rbase = row_base + h * 16 + quad * 4;
#pragma unroll
            for (int j = 0; j < 4; ++j)
                out[(size_t)(rbase + j) * 200 + colg] = acc[nf][h][j];
        }
    }
}

__global__ __launch_bounds__(256) void fc_gemm(
    const _Float16* __restrict__ Ph, const _Float16* __restrict__ Wt,
    float* __restrict__ part)
{
    __shared__ _Float16 Bs[112 * 40];
    int ky = blockIdx.y >> 1;
    if ((blockIdx.y & 1) == 0)
        fc_gemm_body<0, 7>(Ph, Wt, part, ky, Bs);
    else
        fc_gemm_body<7, 6>(Ph, Wt, part, ky, Bs);
}

__global__ __launch_bounds__(256) void fc_reduce(
    const float* __restrict__ part, const float* __restrict__ bias,
    float* __restrict__ hfc)
{
    int i = blockIdx.x * 256 + threadIdx.x;
    float acc = bias[i % 200];
#pragma unroll
    for (int y = 0; y < 49; ++y) acc += part[(size_t)y * (NB * 200) + i];
    hfc[i] = acc;
}

// ---------------------------------------------------------------- stats / bn
__global__ __launch_bounds__(256) void colstats(
    const float* __restrict__ X, int M, int rpb,
    double* __restrict__ s1, double* __restrict__ s2)
{
    int c = threadIdx.x;
    if (c >= 200) return;
    int r0 = blockIdx.x * rpb;
    int r1 = min(r0 + rpb, M);
    float sum = 0.f, sq = 0.f;
    for (int rr = r0; rr < r1; ++rr) {
        float v = X[(size_t)rr * 200 + c];
        sum += v; sq += v * v;
    }
    gAtomicAdd(&s1[c], (double)sum);
    gAtomicAdd(&s2[c], (double)sq);
}

__global__ void finalize_stats(const double* __restrict__ s1, const double* __restrict__ s2,
                               const float* __restrict__ g, const float* __restrict__ bb,
                               float* __restrict__ sc, float* __restrict__ sh,
                               int ncols, double count)
{
    int c = threadIdx.x;
    if (c >= ncols) return;
    double m = s1[c] / count;
    double v = s2[c] / count - m * m;
    double scd = (double)g[c] / sqrt(v + 1e-5);
    sc[c] = (float)scd;
    sh[c] = (float)((double)bb[c] - m * scd);
}

// bn + tanh, fp32 in -> fp16 out (layer-1 x for gather + gemm A2)
__global__ __launch_bounds__(256) void bn_tanh_f16(
    const float* __restrict__ X, const float* __restrict__ sc,
    const float* __restrict__ sh, _Float16* __restrict__ Y, long n4)
{
    long stride = (long)gridDim.x * blockDim.x;
    for (long i = (long)blockIdx.x * blockDim.x + threadIdx.x; i < n4; i += stride) {
        int c4 = (int)(i % 50) * 4;
        float4 v = ((const float4*)X)[i];
        halfx4 h;
        h[0] = (_Float16)tanhf(v.x * sc[c4 + 0] + sh[c4 + 0]);
        h[1] = (_Float16)tanhf(v.y * sc[c4 + 1] + sh[c4 + 1]);
        h[2] = (_Float16)tanhf(v.z * sc[c4 + 2] + sh[c4 + 2]);
        h[3] = (_Float16)tanhf(v.w * sc[c4 + 3] + sh[c4 + 3]);
        ((halfx4*)Y)[i] = h;
    }
}

__global__ __launch_bounds__(256) void bn_act_200(
    float* __restrict__ X, const float* __restrict__ sc, const float* __restrict__ sh,
    long n4, int act)
{
    long stride = (long)gridDim.x * blockDim.x;
    for (long i = (long)blockIdx.x * blockDim.x + threadIdx.x; i < n4; i += stride) {
        int c4 = (int)(i % 50) * 4;
        float4 v = ((const float4*)X)[i];
        float a0 = v.x * sc[c4 + 0] + sh[c4 + 0];
        float a1 = v.y * sc[c4 + 1] + sh[c4 + 1];
        float a2 = v.z * sc[c4 + 2] + sh[c4 + 2];
        float a3 = v.w * sc[c4 + 3] + sh[c4 + 3];
        if (act == 0) { a0 = tanhf(a0); a1 = tanhf(a1); a2 = tanhf(a2); a3 = tanhf(a3); }
        else { a0 = fmaxf(a0, 0.f); a1 = fmaxf(a1, 0.f); a2 = fmaxf(a2, 0.f); a3 = fmaxf(a3, 0.f); }
        ((float4*)X)[i] = make_float4(a0, a1, a2, a3);
    }
}

__global__ __launch_bounds__(256) void rel_mm(
    const float* __restrict__ R, const float* __restrict__ W, float* __restrict__ O)
{
    int idx = blockIdx.x * blockDim.x + threadIdx.x;
    if (idx >= 200 * 200) return;
    int row = idx / 200, col = idx - row * 200;
    float acc = 0.f;
    for (int k = 0; k < 200; ++k) acc = fmaf(R[row * 200 + k], W[k * 200 + col], acc);
    O[idx] = acc;
}

__global__ __launch_bounds__(256) void build_stk(
    const float* __restrict__ x2c, const float* __restrict__ r2,
    const int* __restrict__ subj, const int* __restrict__ ridx,
    const int* __restrict__ map,
    float* __restrict__ stk, double* __restrict__ s1, double* __restrict__ s2)
{
    __shared__ float wsum[4], wsq[4];
    int b = blockIdx.x, t = threadIdx.x;
    const float* se = x2c + (size_t)map[subj[b]] * DIM;
    const float* re = r2 + (size_t)ridx[b] * DIM;
    float sum = 0.f, sq = 0.f;
    for (int i = t; i < 400; i += 256) {
        float v = (i < 200) ? se[i] : re[i - 200];
        stk[(size_t)b * 400 + i] = v;
        sum += v; sq += v * v;
    }
    for (int off = 32; off > 0; off >>= 1) {
        sum += __shfl_down(sum, off);
        sq  += __shfl_down(sq, off);
    }
    if ((t & 63) == 0) { wsum[t >> 6] = sum; wsq[t >> 6] = sq; }
    __syncthreads();
    if (t == 0) {
        float S = wsum[0] + wsum[1] + wsum[2] + wsum[3];
        float Q = wsq[0] + wsq[1] + wsq[2] + wsq[3];
        gAtomicAdd(&s1[0], (double)S);
        gAtomicAdd(&s2[0], (double)Q);
    }
}

__global__ __launch_bounds__(256) void conv_fwd(
    const float* __restrict__ stk, const float* __restrict__ conv_w,
    const float* __restrict__ conv_b, const float* __restrict__ sc0,
    const float* __restrict__ sh0, _Float16* __restrict__ Ph,
    double* __restrict__ s1, double* __restrict__ s2)
{
    __shared__ float img[400];
    __shared__ float wsm[9800];
    __shared__ float bsm[200];
    __shared__ float fsum[200];
    __shared__ float fsq[200];
    int b = blockIdx.x, t = threadIdx.x;
    float scale0 = sc0[0], shift0 = sh0[0];
    if (t < 200) { fsum[t] = 0.f; fsq[t] = 0.f; bsm[t] = conv_b[t]; }
    for (int i = t; i < 400; i += 256) img[i] = stk[(size_t)b * 400 + i] * scale0 + shift0;
    for (int i = t; i < 9800; i += 256) wsm[i] = conv_w[i];
    __syncthreads();
    for (int fy = t; fy < 2800; fy += 256) {
        int f = fy / 14, y = fy - (fy / 14) * 14;
        const float* wf = &wsm[f * 49];
        float acc[14];
        float bias = bsm[f];
#pragma unroll
        for (int xx = 0; xx < 14; ++xx) acc[xx] = bias;
#pragma unroll
        for (int i = 0; i < 7; ++i) {
            const float* rowp = &img[(y + i) * 20];
            float rv[20];
#pragma unroll
            for (int c = 0; c < 20; ++c) rv[c] = rowp[c];
#pragma unroll
            for (int j = 0; j < 7; ++j) {
                float wv = wf[i * 7 + j];
#pragma unroll
                for (int xx = 0; xx < 14; ++xx) acc[xx] = fmaf(rv[xx + j], wv, acc[xx]);
            }
        }
        float ls = 0.f, lq = 0.f;
        _Float16* pp = Ph + (size_t)b * FLATSZ + (size_t)f * 196 + y * 14;
#pragma unroll
        for (int xx = 0; xx < 14; ++xx) {
            float v = acc[xx];
            pp[xx] = (_Float16)v;
            ls += v; lq += v * v;
        }
        atomicAdd(&fsum[f], ls);
        atomicAdd(&fsq[f], lq);
    }
    __syncthreads();
    if (t < 200) {
        gAtomicAdd(&s1[t], (double)fsum[t]);
        gAtomicAdd(&s2[t], (double)fsq[t]);
    }
}

__global__ __launch_bounds__(256) void bn1_relu_f16(
    _Float16* __restrict__ Ph, const float* __restrict__ sc, const float* __restrict__ sh)
{
    long n4 = (long)NB * (FLATSZ / 4);
    long stride = (long)gridDim.x * blockDim.x;
    for (long i = (long)blockIdx.x * blockDim.x + threadIdx.x; i < n4; i += stride) {
        int k4 = (int)(i % (FLATSZ / 4));
        int f = k4 / 49;
        float s = sc[f], h = sh[f];
        halfx4 v = ((const halfx4*)Ph)[i];
#pragma unroll
        for (int e = 0; e < 4; ++e) {
            float x = (float)v[e];
            x = fmaxf(x * s + h, 0.f);
            v[e] = (_Float16)x;
        }
        ((halfx4*)Ph)[i] = v;
    }
}

__global__ __launch_bounds__(256) void score_mm(
    const float* __restrict__ Hn, const float* __restrict__ x2c,
    const int* __restrict__ obj, const int* __restrict__ map,
    float* __restrict__ out)
{
    __shared__ float Asm[16][17];
    __shared__ float Bsm[16][17];
    int tx = threadIdx.x & 15, ty = threadIdx.x >> 4;
    int row = blockIdx.y * 16 + ty;
    int col = blockIdx.x * 16 + tx;
    int oj = map[obj[blockIdx.x * 16 + ty]];
    float acc = 0.f;
    for (int k0 = 0; k0 < 200; k0 += 16) {
        int k = k0 + tx;
        Asm[ty][tx] = (k < 200) ? Hn[(size_t)row * 200 + k] : 0.f;
        Bsm[ty][tx] = (k < 200) ? x2c[(size_t)oj * 200 + k] : 0.f;
        __syncthreads();
#pragma unroll
        for (int kk = 0; kk < 16; ++kk) acc = fmaf(Asm[ty][kk], Bsm[tx][kk], acc);
        __syncthreads();
    }
    out[(size_t)row * NB + col] = 1.f / (1.f + expf(-acc));
}

// ---------------------------------------------------------------- driver
extern "C" void kernel_launch(void* const* d_in, const int* in_sizes, int n_in,
                              void* d_out, int out_size, void* d_ws, size_t ws_size,
                              hipStream_t stream)
{
    (void)in_sizes; (void)n_in; (void)out_size;
    const float* init_embed = (const float*)d_in[0];
    const float* init_rel   = (const float*)d_in[1];
    const float* edge_norm  = (const float*)d_in[2];
    const float* w_in1  = (const float*)d_in[3];
    const float* w_out1 = (const float*)d_in[4];
    const float* w_loop1= (const float*)d_in[5];
    const float* w_rel1 = (const float*)d_in[6];
    const float* lrel1  = (const float*)d_in[7];
    const float* b1     = (const float*)d_in[8];
    const float* gm1    = (const float*)d_in[9];
    const float* be1    = (const float*)d_in[10];
    const float* w_in2  = (const float*)d_in[11];
    const float* w_out2 = (const float*)d_in[12];
    const float* w_loop2= (const float*)d_in[13];
    const float* w_rel2 = (const float*)d_in[14];
    const float* lrel2  = (const float*)d_in[15];
    const float* b2     = (const float*)d_in[16];
    const float* gm2    = (const float*)d_in[17];
    const float* be2    = (const float*)d_in[18];
    const float* conv_w = (const float*)d_in[19];
    const float* conv_b = (const float*)d_in[20];
    const float* fc_w   = (const float*)d_in[21];
    const float* fc_b   = (const float*)d_in[22];
    const float* bn0_g  = (const float*)d_in[23];
    const float* bn0_b  = (const float*)d_in[24];
    const float* bn1_g  = (const float*)d_in[25];
    const float* bn1_b  = (const float*)d_in[26];
    const float* bn2_g  = (const float*)d_in[27];
    const float* bn2_b  = (const float*)d_in[28];
    const int* subj   = (const int*)d_in[29];
    const int* relidx = (const int*)d_in[30];
    const int* obj    = (const int*)d_in[31];
    const int* src    = (const int*)d_in[32];
    const int* dst    = (const int*)d_in[33];
    const int* etype  = (const int*)d_in[34];

    float* ws = (float*)d_ws;
    float* R0 = ws;                 // L1: x1f (C); L2: aggI2; head: Ph
    float* R1 = ws + REGF;          // L1: aggI1 (1st half) + ie16 (2nd half); then x1h
    float* R2 = ws + 2 * REGF;      // aggO (both layers); head: fch + fpart
    float* p = ws + 3 * REGF;       // tail
    float* r1v = p;            p += 40000;
    float* r2v = p;            p += 40000;
    float* stk = p;            p += 409600;
    float* hfc = p;            p += 204800;
    float* x2c = p;            p += 409600;
    float* fsc = p;            p += 256;
    float* fsh = p;            p += 256;
    double* ds1 = (double*)p;  p += 512;
    double* ds2 = (double*)p;  p += 512;
    _Float16* Wp = (_Float16*)p; p += (WT_TOTAL_H + 1) / 2;
    _Float16* rg16 = (_Float16*)p; p += 20000;   // fp16 relation table (both layers)
    int* map = (int*)p;        p += NENT;
    int* hist = (int*)p;       p += NENT;
    int* offs = (int*)p;       p += NENT + 4;
    int* cursor = (int*)p;     p += NENT;
    int* bsum = (int*)p;       p += 512;
    int4* recs = (int4*)p;     p += (size_t)NEDGE * 4;

    float* x1f = R0;                           // L1 gemm C (fp32)
    _Float16* aggI1 = (_Float16*)R1;           // L1 aggI (fp16, 20M halves)
    _Float16* ie16  = (_Float16*)(R1 + 10050000); // fp16 init_embed (A2 for L1)
    _Float16* aggOh = (_Float16*)R2;           // agg-out fp16 (both layers)
    _Float16* x1h = (_Float16*)R1;             // fp16 x1 (aggI1/ie16 dead after L1 gemm)
    _Float16* aggI2 = (_Float16*)R0;           // L2 aggI (x1f dead after bn_tanh_f16)
    _Float16* Ph  = (_Float16*)R0;
    _Float16* fch = (_Float16*)R2;
    float* fpart = R2 + 4200000;

    const size_t NEED = (size_t)(p - ws) * sizeof(float);
    if (ws_size < NEED) return;

    const int NBLK = (NENT + 255) / 256;
    const size_t DSBYTES = 512 * sizeof(double);

    // -------- CSR build + slot map --------
    hipMemsetAsync(hist, 0, NENT * sizeof(int), stream);
    hipMemsetAsync(map, 0xFF, NENT * sizeof(int), stream);
    edge_hist<<<1024, 256, 0, stream>>>(dst, hist);
    scan1<<<NBLK, 256, 0, stream>>>(hist, offs, bsum);
    scan2<<<1, 512, 0, stream>>>(bsum, NBLK);
    scan3<<<NBLK, 256, 0, stream>>>(hist, offs, bsum, cursor);
    edge_fill<<<1024, 256, 0, stream>>>(src, dst, etype, edge_norm, cursor, recs);
    build_map<<<(2 * NB + 255) / 256, 256, 0, stream>>>(subj, obj, map);

    const int PACK_BLKS = (WT_TOTAL_H + 255) / 256;

    // -------- layer 1 --------
    pack_w3<<<PACK_BLKS, 256, 0, stream>>>(w_in1, w_out1, w_loop1, lrel1, Wp);
    to_f16<<<4096, 256, 0, stream>>>(init_embed, ie16, (long)NENT * 50);
    to_f16<<<40, 256, 0, stream>>>(init_rel, rg16, 10000);
    gather_nodes<<<(NENT + 3) / 4, 256, 0, stream>>>(ie16, rg16, offs, recs,
                                                     aggI1, aggOh);
    hipMemsetAsync(ds1, 0, DSBYTES, stream);
    gemm_big<0><<<256, 1024, 0, stream>>>(aggI1, aggOh, ie16, Wp,
                                          x1f, b1, nullptr, 1.f / 3.f, ds1, ds2);
    gemm_big<1><<<256, 1024, 0, stream>>>(aggI1, aggOh, ie16, Wp,
                                          x1f, b1, nullptr, 1.f / 3.f, ds1, ds2);
    finalize_stats<<<1, 256, 0, stream>>>(ds1, ds2, gm1, be1, fsc, fsh, 200, (double)NENT);
    bn_tanh_f16<<<4096, 256, 0, stream>>>(x1f, fsc, fsh, x1h, (long)NENT * 50);
    rel_mm<<<(40000 + 255) / 256, 256, 0, stream>>>(init_rel, w_rel1, r1v);

    // -------- layer 2 (fp16 x; compact output) --------
    pack_w3<<<PACK_BLKS, 256, 0, stream>>>(w_in2, w_out2, w_loop2, lrel2, Wp);
    to_f16<<<40, 256, 0, stream>>>(r1v, rg16, 10000);
    gather_nodes<<<(NENT + 3) / 4, 256, 0, stream>>>(x1h, rg16, offs, recs,
                                                     aggI2, aggOh);
    hipMemsetAsync(ds1, 0, DSBYTES, stream);
    gemm_big<0><<<256, 1024, 0, stream>>>(aggI2, aggOh, x1h, Wp,
                                          x2c, b2, map, 1.f / 3.f, ds1, ds2);
    gemm_big<1><<<256, 1024, 0, stream>>>(aggI2, aggOh, x1h, Wp,
                                          x2c, b2, map, 1.f / 3.f, ds1, ds2);
    finalize_stats<<<1, 256, 0, stream>>>(ds1, ds2, gm2, be2, fsc, fsh, 200, (double)NENT);
    bn_act_200<<<400, 256, 0, stream>>>(x2c, fsc, fsh, (long)2 * NB * 50, 0);
    rel_mm<<<(40000 + 255) / 256, 256, 0, stream>>>(r1v, w_rel2, r2v);

    // -------- ConvE head --------
    hipMemsetAsync(ds1, 0, DSBYTES, stream);
    build_stk<<<NB, 256, 0, stream>>>(x2c, r2v, subj, relidx, map, stk, ds1, ds2);
    finalize_stats<<<1, 256, 0, stream>>>(ds1, ds2, bn0_g, bn0_b, fsc, fsh, 1,
                                          (double)((long)NB * 400));
    hipMemsetAsync(ds1, 0, DSBYTES, stream);
    conv_fwd<<<NB, 256, 0, stream>>>(stk, conv_w, conv_b, fsc, fsh, Ph, ds1, ds2);
    finalize_stats<<<1, 256, 0, stream>>>(ds1, ds2, bn1_g, bn1_b, fsc, fsh, 200,
                                          (double)((long)NB * 196));
    bn1_relu_f16<<<4096, 256, 0, stream>>>(Ph, fsc, fsh);
    pack_fcw<<<(int)(((long)208 * FLATSZ + 255) / 256), 256, 0, stream>>>(fc_w, fch);
    fc_gemm<<<dim3(8, 98), 256, 0, stream>>>(Ph, fch, fpart);
    fc_reduce<<<800, 256, 0, stream>>>(fpart, fc_b, hfc);
    hipMemsetAsync(ds1, 0, DSBYTES, stream);
    colstats<<<4, 256, 0, stream>>>(hfc, NB, 256, ds1, ds2);
    finalize_stats<<<1, 256, 0, stream>>>(ds1, ds2, bn2_g, bn2_b, fsc, fsh, 200, (double)NB);
    bn_act_200<<<200, 256, 0, stream>>>(hfc, fsc, fsh, (long)NB * 50, 1);
    score_mm<<<dim3(NB / 16, NB / 16), 256, 0, stream>>>(hfc, x2c, obj, map, (float*)d_out);
}

// Round 9
// 1032.502 us; speedup vs baseline: 1.7973x; 1.0323x over previous
//
#include <hip/hip_runtime.h>

#define DIM 200
#define NENT 100000
#define NEDGE 1000000
#define EHALF 500000
#define NB 1024
#define NFILT 200
#define FLATSZ 39200

#define NDF ((size_t)NENT * DIM)
#define REGF ((size_t)20100000)

// fp16 weight panel image: 21 panels (seg*7+c), each 6656 halves:
//   [y0: rows 0..111][y1: rows 0..95], row = 32 halves, 16B-chunk index
//   XOR-swizzled by ((row>>1)&3)  (round-5/6 verified: 0 bank conflicts).
#define PANEL_TOT_H 6656
#define Y1OFF_H 3584
#define WT_TOTAL_H 139776      // 21 * 6656

typedef float floatx4 __attribute__((ext_vector_type(4)));
typedef _Float16 halfx8 __attribute__((ext_vector_type(8)));
typedef _Float16 halfx4 __attribute__((ext_vector_type(4)));

__device__ __forceinline__ void gAtomicAdd(float* p, float v) { unsafeAtomicAdd(p, v); }
__device__ __forceinline__ void gAtomicAdd(double* p, double v) { unsafeAtomicAdd(p, v); }

// async global -> LDS, 16B per lane (wave-uniform LDS base + lane*16)
__device__ __forceinline__ void gload16h(const _Float16* g, _Float16* l) {
    __builtin_amdgcn_global_load_lds(
        (const __attribute__((address_space(1))) void*)g,
        (__attribute__((address_space(3))) void*)l,
        16, 0, 0);
}

// ---------------------------------------------------------------- CSR build
__global__ __launch_bounds__(256) void edge_hist(
    const int* __restrict__ dst, int* __restrict__ hist)
{
    int stride = gridDim.x * blockDim.x;
    for (int e = blockIdx.x * 256 + threadIdx.x; e < NEDGE; e += stride)
        atomicAdd(&hist[dst[e]], 1);
}

__global__ __launch_bounds__(256) void scan1(
    const int* __restrict__ hist, int* __restrict__ incl, int* __restrict__ bsum)
{
    __shared__ int sm[256];
    int i = blockIdx.x * 256 + threadIdx.x;
    int t = threadIdx.x;
    sm[t] = (i < NENT) ? hist[i] : 0;
    __syncthreads();
    for (int off = 1; off < 256; off <<= 1) {
        int v = (t >= off) ? sm[t - off] : 0;
        __syncthreads();
        sm[t] += v;
        __syncthreads();
    }
    if (i < NENT) incl[i] = sm[t];
    if (t == 255) bsum[blockIdx.x] = sm[255];
}

__global__ __launch_bounds__(512) void scan2(int* bsum, int nb)
{
    __shared__ int sm[512];
    int t = threadIdx.x;
    int v = (t < nb) ? bsum[t] : 0;
    sm[t] = v;
    __syncthreads();
    for (int off = 1; off < 512; off <<= 1) {
        int u = (t >= off) ? sm[t - off] : 0;
        __syncthreads();
        sm[t] += u;
        __syncthreads();
    }
    if (t < nb) bsum[t] = sm[t] - v;
}

__global__ __launch_bounds__(256) void scan3(
    const int* __restrict__ hist, int* __restrict__ offs,
    const int* __restrict__ bsum, int* __restrict__ cursor)
{
    int i = blockIdx.x * 256 + threadIdx.x;
    if (i < NENT) {
        int excl = offs[i] - hist[i] + bsum[blockIdx.x];
        offs[i] = excl;
        cursor[i] = excl;
    }
    if (i == 0) offs[NENT] = NEDGE;
}

// rec: word0 = src*400 (byte offset) | invFlag<<31; word1 = etype | w_fp16<<16
__global__ __launch_bounds__(256) void edge_fill(
    const int* __restrict__ src, const int* __restrict__ dst,
    const int* __restrict__ etype, const float* __restrict__ enorm,
    int* __restrict__ cursor, uint2* __restrict__ recs)
{
    int stride = gridDim.x * blockDim.x;
    for (int e = blockIdx.x * 256 + threadIdx.x; e < NEDGE; e += stride) {
        int pos = atomicAdd(&cursor[dst[e]], 1);
        union { _Float16 h; unsigned short s; } wc;
        wc.h = (_Float16)enorm[e];
        unsigned a = (unsigned)(src[e] * 400) | ((e >= EHALF) ? 0x80000000u : 0u);
        unsigned b = (unsigned)etype[e] | ((unsigned)wc.s << 16);
        recs[pos] = make_uint2(a, b);
    }
}

__global__ __launch_bounds__(256) void build_map(
    const int* __restrict__ subj, const int* __restrict__ obj, int* __restrict__ map)
{
    int i = blockIdx.x * 256 + threadIdx.x;
    if (i < NB) map[subj[i]] = i;
    else if (i < 2 * NB) map[obj[i - NB]] = i;
}

// fp32 -> fp16 elementwise
__global__ __launch_bounds__(256) void to_f16(
    const float* __restrict__ X, _Float16* __restrict__ Y, long n4)
{
    long stride = (long)gridDim.x * blockDim.x;
    for (long i = (long)blockIdx.x * blockDim.x + threadIdx.x; i < n4; i += stride) {
        float4 v = ((const float4*)X)[i];
        halfx4 h;
        h[0] = (_Float16)v.x; h[1] = (_Float16)v.y;
        h[2] = (_Float16)v.z; h[3] = (_Float16)v.w;
        ((halfx4*)Y)[i] = h;
    }
}

// fp32 [200][200] -> fp16 padded [200][256] (512B row stride for 1-shift addressing)
__global__ __launch_bounds__(256) void to_f16_pad(
    const float* __restrict__ X, _Float16* __restrict__ Y)
{
    int i = blockIdx.x * 256 + threadIdx.x;
    if (i >= 40000) return;
    int row = i / 200, col = i - row * 200;
    Y[row * 256 + col] = (_Float16)X[i];
}

// ---------------------------------------------------------------- gather
// Scalarized CSR walk: node/beg/end/rec are wave-uniform (readfirstlane) ->
// rec loads go to the scalar pipe, loop control is scalar, in/out branch is
// a uniform s_cbranch. Per-edge vector work: 2 v_add (addr), 2 loads,
// 2 pk_mul, 2 pk_fma, 4 movs. Weights pre-converted to fp16 in edge_fill
// (bit-identical); zero-weight fma removed (adds exactly 0).
__global__ __launch_bounds__(256) void gather_nodes(
    const _Float16* __restrict__ x16, const _Float16* __restrict__ r16p,
    const int* __restrict__ offs, const uint2* __restrict__ recs,
    _Float16* __restrict__ aggI, _Float16* __restrict__ aggO)
{
    int node = __builtin_amdgcn_readfirstlane(blockIdx.x * 4 + (threadIdx.x >> 6));
    int lane = threadIdx.x & 63;
    if (node >= NENT) return;
    int beg = offs[node], end = offs[node + 1];
    bool act = lane < 50;
    int lane_c = min(lane, 49);
    unsigned lo = (unsigned)(lane_c * 8);
    const char* xb = (const char*)x16;
    const char* rb = (const char*)r16p;
    halfx4 aI = (halfx4)0, aO = (halfx4)0;

    if (beg < end) {
        uint2 rcA = recs[beg];
        uint2 rcB = recs[min(beg + 1, end - 1)];
        halfx4 xvA = *(const halfx4*)(xb + ((rcA.x & 0x7FFFFFFFu) + lo));
        halfx4 rvA = *(const halfx4*)(rb + (((rcA.y & 0x1FFu) << 9) + lo));
        for (int i = beg; i < end; ++i) {
            uint2 rcC = recs[min(i + 2, end - 1)];
            halfx4 xvB = *(const halfx4*)(xb + ((rcB.x & 0x7FFFFFFFu) + lo));
            halfx4 rvB = *(const halfx4*)(rb + (((rcB.y & 0x1FFu) << 9) + lo));
            union { unsigned u; _Float16 h[2]; } wu; wu.u = rcA.y;
            _Float16 wh = wu.h[1];
            halfx4 w4 = {wh, wh, wh, wh};
            halfx4 comp = xvA * rvA;
            if ((int)rcA.x < 0) aO += comp * w4;   // inverse edge -> w_out path
            else aI += comp * w4;                  // forward edge -> w_in path
            rcA = rcB; rcB = rcC; xvA = xvB; rvA = rvB;
        }
    }
    if (act) {
        size_t base = (size_t)node * 200 + lane * 4;
        *(halfx4*)&aggI[base] = aI;
        *(halfx4*)&aggO[base] = aO;
    }
}

// ---------------------------------------------------------------- weight packing (fp16 panel + swizzle)
__global__ __launch_bounds__(256) void pack_w3(
    const float* __restrict__ w0, const float* __restrict__ w1,
    const float* __restrict__ w2, const float* __restrict__ lrel,
    _Float16* __restrict__ WpP)
{
    int i = blockIdx.x * 256 + threadIdx.x;
    if (i >= WT_TOTAL_H) return;
    int p = i / PANEL_TOT_H;
    int r = i % PANEL_TOT_H;
    int y = (r >= Y1OFF_H) ? 1 : 0;
    int rr = y ? (r - Y1OFF_H) : r;
    int rl = rr >> 5;
    int qx = (rr >> 3) & 3;
    int e = rr & 7;
    int q = qx ^ ((rl >> 1) & 3);
    int n = y * 112 + rl;
    int seg = p / 7, c = p - seg * 7;
    int k = c * 32 + q * 8 + e;
    const float* W = (seg == 0) ? w0 : (seg == 1) ? w1 : w2;
    float v = (n < 200 && k < 200) ? W[k * 200 + n] : 0.f;
    if (seg == 2 && n < 200 && k < 200) v *= lrel[k];
    WpP[i] = (_Float16)v;
}

__global__ __launch_bounds__(256) void pack_fcw(
    const float* __restrict__ W, _Float16* __restrict__ Wt)
{
    long i = (long)blockIdx.x * 256 + threadIdx.x;
    if (i >= (long)208 * FLATSZ) return;
    int n = (int)(i / FLATSZ);
    Wt[i] = (n < 200) ? (_Float16)W[i] : (_Float16)0.f;
}

// ---------------------------------------------------------------- fp16 MFMA GEMM, barrier-free K loop
template<int Y>
__global__ __launch_bounds__(1024) void gemm_big(
    const _Float16* __restrict__ A0h, const _Float16* __restrict__ A1h,
    const _Float16* __restrict__ A2h, const _Float16* __restrict__ WpP,
    float* __restrict__ C, const float* __restrict__ bias,
    const int* __restrict__ map, float alpha,
    double* __restrict__ s1, double* __restrict__ s2)
{
    constexpr int NF = Y ? 6 : 7;
    constexpr int PC = NF;                   // 1KB chunks per panel
    constexpr int PANEL_H = NF * 512;        // halves per panel (3584/3072)
    constexpr int YOFF_H = Y ? Y1OFF_H : 0;
    constexpr int SEG_LDS_H = 7 * PANEL_H;   // halves per seg buffer
    __shared__ _Float16 Sb[2 * SEG_LDS_H];   // 100352 B (Y=0) / 86016 B (Y=1)
    __shared__ float fsum[NF * 16];
    __shared__ float fsq[NF * 16];

    int tid = threadIdx.x;
    int lane = tid & 63, wave = tid >> 6;
    int col16 = lane & 15, quad = lane >> 4;
    if (tid < NF * 16) { fsum[tid] = 0.f; fsq[tid] = 0.f; }

    int gw = blockIdx.x * 16 + wave;         // 0..4095
    bool act = gw < 3125;                    // 3125 * 32 == 100000 exactly
    int t = act ? gw : 0;
    int r0 = t * 32 + col16, r1 = r0 + 16;
    size_t b0 = (size_t)r0 * 200, b1 = (size_t)r1 * 200;

    floatx4 acc[NF][2];
#pragma unroll
    for (int nf = 0; nf < NF; ++nf) { acc[nf][0] = (floatx4)0.f; acc[nf][1] = (floatx4)0.f; }

    halfx8 ca0, ca1, na0, na1;

    auto stage = [&](int seg, int bufi) {
        for (int cc = wave; cc < 7 * PC; cc += 16) {
            int p7 = cc / PC, sub = cc - p7 * PC;
            const _Float16* g = WpP + (size_t)(seg * 7 + p7) * PANEL_TOT_H
                              + YOFF_H + sub * 512 + lane * 8;
            gload16h(g, Sb + bufi * SEG_LDS_H + cc * 512);
        }
    };
    auto loadA = [&](int kc, halfx8& a0, halfx8& a1) {
        int seg = kc / 7, c = kc - seg * 7;
        int koff = c * 32 + quad * 8;
        if (koff < 200) {
            const _Float16* A = (seg == 0) ? A0h : (seg == 1) ? A1h : A2h;
            a0 = *(const halfx8*)&A[b0 + koff];
            a1 = *(const halfx8*)&A[b1 + koff];
        } else {
            a0 = (halfx8)0; a1 = (halfx8)0;
        }
    };

    stage(0, 0);
    if (act) loadA(0, ca0, ca1);
    __syncthreads();                         // publishes seg0 panel

    int buf = 0;
    for (int seg = 0; seg < 3; ++seg) {
        if (seg < 2) stage(seg + 1, buf ^ 1);   // async, overlaps MFMAs below
        if (act) {
#pragma unroll
            for (int c = 0; c < 7; ++c) {
                int kc = seg * 7 + c;
                if (kc < 20) loadA(kc + 1, na0, na1);
                const _Float16* P = Sb + buf * SEG_LDS_H + c * PANEL_H;
                __builtin_amdgcn_s_setprio(1);
#pragma unroll
                for (int nf = 0; nf < NF; ++nf) {
                    int rl = nf * 16 + col16;
                    int qs = quad ^ ((rl >> 1) & 3);
                    halfx8 b = *(const halfx8*)&P[rl * 32 + qs * 8];
                    acc[nf][0] = __builtin_amdgcn_mfma_f32_16x16x32_f16(ca0, b, acc[nf][0], 0, 0, 0);
                    acc[nf][1] = __builtin_amdgcn_mfma_f32_16x16x32_f16(ca1, b, acc[nf][1], 0, 0, 0);
                }
                __builtin_amdgcn_s_setprio(0);
                ca0 = na0; ca1 = na1;
            }
        }
        __syncthreads();                     // seg done; next-seg panel published
        buf ^= 1;
    }

    int slot[2][4];
    if (map && act) {
#pragma unroll
        for (int h = 0; h < 2; ++h)
#pragma unroll
            for (int j = 0; j < 4; ++j)
                slot[h][j] = map[t * 32 + h * 16 + quad * 4 + j];
    }
    if (act) {
#pragma unroll
        for (int nf = 0; nf < NF; ++nf) {
            int lc = nf * 16 + col16;
            int colg = Y * 112 + lc;
            float ls = 0.f, lq = 0.f;
            if (colg < 200) {
                float bv = bias[colg];
#pragma unroll
                for (int h = 0; h < 2; ++h) {
                    int rbase = t * 32 + h * 16 + quad * 4;
#pragma unroll
                    for (int j = 0; j < 4; ++j) {
                        float v = acc[nf][h][j] * alpha + bv;
                        ls += v; lq += v * v;
                        if (!map) {
                            C[(size_t)(rbase + j) * 200 + colg] = v;
                        } else {
                            int s = slot[h][j];
                            if (s >= 0) C[(size_t)s * 200 + colg] = v;
                        }
                    }
                }
            }
            ls += __shfl_down(ls, 32); ls += __shfl_down(ls, 16);
            lq += __shfl_down(lq, 32); lq += __shfl_down(lq, 16);
            if (quad == 0 && colg < 200) {
                atomicAdd(&fsum[lc], ls);
                atomicAdd(&fsq[lc], lq);
            }
        }
    }
    __syncthreads();
    if (tid < NF * 16) {
        int colg = Y * 112 + tid;
        if (colg < 200) {
            gAtomicAdd(&s1[colg], (double)fsum[tid]);
            gAtomicAdd(&s2[colg], (double)fsq[tid]);
        }
    }
}

// ---------------------------------------------------------------- fc MFMA GEMM body (fp16)
template<int NF0, int NF>
__device__ __forceinline__ void fc_gemm_body(
    const _Float16* __restrict__ Ph, const _Float16* __restrict__ Wt,
    float* __restrict__ part, int ky, _Float16* Bs)
{
    int t = threadIdx.x;
    int lane = t & 63, wave = t >> 6;
    int col16 = lane & 15, quad = lane >> 4;
    int row_base = blockIdx.x * 128 + wave * 32;
    int c0 = ky * 25;
    floatx4 acc[NF][2];
#pragma unroll
    for (int nf = 0; nf < NF; ++nf) { acc[nf][0] = (floatx4)0.f; acc[nf][1] = (floatx4)0.f; }
    int r0 = row_base + col16, r1 = row_base + 16 + col16;
    const int rows4 = NF * 16 * 4;

    for (int c = c0; c < c0 + 25; ++c) {
        int k0 = c * 32;
        for (int i = t; i < rows4; i += 256) {
            int nl = i >> 2, part_i = i & 3;
            int n = NF0 * 16 + nl;
            *(halfx8*)&Bs[nl * 40 + part_i * 8] =
                *(const halfx8*)&Wt[(size_t)n * FLATSZ + k0 + part_i * 8];
        }
        __syncthreads();
        int koff = k0 + quad * 8;
        halfx8 a0 = *(const halfx8*)&Ph[(size_t)r0 * FLATSZ + koff];
        halfx8 a1 = *(const halfx8*)&Ph[(size_t)r1 * FLATSZ + koff];
#pragma unroll
        for (int nf = 0; nf < NF; ++nf) {
            halfx8 b = *(const halfx8*)&Bs[(nf * 16 + col16) * 40 + quad * 8];
            acc[nf][0] = __builtin_amdgcn_mfma_f32_16x16x32_f16(a0, b, acc[nf][0], 0, 0, 0);
            acc[nf][1] = __builtin_amdgcn_mfma_f32_16x16x32_f16(a1, b, acc[nf][1], 0, 0, 0);
        }
        __syncthreads();
    }
    float* out = part + (size_t)ky * (NB * 200);
#pragma unroll
    for (int nf = 0; nf < NF; ++nf) {
        int colg = NF0 * 16 + nf * 16 + col16;
        if (colg >= 200) continue;
#pragma unroll
        for (int h = 0; h < 2; ++h) {
            int rbase = row_base + h * 16 + quad * 4;
#pragma unroll
            for (int j = 0; j < 4; ++j)
                out[(size_t)(rbase + j) * 200 + colg] = acc[nf][h][j];
        }
    }
}

__global__ __launch_bounds__(256) void fc_gemm(
    const _Float16* __restrict__ Ph, const _Float16* __restrict__ Wt,
    float* __restrict__ part)
{
    __shared__ _Float16 Bs[112 * 40];
    int ky = blockIdx.y >> 1;
    if ((blockIdx.y & 1) == 0)
        fc_gemm_body<0, 7>(Ph, Wt, part, ky, Bs);
    else
        fc_gemm_body<7, 6>(Ph, Wt, part, ky, Bs);
}

__global__ __launch_bounds__(256) void fc_reduce(
    const float* __restrict__ part, const float* __restrict__ bias,
    float* __restrict__ hfc)
{
    int i = blockIdx.x * 256 + threadIdx.x;
    float acc = bias[i % 200];
#pragma unroll
    for (int y = 0; y < 49; ++y) acc += part[(size_t)y * (NB * 200) + i];
    hfc[i] = acc;
}

// ---------------------------------------------------------------- stats / bn
__global__ __launch_bounds__(256) void colstats(
    const float* __restrict__ X, int M, int rpb,
    double* __restrict__ s1, double* __restrict__ s2)
{
    int c = threadIdx.x;
    if (c >= 200) return;
    int r0 = blockIdx.x * rpb;
    int r1 = min(r0 + rpb, M);
    float sum = 0.f, sq = 0.f;
    for (int rr = r0; rr < r1; ++rr) {
        float v = X[(size_t)rr * 200 + c];
        sum += v; sq += v * v;
    }
    gAtomicAdd(&s1[c], (double)sum);
    gAtomicAdd(&s2[c], (double)sq);
}

__global__ void finalize_stats(const double* __restrict__ s1, const double* __restrict__ s2,
                               const float* __restrict__ g, const float* __restrict__ bb,
                               float* __restrict__ sc, float* __restrict__ sh,
                               int ncols, double count)
{
    int c = threadIdx.x;
    if (c >= ncols) return;
    double m = s1[c] / count;
    double v = s2[c] / count - m * m;
    double scd = (double)g[c] / sqrt(v + 1e-5);
    sc[c] = (float)scd;
    sh[c] = (float)((double)bb[c] - m * scd);
}

// bn + tanh, fp32 in -> fp16 out (layer-1 x for gather + gemm A2)
__global__ __launch_bounds__(256) void bn_tanh_f16(
    const float* __restrict__ X, const float* __restrict__ sc,
    const float* __restrict__ sh, _Float16* __restrict__ Y, long n4)
{
    long stride = (long)gridDim.x * blockDim.x;
    for (long i = (long)blockIdx.x * blockDim.x + threadIdx.x; i < n4; i += stride) {
        int c4 = (int)(i % 50) * 4;
        float4 v = ((const float4*)X)[i];
        halfx4 h;
        h[0] = (_Float16)tanhf(v.x * sc[c4 + 0] + sh[c4 + 0]);
        h[1] = (_Float16)tanhf(v.y * sc[c4 + 1] + sh[c4 + 1]);
        h[2] = (_Float16)tanhf(v.z * sc[c4 + 2] + sh[c4 + 2]);
        h[3] = (_Float16)tanhf(v.w * sc[c4 + 3] + sh[c4 + 3]);
        ((halfx4*)Y)[i] = h;
    }
}

__global__ __launch_bounds__(256) void bn_act_200(
    float* __restrict__ X, const float* __restrict__ sc, const float* __restrict__ sh,
    long n4, int act)
{
    long stride = (long)gridDim.x * blockDim.x;
    for (long i = (long)blockIdx.x * blockDim.x + threadIdx.x; i < n4; i += stride) {
        int c4 = (int)(i % 50) * 4;
        float4 v = ((const float4*)X)[i];
        float a0 = v.x * sc[c4 + 0] + sh[c4 + 0];
        float a1 = v.y * sc[c4 + 1] + sh[c4 + 1];
        float a2 = v.z * sc[c4 + 2] + sh[c4 + 2];
        float a3 = v.w * sc[c4 + 3] + sh[c4 + 3];
        if (act == 0) { a0 = tanhf(a0); a1 = tanhf(a1); a2 = tanhf(a2); a3 = tanhf(a3); }
        else { a0 = fmaxf(a0, 0.f); a1 = fmaxf(a1, 0.f); a2 = fmaxf(a2, 0.f); a3 = fmaxf(a3, 0.f); }
        ((float4*)X)[i] = make_float4(a0, a1, a2, a3);
    }
}

__global__ __launch_bounds__(256) void rel_mm(
    const float* __restrict__ R, const float* __restrict__ W, float* __restrict__ O)
{
    int idx = blockIdx.x * blockDim.x + threadIdx.x;
    if (idx >= 200 * 200) return;
    int row = idx / 200, col = idx - row * 200;
    float acc = 0.f;
    for (int k = 0; k < 200; ++k) acc = fmaf(R[row * 200 + k], W[k * 200 + col], acc);
    O[idx] = acc;
}

__global__ __launch_bounds__(256) void build_stk(
    const float* __restrict__ x2c, const float* __restrict__ r2,
    const int* __restrict__ subj, const int* __restrict__ ridx,
    const int* __restrict__ map,
    float* __restrict__ stk, double* __restrict__ s1, double* __restrict__ s2)
{
    __shared__ float wsum[4], wsq[4];
    int b = blockIdx.x, t = threadIdx.x;
    const float* se = x2c + (size_t)map[subj[b]] * DIM;
    const float* re = r2 + (size_t)ridx[b] * DIM;
    float sum = 0.f, sq = 0.f;
    for (int i = t; i < 400; i += 256) {
        float v = (i < 200) ? se[i] : re[i - 200];
        stk[(size_t)b * 400 + i] = v;
        sum += v; sq += v * v;
    }
    for (int off = 32; off > 0; off >>= 1) {
        sum += __shfl_down(sum, off);
        sq  += __shfl_down(sq, off);
    }
    if ((t & 63) == 0) { wsum[t >> 6] = sum; wsq[t >> 6] = sq; }
    __syncthreads();
    if (t == 0) {
        float S = wsum[0] + wsum[1] + wsum[2] + wsum[3];
        float Q = wsq[0] + wsq[1] + wsq[2] + wsq[3];
        gAtomicAdd(&s1[0], (double)S);
        gAtomicAdd(&s2[0], (double)Q);
    }
}

__global__ __launch_bounds__(256) void conv_fwd(
    const float* __restrict__ stk, const float* __restrict__ conv_w,
    const float* __restrict__ conv_b, const float* __restrict__ sc0,
    const float* __restrict__ sh0, _Float16* __restrict__ Ph,
    double* __restrict__ s1, double* __restrict__ s2)
{
    __shared__ float img[400];
    __shared__ float wsm[9800];
    __shared__ float bsm[200];
    __shared__ float fsum[200];
    __shared__ float fsq[200];
    int b = blockIdx.x, t = threadIdx.x;
    float scale0 = sc0[0], shift0 = sh0[0];
    if (t < 200) { fsum[t] = 0.f; fsq[t] = 0.f; bsm[t] = conv_b[t]; }
    for (int i = t; i < 400; i += 256) img[i] = stk[(size_t)b * 400 + i] * scale0 + shift0;
    for (int i = t; i < 9800; i += 256) wsm[i] = conv_w[i];
    __syncthreads();
    for (int fy = t; fy < 2800; fy += 256) {
        int f = fy / 14, y = fy - (fy / 14) * 14;
        const float* wf = &wsm[f * 49];
        float acc[14];
        float bias = bsm[f];
#pragma unroll
        for (int xx = 0; xx < 14; ++xx) acc[xx] = bias;
#pragma unroll
        for (int i = 0; i < 7; ++i) {
            const float* rowp = &img[(y + i) * 20];
            float rv[20];
#pragma unroll
            for (int c = 0; c < 20; ++c) rv[c] = rowp[c];
#pragma unroll
            for (int j = 0; j < 7; ++j) {
                float wv = wf[i * 7 + j];
#pragma unroll
                for (int xx = 0; xx < 14; ++xx) acc[xx] = fmaf(rv[xx + j], wv, acc[xx]);
            }
        }
        float ls = 0.f, lq = 0.f;
        _Float16* pp = Ph + (size_t)b * FLATSZ + (size_t)f * 196 + y * 14;
#pragma unroll
        for (int xx = 0; xx < 14; ++xx) {
            float v = acc[xx];
            pp[xx] = (_Float16)v;
            ls += v; lq += v * v;
        }
        atomicAdd(&fsum[f], ls);
        atomicAdd(&fsq[f], lq);
    }
    __syncthreads();
    if (t < 200) {
        gAtomicAdd(&s1[t], (double)fsum[t]);
        gAtomicAdd(&s2[t], (double)fsq[t]);
    }
}

__global__ __launch_bounds__(256) void bn1_relu_f16(
    _Float16* __restrict__ Ph, const float* __restrict__ sc, const float* __restrict__ sh)
{
    long n4 = (long)NB * (FLATSZ / 4);
    long stride = (long)gridDim.x * blockDim.x;
    for (long i = (long)blockIdx.x * blockDim.x + threadIdx.x; i < n4; i += stride) {
        int k4 = (int)(i % (FLATSZ / 4));
        int f = k4 / 49;
        float s = sc[f], h = sh[f];
        halfx4 v = ((const halfx4*)Ph)[i];
#pragma unroll
        for (int e = 0; e < 4; ++e) {
            float x = (float)v[e];
            x = fmaxf(x * s + h, 0.f);
            v[e] = (_Float16)x;
        }
        ((halfx4*)Ph)[i] = v;
    }
}

__global__ __launch_bounds__(256) void score_mm(
    const float* __restrict__ Hn, const float* __restrict__ x2c,
    const int* __restrict__ obj, const int* __restrict__ map,
    float* __restrict__ out)
{
    __shared__ float Asm[16][17];
    __shared__ float Bsm[16][17];
    int tx = threadIdx.x & 15, ty = threadIdx.x >> 4;
    int row = blockIdx.y * 16 + ty;
    int col = blockIdx.x * 16 + tx;
    int oj = map[obj[blockIdx.x * 16 + ty]];
    float acc = 0.f;
    for (int k0 = 0; k0 < 200; k0 += 16) {
        int k = k0 + tx;
        Asm[ty][tx] = (k < 200) ? Hn[(size_t)row * 200 + k] : 0.f;
        Bsm[ty][tx] = (k < 200) ? x2c[(size_t)oj * 200 + k] : 0.f;
        __syncthreads();
#pragma unroll
        for (int kk = 0; kk < 16; ++kk) acc = fmaf(Asm[ty][kk], Bsm[tx][kk], acc);
        __syncthreads();
    }
    out[(size_t)row * NB + col] = 1.f / (1.f + expf(-acc));
}

// ---------------------------------------------------------------- driver
extern "C" void kernel_launch(void* const* d_in, const int* in_sizes, int n_in,
                              void* d_out, int out_size, void* d_ws, size_t ws_size,
                              hipStream_t stream)
{
    (void)in_sizes; (void)n_in; (void)out_size;
    const float* init_embed = (const float*)d_in[0];
    const float* init_rel   = (const float*)d_in[1];
    const float* edge_norm  = (const float*)d_in[2];
    const float* w_in1  = (const float*)d_in[3];
    const float* w_out1 = (const float*)d_in[4];
    const float* w_loop1= (const float*)d_in[5];
    const float* w_rel1 = (const float*)d_in[6];
    const float* lrel1  = (const float*)d_in[7];
    const float* b1     = (const float*)d_in[8];
    const float* gm1    = (const float*)d_in[9];
    const float* be1    = (const float*)d_in[10];
    const float* w_in2  = (const float*)d_in[11];
    const float* w_out2 = (const float*)d_in[12];
    const float* w_loop2= (const float*)d_in[13];
    const float* w_rel2 = (const float*)d_in[14];
    const float* lrel2  = (const float*)d_in[15];
    const float* b2     = (const float*)d_in[16];
    const float* gm2    = (const float*)d_in[17];
    const float* be2    = (const float*)d_in[18];
    const float* conv_w = (const float*)d_in[19];
    const float* conv_b = (const float*)d_in[20];
    const float* fc_w   = (const float*)d_in[21];
    const float* fc_b   = (const float*)d_in[22];
    const float* bn0_g  = (const float*)d_in[23];
    const float* bn0_b  = (const float*)d_in[24];
    const float* bn1_g  = (const float*)d_in[25];
    const float* bn1_b  = (const float*)d_in[26];
    const float* bn2_g  = (const float*)d_in[27];
    const float* bn2_b  = (const float*)d_in[28];
    const int* subj   = (const int*)d_in[29];
    const int* relidx = (const int*)d_in[30];
    const int* obj    = (const int*)d_in[31];
    const int* src    = (const int*)d_in[32];
    const int* dst    = (const int*)d_in[33];
    const int* etype  = (const int*)d_in[34];

    float* ws = (float*)d_ws;
    float* R0 = ws;                 // L1: x1f (C); L2: aggI2; head: Ph
    float* R1 = ws + REGF;          // L1: aggI1 (1st half) + ie16 (2nd half); then x1h
    float* R2 = ws + 2 * REGF;      // aggO (both layers); head: fch + fpart
    float* p = ws + 3 * REGF;       // tail
    float* r1v = p;            p += 40000;
    float* r2v = p;            p += 40000;
    float* stk = p;            p += 409600;
    float* hfc = p;            p += 204800;
    float* x2c = p;            p += 409600;
    float* fsc = p;            p += 256;
    float* fsh = p;            p += 256;
    double* ds1 = (double*)p;  p += 512;
    double* ds2 = (double*)p;  p += 512;
    _Float16* Wp = (_Float16*)p; p += (WT_TOTAL_H + 1) / 2;
    _Float16* rg16p = (_Float16*)p; p += 25600;  // fp16 rel table, 256-half row stride
    int* map = (int*)p;        p += NENT;
    int* hist = (int*)p;       p += NENT;
    int* offs = (int*)p;       p += NENT + 4;
    int* cursor = (int*)p;     p += NENT;
    int* bsum = (int*)p;       p += 512;
    uint2* recs = (uint2*)p;   p += (size_t)NEDGE * 2;

    float* x1f = R0;                           // L1 gemm C (fp32)
    _Float16* aggI1 = (_Float16*)R1;           // L1 aggI (fp16, 20M halves)
    _Float16* ie16  = (_Float16*)(R1 + 10050000); // fp16 init_embed (A2 for L1)
    _Float16* aggOh = (_Float16*)R2;           // agg-out fp16 (both layers)
    _Float16* x1h = (_Float16*)R1;             // fp16 x1 (aggI1/ie16 dead after L1 gemm)
    _Float16* aggI2 = (_Float16*)R0;           // L2 aggI (x1f dead after bn_tanh_f16)
    _Float16* Ph  = (_Float16*)R0;
    _Float16* fch = (_Float16*)R2;
    float* fpart = R2 + 4200000;

    const size_t NEED = (size_t)(p - ws) * sizeof(float);
    if (ws_size < NEED) return;

    const int NBLK = (NENT + 255) / 256;
    const size_t DSBYTES = 512 * sizeof(double);

    // -------- CSR build + slot map --------
    hipMemsetAsync(hist, 0, NENT * sizeof(int), stream);
    hipMemsetAsync(map, 0xFF, NENT * sizeof(int), stream);
    edge_hist<<<1024, 256, 0, stream>>>(dst, hist);
    scan1<<<NBLK, 256, 0, stream>>>(hist, offs, bsum);
    scan2<<<1, 512, 0, stream>>>(bsum, NBLK);
    scan3<<<NBLK, 256, 0, stream>>>(hist, offs, bsum, cursor);
    edge_fill<<<1024, 256, 0, stream>>>(src, dst, etype, edge_norm, cursor, recs);
    build_map<<<(2 * NB + 255) / 256, 256, 0, stream>>>(subj, obj, map);

    const int PACK_BLKS = (WT_TOTAL_H + 255) / 256;

    // -------- layer 1 --------
    pack_w3<<<PACK_BLKS, 256, 0, stream>>>(w_in1, w_out1, w_loop1, lrel1, Wp);
    to_f16<<<4096, 256, 0, stream>>>(init_embed, ie16, (long)NENT * 50);
    to_f16_pad<<<157, 256, 0, stream>>>(init_rel, rg16p);
    gather_nodes<<<(NENT + 3) / 4, 256, 0, stream>>>(ie16, rg16p, offs, recs,
                                                     aggI1, aggOh);
    hipMemsetAsync(ds1, 0, DSBYTES, stream);
    gemm_big<0><<<256, 1024, 0, stream>>>(aggI1, aggOh, ie16, Wp,
                                          x1f, b1, nullptr, 1.f / 3.f, ds1, ds2);
    gemm_big<1><<<256, 1024, 0, stream>>>(aggI1, aggOh, ie16, Wp,
                                          x1f, b1, nullptr, 1.f / 3.f, ds1, ds2);
    finalize_stats<<<1, 256, 0, stream>>>(ds1, ds2, gm1, be1, fsc, fsh, 200, (double)NENT);
    bn_tanh_f16<<<4096, 256, 0, stream>>>(x1f, fsc, fsh, x1h, (long)NENT * 50);
    rel_mm<<<(40000 + 255) / 256, 256, 0, stream>>>(init_rel, w_rel1, r1v);

    // -------- layer 2 (fp16 x; compact output) --------
    pack_w3<<<PACK_BLKS, 256, 0, stream>>>(w_in2, w_out2, w_loop2, lrel2, Wp);
    to_f16_pad<<<157, 256, 0, stream>>>(r1v, rg16p);
    gather_nodes<<<(NENT + 3) / 4, 256, 0, stream>>>(x1h, rg16p, offs, recs,
                                                     aggI2, aggOh);
    hipMemsetAsync(ds1, 0, DSBYTES, stream);
    gemm_big<0><<<256, 1024, 0, stream>>>(aggI2, aggOh, x1h, Wp,
                                          x2c, b2, map, 1.f / 3.f, ds1, ds2);
    gemm_big<1><<<256, 1024, 0, stream>>>(aggI2, aggOh, x1h, Wp,
                                          x2c, b2, map, 1.f / 3.f, ds1, ds2);
    finalize_stats<<<1, 256, 0, stream>>>(ds1, ds2, gm2, be2, fsc, fsh, 200, (double)NENT);
    bn_act_200<<<400, 256, 0, stream>>>(x2c, fsc, fsh, (long)2 * NB * 50, 0);
    rel_mm<<<(40000 + 255) / 256, 256, 0, stream>>>(r1v, w_rel2, r2v);

    // -------- ConvE head --------
    hipMemsetAsync(ds1, 0, DSBYTES, stream);
    build_stk<<<NB, 256, 0, stream>>>(x2c, r2v, subj, relidx, map, stk, ds1, ds2);
    finalize_stats<<<1, 256, 0, stream>>>(ds1, ds2, bn0_g, bn0_b, fsc, fsh, 1,
                                          (double)((long)NB * 400));
    hipMemsetAsync(ds1, 0, DSBYTES, stream);
    conv_fwd<<<NB, 256, 0, stream>>>(stk, conv_w, conv_b, fsc, fsh, Ph, ds1, ds2);
    finalize_stats<<<1, 256, 0, stream>>>(ds1, ds2, bn1_g, bn1_b, fsc, fsh, 200,
                                          (double)((long)NB * 196));
    bn1_relu_f16<<<4096, 256, 0, stream>>>(Ph, fsc, fsh);
    pack_fcw<<<(int)(((long)208 * FLATSZ + 255) / 256), 256, 0, stream>>>(fc_w, fch);
    fc_gemm<<<dim3(8, 98), 256, 0, stream>>>(Ph, fch, fpart);
    fc_reduce<<<800, 256, 0, stream>>>(fpart, fc_b, hfc);
    hipMemsetAsync(ds1, 0, DSBYTES, stream);
    colstats<<<4, 256, 0, stream>>>(hfc, NB, 256, ds1, ds2);
    finalize_stats<<<1, 256, 0, stream>>>(ds1, ds2, bn2_g, bn2_b, fsc, fsh, 200, (double)NB);
    bn_act_200<<<200, 256, 0, stream>>>(hfc, fsc, fsh, (long)NB * 50, 1);
    score_mm<<<dim3(NB / 16, NB / 16), 256, 0, stream>>>(hfc, x2c, obj, map, (float*)d_out);
}